// Round 2
// baseline (1472.127 us; speedup 1.0000x reference)
//
#include <hip/hip_runtime.h>
#include <hip/hip_bf16.h>

// GraphSAGE 2-layer forward on MI355X.
// Restructure: mean(x[src]) @ W_l  ==  mean((x@W_l)[src])  (linearity),
// so GEMM happens at node granularity (dense, fast) and the edge phase
// only scatters rows. x@W_r is fused into the combine kernels.

constexpr int BLOCK = 256;

// ---------------- GEMM: out[n x DO] = in[n x DK] @ W[DK x DO] ----------------
template<int DK, int DO>
__global__ __launch_bounds__(256) void gemm_kernel(const float* __restrict__ in,
                                                   const float* __restrict__ W,
                                                   float* __restrict__ out, int n) {
    __shared__ float sW[DK * DO];
    for (int idx = threadIdx.x * 4; idx < DK * DO; idx += BLOCK * 4)
        *reinterpret_cast<float4*>(&sW[idx]) = *reinterpret_cast<const float4*>(&W[idx]);
    __syncthreads();

    const int wave = threadIdx.x >> 6, lane = threadIdx.x & 63;
    const int node = blockIdx.x * 4 + wave;
    if (node >= n) return;

    const float4* xrow = reinterpret_cast<const float4*>(in + (size_t)node * DK);
    float acc[DO / 64];
#pragma unroll
    for (int o = 0; o < DO / 64; ++o) acc[o] = 0.f;

#pragma unroll
    for (int k4 = 0; k4 < DK / 4; ++k4) {
        float4 xv = xrow[k4];
#pragma unroll
        for (int i = 0; i < 4; ++i) {
            float xs = (&xv.x)[i];
#pragma unroll
            for (int o = 0; o < DO / 64; ++o)
                acc[o] = fmaf(xs, sW[(k4 * 4 + i) * DO + lane + o * 64], acc[o]);
        }
    }
#pragma unroll
    for (int o = 0; o < DO / 64; ++o)
        out[(size_t)node * DO + lane + o * 64] = acc[o];
}

// ---------------- edge scatter: msg[dst] += y[src]; cnt[dst] += 1 ----------------
template<int D>
__global__ __launch_bounds__(256) void scatter_kernel(const float* __restrict__ y,
                                                      const int* __restrict__ ei,
                                                      float* __restrict__ msg,
                                                      float* __restrict__ cnt, int E) {
    const int wave = threadIdx.x >> 6, lane = threadIdx.x & 63;
    const int e = blockIdx.x * 4 + wave;
    if (e >= E) return;
    const int src = ei[e];
    const int dst = ei[E + e];
#pragma unroll
    for (int o = 0; o < D / 64; ++o) {
        float v = y[(size_t)src * D + lane + o * 64];
        atomicAdd(&msg[(size_t)dst * D + lane + o * 64], v);
    }
    if (lane == 0) atomicAdd(&cnt[dst], 1.0f);
}

// ---------------- combine layer 1: h = relu(msg/max(cnt,1) + b + x@W_r) ----------------
__global__ __launch_bounds__(256) void combine1_kernel(const float* __restrict__ x,
                                                       const float* __restrict__ Wr,
                                                       const float* __restrict__ b,
                                                       const float* __restrict__ msg,
                                                       const float* __restrict__ cnt,
                                                       float* __restrict__ h, int n) {
    __shared__ float sW[128 * 128];
    __shared__ float sb[128];
    for (int idx = threadIdx.x * 4; idx < 128 * 128; idx += BLOCK * 4)
        *reinterpret_cast<float4*>(&sW[idx]) = *reinterpret_cast<const float4*>(&Wr[idx]);
    if (threadIdx.x < 128) sb[threadIdx.x] = b[threadIdx.x];
    __syncthreads();

    const int wave = threadIdx.x >> 6, lane = threadIdx.x & 63;
    const int node = blockIdx.x * 4 + wave;
    if (node >= n) return;

    const float4* xrow = reinterpret_cast<const float4*>(x + (size_t)node * 128);
    float acc[2] = {0.f, 0.f};
#pragma unroll
    for (int k4 = 0; k4 < 32; ++k4) {
        float4 xv = xrow[k4];
#pragma unroll
        for (int i = 0; i < 4; ++i) {
            float xs = (&xv.x)[i];
            acc[0] = fmaf(xs, sW[(k4 * 4 + i) * 128 + lane], acc[0]);
            acc[1] = fmaf(xs, sW[(k4 * 4 + i) * 128 + lane + 64], acc[1]);
        }
    }
    const float c = fmaxf(cnt[node], 1.0f);
#pragma unroll
    for (int o = 0; o < 2; ++o) {
        int j = lane + o * 64;
        float v = msg[(size_t)node * 128 + j] / c + sb[j] + acc[o];
        h[(size_t)node * 128 + j] = fmaxf(v, 0.0f);
    }
}

// ------------- combine layer 2 + log_softmax: out = lsm(msg/max(cnt,1) + b + h@W_r) -------------
__global__ __launch_bounds__(256) void combine2_kernel(const float* __restrict__ h,
                                                       const float* __restrict__ Wr,
                                                       const float* __restrict__ b,
                                                       const float* __restrict__ msg,
                                                       const float* __restrict__ cnt,
                                                       float* __restrict__ out, int n) {
    __shared__ float sW[128 * 64];
    __shared__ float sb[64];
    for (int idx = threadIdx.x * 4; idx < 128 * 64; idx += BLOCK * 4)
        *reinterpret_cast<float4*>(&sW[idx]) = *reinterpret_cast<const float4*>(&Wr[idx]);
    if (threadIdx.x < 64) sb[threadIdx.x] = b[threadIdx.x];
    __syncthreads();

    const int wave = threadIdx.x >> 6, lane = threadIdx.x & 63;
    const int node = blockIdx.x * 4 + wave;
    if (node >= n) return;

    const float4* hrow = reinterpret_cast<const float4*>(h + (size_t)node * 128);
    float acc = 0.f;
#pragma unroll
    for (int k4 = 0; k4 < 32; ++k4) {
        float4 xv = hrow[k4];
#pragma unroll
        for (int i = 0; i < 4; ++i)
            acc = fmaf((&xv.x)[i], sW[(k4 * 4 + i) * 64 + lane], acc);
    }
    const float c = fmaxf(cnt[node], 1.0f);
    float o = msg[(size_t)node * 64 + lane] / c + sb[lane] + acc;

    // log_softmax across the 64 lanes (one class per lane)
    float m = o;
#pragma unroll
    for (int off = 32; off; off >>= 1) m = fmaxf(m, __shfl_xor(m, off));
    float e = expf(o - m);
    float s = e;
#pragma unroll
    for (int off = 32; off; off >>= 1) s += __shfl_xor(s, off);
    out[(size_t)node * 64 + lane] = o - m - logf(s);
}

extern "C" void kernel_launch(void* const* d_in, const int* in_sizes, int n_in,
                              void* d_out, int out_size, void* d_ws, size_t ws_size,
                              hipStream_t stream) {
    const float* x    = (const float*)d_in[0];
    const int*   ei1  = (const int*)d_in[1];
    const int*   ei2  = (const int*)d_in[2];
    const float* W_l1 = (const float*)d_in[3];
    const float* b_l1 = (const float*)d_in[4];
    const float* W_r1 = (const float*)d_in[5];
    const float* W_l2 = (const float*)d_in[6];
    const float* b_l2 = (const float*)d_in[7];
    const float* W_r2 = (const float*)d_in[8];

    const int n  = in_sizes[0] / 128;
    const int E1 = in_sizes[1] / 2;
    const int E2 = in_sizes[2] / 2;

    // workspace layout (floats):
    //   A    : n*128   (y1 = x@W_l1, later reused for h)
    //   B    : n*128   (msg1, later reused for {msg2 [0,n*64), z2 [n*64,n*128)})
    //   cnt1 : n
    //   cnt2 : n
    float* A    = (float*)d_ws;
    float* B    = A + (size_t)n * 128;
    float* cnt1 = B + (size_t)n * 128;
    float* cnt2 = cnt1 + n;
    float* out  = (float*)d_out;

    hipMemsetAsync(B, 0, (size_t)n * 128 * sizeof(float), stream);
    hipMemsetAsync(cnt1, 0, 2 * (size_t)n * sizeof(float), stream);

    const int nb4 = (n + 3) / 4;

    // layer 1
    gemm_kernel<128, 128><<<nb4, BLOCK, 0, stream>>>(x, W_l1, A, n);
    scatter_kernel<128><<<(E1 + 3) / 4, BLOCK, 0, stream>>>(A, ei1, B, cnt1, E1);
    combine1_kernel<<<nb4, BLOCK, 0, stream>>>(x, W_r1, b_l1, B, cnt1, A, n);  // A = h

    // layer 2
    hipMemsetAsync(B, 0, (size_t)n * 64 * sizeof(float), stream);              // msg2 region
    float* z2 = B + (size_t)n * 64;
    gemm_kernel<128, 64><<<nb4, BLOCK, 0, stream>>>(A, W_l2, z2, n);
    scatter_kernel<64><<<(E2 + 3) / 4, BLOCK, 0, stream>>>(z2, ei2, B, cnt2, E2);
    combine2_kernel<<<nb4, BLOCK, 0, stream>>>(A, W_r2, b_l2, B, cnt2, out, n);
}

// Round 3
// 1123.335 us; speedup vs baseline: 1.3105x; 1.3105x over previous
//
#include <hip/hip_runtime.h>
#include <hip/hip_bf16.h>

// GraphSAGE 2-layer forward on MI355X.
// mean(x[src]) @ W_l == mean((x@W_l)[src])  (linearity) -> GEMM at node
// granularity, edge phase is a CSR gather-reduce (NO f32 atomics -- round-2
// profile showed the atomic scatter at 454us, 7% VALU, 22% HBM: atomic-bound).

constexpr int BLOCK = 256;

// ---------------- GEMM: out[n x DO] = in[n x DK] @ W[DK x DO] ----------------
template<int DK, int DO>
__global__ __launch_bounds__(256) void gemm_kernel(const float* __restrict__ in,
                                                   const float* __restrict__ W,
                                                   float* __restrict__ out, int n) {
    __shared__ float sW[DK * DO];
    for (int idx = threadIdx.x * 4; idx < DK * DO; idx += BLOCK * 4)
        *reinterpret_cast<float4*>(&sW[idx]) = *reinterpret_cast<const float4*>(&W[idx]);
    __syncthreads();

    const int wave = threadIdx.x >> 6, lane = threadIdx.x & 63;
    const int node = blockIdx.x * 4 + wave;
    if (node >= n) return;

    const float4* xrow = reinterpret_cast<const float4*>(in + (size_t)node * DK);
    float acc[DO / 64];
#pragma unroll
    for (int o = 0; o < DO / 64; ++o) acc[o] = 0.f;

#pragma unroll
    for (int k4 = 0; k4 < DK / 4; ++k4) {
        float4 xv = xrow[k4];
#pragma unroll
        for (int i = 0; i < 4; ++i) {
            float xs = (&xv.x)[i];
#pragma unroll
            for (int o = 0; o < DO / 64; ++o)
                acc[o] = fmaf(xs, sW[(k4 * 4 + i) * DO + lane + o * 64], acc[o]);
        }
    }
#pragma unroll
    for (int o = 0; o < DO / 64; ++o)
        out[(size_t)node * DO + lane + o * 64] = acc[o];
}

// ---------------- CSR build ----------------
__global__ void hist_kernel(const int* __restrict__ ei, int E, int* __restrict__ rowptr) {
    int e = blockIdx.x * blockDim.x + threadIdx.x;
    if (e < E) atomicAdd(&rowptr[ei[E + e]], 1);   // dst in-degree
}

// exclusive scan of rowptr[0..n) in place; rowptr[n] = total.  1024 elems/block.
__global__ void scan_p1(const int* __restrict__ deg, int n, int* __restrict__ partial) {
    __shared__ int sw[4];
    int base = blockIdx.x * 1024 + threadIdx.x * 4;
    int s = 0;
#pragma unroll
    for (int k = 0; k < 4; ++k) { int i = base + k; if (i < n) s += deg[i]; }
#pragma unroll
    for (int off = 1; off < 64; off <<= 1) s += __shfl_xor(s, off);
    int wave = threadIdx.x >> 6, lane = threadIdx.x & 63;
    if (lane == 0) sw[wave] = s;
    __syncthreads();
    if (threadIdx.x == 0) partial[blockIdx.x] = sw[0] + sw[1] + sw[2] + sw[3];
}

__global__ void scan_p2(int* __restrict__ partial, int nb, int* __restrict__ rowptr, int n) {
    int run = 0;
    for (int b = 0; b < nb; ++b) { int t = partial[b]; partial[b] = run; run += t; }
    rowptr[n] = run;
}

__global__ void scan_p3(int* __restrict__ rowptr, int n, const int* __restrict__ partial) {
    __shared__ int sw[4];
    int base = blockIdx.x * 1024 + threadIdx.x * 4;
    int v[4]; int ts = 0;
#pragma unroll
    for (int k = 0; k < 4; ++k) { int i = base + k; v[k] = (i < n) ? rowptr[i] : 0; ts += v[k]; }
    int lane = threadIdx.x & 63, wave = threadIdx.x >> 6;
    int x = ts;
#pragma unroll
    for (int off = 1; off < 64; off <<= 1) { int y = __shfl_up(x, off); if (lane >= off) x += y; }
    if (lane == 63) sw[wave] = x;
    __syncthreads();
    int woff = 0;
#pragma unroll
    for (int w = 0; w < 4; ++w) if (w < wave) woff += sw[w];
    int run = partial[blockIdx.x] + woff + (x - ts);
#pragma unroll
    for (int k = 0; k < 4; ++k) { int i = base + k; if (i < n) { rowptr[i] = run; run += v[k]; } }
}

__global__ void fill_kernel(const int* __restrict__ ei, int E, const int* __restrict__ rowptr,
                            int* __restrict__ cursor, int* __restrict__ csr) {
    int e = blockIdx.x * blockDim.x + threadIdx.x;
    if (e >= E) return;
    int src = ei[e], dst = ei[E + e];
    int pos = rowptr[dst] + atomicAdd(&cursor[dst], 1);
    csr[pos] = src;
}

// ---------------- gather-reduce: agg[i] = mean_{j in in(i)} y[j] ----------------
template<int D>
__global__ __launch_bounds__(256) void gather_kernel(const float* __restrict__ y,
                                                     const int* __restrict__ rowptr,
                                                     const int* __restrict__ csr,
                                                     float* __restrict__ agg, int n) {
    const int wave = threadIdx.x >> 6, lane = threadIdx.x & 63;
    const int node = blockIdx.x * 4 + wave;
    if (node >= n) return;
    const int start = rowptr[node], end = rowptr[node + 1];

    float acc[D / 64];
#pragma unroll
    for (int o = 0; o < D / 64; ++o) acc[o] = 0.f;

    for (int base = start; base < end; base += 64) {
        const int m = min(64, end - base);
        int s = (lane < m) ? csr[base + lane] : 0;
#pragma unroll 4
        for (int j = 0; j < m; ++j) {
            const int sj = __shfl(s, j);
            const float* row = y + (size_t)sj * D;
#pragma unroll
            for (int o = 0; o < D / 64; ++o) acc[o] += row[lane + o * 64];
        }
    }
    const float inv = 1.0f / fmaxf((float)(end - start), 1.0f);
#pragma unroll
    for (int o = 0; o < D / 64; ++o)
        agg[(size_t)node * D + lane + o * 64] = acc[o] * inv;
}

// ---------------- combine layer 1: h = relu(agg + b + x@W_r) ----------------
__global__ __launch_bounds__(256) void combine1_kernel(const float* __restrict__ x,
                                                       const float* __restrict__ Wr,
                                                       const float* __restrict__ b,
                                                       const float* __restrict__ agg,
                                                       float* __restrict__ h, int n) {
    __shared__ float sW[128 * 128];
    __shared__ float sb[128];
    for (int idx = threadIdx.x * 4; idx < 128 * 128; idx += BLOCK * 4)
        *reinterpret_cast<float4*>(&sW[idx]) = *reinterpret_cast<const float4*>(&Wr[idx]);
    if (threadIdx.x < 128) sb[threadIdx.x] = b[threadIdx.x];
    __syncthreads();

    const int wave = threadIdx.x >> 6, lane = threadIdx.x & 63;
    const int node = blockIdx.x * 4 + wave;
    if (node >= n) return;

    const float4* xrow = reinterpret_cast<const float4*>(x + (size_t)node * 128);
    float acc[2] = {0.f, 0.f};
#pragma unroll
    for (int k4 = 0; k4 < 32; ++k4) {
        float4 xv = xrow[k4];
#pragma unroll
        for (int i = 0; i < 4; ++i) {
            float xs = (&xv.x)[i];
            acc[0] = fmaf(xs, sW[(k4 * 4 + i) * 128 + lane], acc[0]);
            acc[1] = fmaf(xs, sW[(k4 * 4 + i) * 128 + lane + 64], acc[1]);
        }
    }
#pragma unroll
    for (int o = 0; o < 2; ++o) {
        int j = lane + o * 64;
        float v = agg[(size_t)node * 128 + j] + sb[j] + acc[o];
        h[(size_t)node * 128 + j] = fmaxf(v, 0.0f);
    }
}

// ------------- combine layer 2 + log_softmax -------------
__global__ __launch_bounds__(256) void combine2_kernel(const float* __restrict__ h,
                                                       const float* __restrict__ Wr,
                                                       const float* __restrict__ b,
                                                       const float* __restrict__ agg,
                                                       float* __restrict__ out, int n) {
    __shared__ float sW[128 * 64];
    __shared__ float sb[64];
    for (int idx = threadIdx.x * 4; idx < 128 * 64; idx += BLOCK * 4)
        *reinterpret_cast<float4*>(&sW[idx]) = *reinterpret_cast<const float4*>(&Wr[idx]);
    if (threadIdx.x < 64) sb[threadIdx.x] = b[threadIdx.x];
    __syncthreads();

    const int wave = threadIdx.x >> 6, lane = threadIdx.x & 63;
    const int node = blockIdx.x * 4 + wave;
    if (node >= n) return;

    const float4* hrow = reinterpret_cast<const float4*>(h + (size_t)node * 128);
    float acc = 0.f;
#pragma unroll
    for (int k4 = 0; k4 < 32; ++k4) {
        float4 xv = hrow[k4];
#pragma unroll
        for (int i = 0; i < 4; ++i)
            acc = fmaf((&xv.x)[i], sW[(k4 * 4 + i) * 64 + lane], acc);
    }
    float o = agg[(size_t)node * 64 + lane] + sb[lane] + acc;

    float m = o;
#pragma unroll
    for (int off = 32; off; off >>= 1) m = fmaxf(m, __shfl_xor(m, off));
    float e = expf(o - m);
    float s = e;
#pragma unroll
    for (int off = 32; off; off >>= 1) s += __shfl_xor(s, off);
    out[(size_t)node * 64 + lane] = o - m - logf(s);
}

extern "C" void kernel_launch(void* const* d_in, const int* in_sizes, int n_in,
                              void* d_out, int out_size, void* d_ws, size_t ws_size,
                              hipStream_t stream) {
    const float* x    = (const float*)d_in[0];
    const int*   ei1  = (const int*)d_in[1];
    const int*   ei2  = (const int*)d_in[2];
    const float* W_l1 = (const float*)d_in[3];
    const float* b_l1 = (const float*)d_in[4];
    const float* W_r1 = (const float*)d_in[5];
    const float* W_l2 = (const float*)d_in[6];
    const float* b_l2 = (const float*)d_in[7];
    const float* W_r2 = (const float*)d_in[8];

    const int n  = in_sizes[0] / 128;
    const int E1 = in_sizes[1] / 2;
    const int E2 = in_sizes[2] / 2;
    const int Emax = E1 > E2 ? E1 : E2;

    // ws layout: A[n*128] f32 | B[n*128] f32 | rowptr[n+1] | cursor[n] | partial[1024] | csr[Emax]
    float* A      = (float*)d_ws;
    float* B      = A + (size_t)n * 128;
    int*   rowptr = (int*)(B + (size_t)n * 128);
    int*   cursor = rowptr + (n + 1);
    int*   partial= cursor + n;
    int*   csr    = partial + 1024;
    float* out    = (float*)d_out;

    const int NB  = (n + 1023) / 1024;
    const int nb4 = (n + 3) / 4;

    auto buildCSR = [&](const int* ei, int E) {
        hipMemsetAsync(rowptr, 0, (size_t)(n + 1) * sizeof(int), stream);
        hist_kernel<<<(E + 255) / 256, 256, 0, stream>>>(ei, E, rowptr);
        scan_p1<<<NB, 256, 0, stream>>>(rowptr, n, partial);
        scan_p2<<<1, 1, 0, stream>>>(partial, NB, rowptr, n);
        scan_p3<<<NB, 256, 0, stream>>>(rowptr, n, partial);
        hipMemsetAsync(cursor, 0, (size_t)n * sizeof(int), stream);
        fill_kernel<<<(E + 255) / 256, 256, 0, stream>>>(ei, E, rowptr, cursor, csr);
    };

    // layer 1
    buildCSR(ei1, E1);
    gemm_kernel<128, 128><<<nb4, BLOCK, 0, stream>>>(x, W_l1, A, n);        // A = x@W_l1
    gather_kernel<128><<<nb4, BLOCK, 0, stream>>>(A, rowptr, csr, B, n);    // B = mean agg
    combine1_kernel<<<nb4, BLOCK, 0, stream>>>(x, W_r1, b_l1, B, A, n);     // A = h

    // layer 2
    buildCSR(ei2, E2);
    float* z2   = B;                    // n*64
    float* agg2 = B + (size_t)n * 64;   // n*64
    gemm_kernel<128, 64><<<nb4, BLOCK, 0, stream>>>(A, W_l2, z2, n);
    gather_kernel<64><<<nb4, BLOCK, 0, stream>>>(z2, rowptr, csr, agg2, n);
    combine2_kernel<<<nb4, BLOCK, 0, stream>>>(A, W_r2, b_l2, agg2, out, n);
}

// Round 4
// 497.046 us; speedup vs baseline: 2.9618x; 2.2600x over previous
//
#include <hip/hip_runtime.h>
#include <hip/hip_bf16.h>

// GraphSAGE 2-layer forward on MI355X — MFMA edition.
// mean(x[src]) @ W == mean((x@W)[src]) -> GEMMs at node granularity (bf16 MFMA,
// weights prepacked in fragment order), edge phase = CSR gather over bf16 rows.
// Round-3 profile: fp32 LDS gemm was latency-bound (VALUBusy 19%, occ 22%).

typedef __attribute__((ext_vector_type(8))) short bf16x8;
typedef __attribute__((ext_vector_type(4))) float f32x4;
typedef unsigned int u32;
typedef unsigned short u16;

__device__ __forceinline__ u16 f2bf(float f) {
    u32 u = __float_as_uint(f);
    return (u16)((u + 0x7fffu + ((u >> 16) & 1u)) >> 16);
}
__device__ __forceinline__ float bf2f(u16 h) { return __uint_as_float((u32)h << 16); }

// ---------------- convert fp32 -> bf16, 8 elems/thread ----------------
__global__ __launch_bounds__(256) void convert_bf16_kernel(const float* __restrict__ in,
                                                           u16* __restrict__ out, long total) {
    long i = ((long)blockIdx.x * 256 + threadIdx.x) * 8;
    if (i >= total) return;
    float4 v0 = *reinterpret_cast<const float4*>(in + i);
    float4 v1 = *reinterpret_cast<const float4*>(in + i + 4);
    bf16x8 o;
    o[0] = (short)f2bf(v0.x); o[1] = (short)f2bf(v0.y);
    o[2] = (short)f2bf(v0.z); o[3] = (short)f2bf(v0.w);
    o[4] = (short)f2bf(v1.x); o[5] = (short)f2bf(v1.y);
    o[6] = (short)f2bf(v1.z); o[7] = (short)f2bf(v1.w);
    *reinterpret_cast<bf16x8*>(out + i) = o;
}

// -------- pack W[K=128][O] into MFMA B-fragment order (bf16) --------
// unit u = (ks*(O/16)+nt)*64 + lane; elem j -> W[ks*32 + (lane>>4)*8 + j][nt*16 + (lane&15)]
__global__ __launch_bounds__(256) void pack_weights(const float* __restrict__ Wl1,
                                                    const float* __restrict__ Wr1,
                                                    const float* __restrict__ Wl2,
                                                    const float* __restrict__ Wr2,
                                                    u16* __restrict__ Pl1, u16* __restrict__ Pr1,
                                                    u16* __restrict__ Pl2, u16* __restrict__ Pr2) {
    int u = blockIdx.x * 256 + threadIdx.x;
    if (u >= 6144) return;
    const float* W; u16* P; int O;
    if (u < 2048)      { W = Wl1; P = Pl1; O = 128; }
    else if (u < 4096) { W = Wr1; P = Pr1; O = 128; u -= 2048; }
    else if (u < 5120) { W = Wl2; P = Pl2; O = 64;  u -= 4096; }
    else               { W = Wr2; P = Pr2; O = 64;  u -= 5120; }
    int lane = u & 63, t = u >> 6;
    int ntiles = O / 16;
    int ks = t / ntiles, nt = t % ntiles;
    int k0 = ks * 32 + (lane >> 4) * 8;
    int col = nt * 16 + (lane & 15);
    bf16x8 o;
#pragma unroll
    for (int j = 0; j < 8; ++j) o[j] = (short)f2bf(W[(size_t)(k0 + j) * O + col]);
    *reinterpret_cast<bf16x8*>(P + (size_t)u * 8) = o;
}

// ---------------- CSR build (proven in round 3) ----------------
__global__ void hist_kernel(const int* __restrict__ ei, int E, int* __restrict__ rowptr) {
    int e = blockIdx.x * blockDim.x + threadIdx.x;
    if (e < E) atomicAdd(&rowptr[ei[E + e]], 1);
}

__global__ void scan_p1(const int* __restrict__ deg, int n, int* __restrict__ partial) {
    __shared__ int sw[4];
    int base = blockIdx.x * 1024 + threadIdx.x * 4;
    int s = 0;
#pragma unroll
    for (int k = 0; k < 4; ++k) { int i = base + k; if (i < n) s += deg[i]; }
#pragma unroll
    for (int off = 1; off < 64; off <<= 1) s += __shfl_xor(s, off);
    int wave = threadIdx.x >> 6, lane = threadIdx.x & 63;
    if (lane == 0) sw[wave] = s;
    __syncthreads();
    if (threadIdx.x == 0) partial[blockIdx.x] = sw[0] + sw[1] + sw[2] + sw[3];
}

__global__ void scan_p2(int* __restrict__ partial, int nb, int* __restrict__ rowptr, int n) {
    int run = 0;
    for (int b = 0; b < nb; ++b) { int t = partial[b]; partial[b] = run; run += t; }
    rowptr[n] = run;
}

__global__ void scan_p3(int* __restrict__ rowptr, int n, const int* __restrict__ partial) {
    __shared__ int sw[4];
    int base = blockIdx.x * 1024 + threadIdx.x * 4;
    int v[4]; int ts = 0;
#pragma unroll
    for (int k = 0; k < 4; ++k) { int i = base + k; v[k] = (i < n) ? rowptr[i] : 0; ts += v[k]; }
    int lane = threadIdx.x & 63, wave = threadIdx.x >> 6;
    int x = ts;
#pragma unroll
    for (int off = 1; off < 64; off <<= 1) { int y = __shfl_up(x, off); if (lane >= off) x += y; }
    if (lane == 63) sw[wave] = x;
    __syncthreads();
    int woff = 0;
#pragma unroll
    for (int w = 0; w < 4; ++w) if (w < wave) woff += sw[w];
    int run = partial[blockIdx.x] + woff + (x - ts);
#pragma unroll
    for (int k = 0; k < 4; ++k) { int i = base + k; if (i < n) { rowptr[i] = run; run += v[k]; } }
}

__global__ void fill_kernel(const int* __restrict__ ei, int E, const int* __restrict__ rowptr,
                            int* __restrict__ cursor, int* __restrict__ csr) {
    int e = blockIdx.x * blockDim.x + threadIdx.x;
    if (e >= E) return;
    int src = ei[e], dst = ei[E + e];
    int pos = rowptr[dst] + atomicAdd(&cursor[dst], 1);
    csr[pos] = src;
}

// ---------------- MFMA GEMM: out[n x O] = A[n x 128] @ W, fused epilogues ----------------
// MODE 0: out = bf16(A@W)
// MODE 1: out = bf16(relu(A@W + bias + agg))
// MODE 2: out = f32(log_softmax(A@W + bias + agg))   (O == 64)
template<int O, int MODE>
__global__ __launch_bounds__(256) void mfma_gemm(const u16* __restrict__ A,
                                                 const u16* __restrict__ Bp,
                                                 const float* __restrict__ bias,
                                                 const u16* __restrict__ agg,
                                                 void* __restrict__ outv, int n) {
    constexpr int NT = O / 16;
    const int wave = threadIdx.x >> 6, lane = threadIdx.x & 63;
    const int row0 = (blockIdx.x * 4 + wave) * 32;
    if (row0 >= n) return;
    const int lr = lane & 15, lg = lane >> 4;

    const int ra0 = min(row0 + lr, n - 1);
    const int ra1 = min(row0 + 16 + lr, n - 1);
    const bf16x8* A0 = reinterpret_cast<const bf16x8*>(A + (size_t)ra0 * 128);
    const bf16x8* A1 = reinterpret_cast<const bf16x8*>(A + (size_t)ra1 * 128);
    const bf16x8* B8 = reinterpret_cast<const bf16x8*>(Bp) + lane;

    f32x4 acc[2][NT];
#pragma unroll
    for (int i = 0; i < 2; ++i)
#pragma unroll
        for (int t = 0; t < NT; ++t) acc[i][t] = (f32x4){0.f, 0.f, 0.f, 0.f};

#pragma unroll
    for (int ks = 0; ks < 4; ++ks) {
        bf16x8 a0 = A0[ks * 4 + lg];
        bf16x8 a1 = A1[ks * 4 + lg];
#pragma unroll
        for (int t = 0; t < NT; ++t) {
            bf16x8 b = B8[(size_t)(ks * NT + t) * 64];
            acc[0][t] = __builtin_amdgcn_mfma_f32_16x16x32_bf16(a0, b, acc[0][t], 0, 0, 0);
            acc[1][t] = __builtin_amdgcn_mfma_f32_16x16x32_bf16(a1, b, acc[1][t], 0, 0, 0);
        }
    }

    // C/D layout (m89-verified): col = lane&15, row = (lane>>4)*4 + reg
    if (MODE == 2) {
        float* out = (float*)outv;
#pragma unroll
        for (int h = 0; h < 2; ++h) {
            float v[NT][4], m[4], s[4];
#pragma unroll
            for (int t = 0; t < NT; ++t) {
                float bv = bias[t * 16 + lr];
#pragma unroll
                for (int r = 0; r < 4; ++r) {
                    int row = min(row0 + h * 16 + lg * 4 + r, n - 1);
                    v[t][r] = acc[h][t][r] + bv + bf2f(agg[(size_t)row * O + t * 16 + lr]);
                }
            }
#pragma unroll
            for (int r = 0; r < 4; ++r)
                m[r] = fmaxf(fmaxf(v[0][r], v[1][r]), fmaxf(v[2][r], v[3][r]));
#pragma unroll
            for (int off = 1; off <= 8; off <<= 1)
#pragma unroll
                for (int r = 0; r < 4; ++r) m[r] = fmaxf(m[r], __shfl_xor(m[r], off));
#pragma unroll
            for (int r = 0; r < 4; ++r)
                s[r] = expf(v[0][r] - m[r]) + expf(v[1][r] - m[r]) +
                       expf(v[2][r] - m[r]) + expf(v[3][r] - m[r]);
#pragma unroll
            for (int off = 1; off <= 8; off <<= 1)
#pragma unroll
                for (int r = 0; r < 4; ++r) s[r] += __shfl_xor(s[r], off);
#pragma unroll
            for (int r = 0; r < 4; ++r) {
                float ls = logf(s[r]);
                int row = row0 + h * 16 + lg * 4 + r;
                if (row < n)
#pragma unroll
                    for (int t = 0; t < NT; ++t)
                        out[(size_t)row * O + t * 16 + lr] = v[t][r] - m[r] - ls;
            }
        }
    } else {
        u16* out = (u16*)outv;
#pragma unroll
        for (int h = 0; h < 2; ++h)
#pragma unroll
            for (int t = 0; t < NT; ++t) {
                float bv = (MODE == 1) ? bias[t * 16 + lr] : 0.f;
#pragma unroll
                for (int r = 0; r < 4; ++r) {
                    int row = row0 + h * 16 + lg * 4 + r;
                    if (row < n) {
                        float val = acc[h][t][r];
                        if (MODE == 1) {
                            val += bv + bf2f(agg[(size_t)row * O + t * 16 + lr]);
                            val = fmaxf(val, 0.f);
                        }
                        out[(size_t)row * O + t * 16 + lr] = f2bf(val);
                    }
                }
            }
    }
}

// ---------------- gather-reduce (bf16 rows, fp32 acc): agg[i] = mean y[src] ----------------
template<int D>
__global__ __launch_bounds__(256) void gather_kernel(const u16* __restrict__ y,
                                                     const int* __restrict__ rowptr,
                                                     const int* __restrict__ csr,
                                                     u16* __restrict__ agg, int n) {
    const int wave = threadIdx.x >> 6, lane = threadIdx.x & 63;
    const int node = blockIdx.x * 4 + wave;
    if (node >= n) return;
    const int start = rowptr[node], end = rowptr[node + 1];
    float acc0 = 0.f, acc1 = 0.f;
    for (int base = start; base < end; base += 64) {
        const int m = min(64, end - base);
        int s = (lane < m) ? csr[base + lane] : 0;
        for (int j = 0; j < m; ++j) {
            const int sj = __shfl(s, j);
            if (D == 128) {
                u32 v = *reinterpret_cast<const u32*>(y + (size_t)sj * 128 + lane * 2);
                acc0 += bf2f((u16)(v & 0xffffu));
                acc1 += bf2f((u16)(v >> 16));
            } else {
                acc0 += bf2f(y[(size_t)sj * 64 + lane]);
            }
        }
    }
    const float inv = 1.0f / fmaxf((float)(end - start), 1.0f);
    if (D == 128) {
        u32 o = (u32)f2bf(acc0 * inv) | ((u32)f2bf(acc1 * inv) << 16);
        *reinterpret_cast<u32*>(agg + (size_t)node * 128 + lane * 2) = o;
    } else {
        agg[(size_t)node * 64 + lane] = f2bf(acc0 * inv);
    }
}

extern "C" void kernel_launch(void* const* d_in, const int* in_sizes, int n_in,
                              void* d_out, int out_size, void* d_ws, size_t ws_size,
                              hipStream_t stream) {
    const float* x    = (const float*)d_in[0];
    const int*   ei1  = (const int*)d_in[1];
    const int*   ei2  = (const int*)d_in[2];
    const float* W_l1 = (const float*)d_in[3];
    const float* b_l1 = (const float*)d_in[4];
    const float* W_r1 = (const float*)d_in[5];
    const float* W_l2 = (const float*)d_in[6];
    const float* b_l2 = (const float*)d_in[7];
    const float* W_r2 = (const float*)d_in[8];

    const int n  = in_sizes[0] / 128;
    const int E1 = in_sizes[1] / 2;
    const int E2 = in_sizes[2] / 2;

    // ws layout (all 16B-aligned for n*128 even):
    char* w = (char*)d_ws;
    u16* xb  = (u16*)w; w += (size_t)n * 128 * 2;   // x as bf16
    u16* hb  = (u16*)w; w += (size_t)n * 128 * 2;   // layer-1 output (bf16)
    u16* yb  = (u16*)w; w += (size_t)n * 128 * 2;   // x@W_l (bf16), reused layer 2 (n x 64)
    u16* agb = (u16*)w; w += (size_t)n * 128 * 2;   // gathered mean (bf16), reused (n x 64)
    u16* Pl1 = (u16*)w; w += 16384 * 2;
    u16* Pr1 = (u16*)w; w += 16384 * 2;
    u16* Pl2 = (u16*)w; w += 8192 * 2;
    u16* Pr2 = (u16*)w; w += 8192 * 2;
    int* rowptr  = (int*)w; w += (size_t)(n + 1) * 4;
    int* cursor  = (int*)w; w += (size_t)n * 4;
    int* partial = (int*)w; w += 1024 * 4;
    int* csr     = (int*)w;

    const int NB   = (n + 1023) / 1024;
    const int nb4  = (n + 3) / 4;
    const int gemb = ((n + 31) / 32 + 3) / 4;

    auto buildCSR = [&](const int* ei, int E) {
        hipMemsetAsync(rowptr, 0, (size_t)(n + 1) * sizeof(int), stream);
        hist_kernel<<<(E + 255) / 256, 256, 0, stream>>>(ei, E, rowptr);
        scan_p1<<<NB, 256, 0, stream>>>(rowptr, n, partial);
        scan_p2<<<1, 1, 0, stream>>>(partial, NB, rowptr, n);
        scan_p3<<<NB, 256, 0, stream>>>(rowptr, n, partial);
        hipMemsetAsync(cursor, 0, (size_t)n * sizeof(int), stream);
        fill_kernel<<<(E + 255) / 256, 256, 0, stream>>>(ei, E, rowptr, cursor, csr);
    };

    convert_bf16_kernel<<<((long)n * 128 / 8 + 255) / 256, 256, 0, stream>>>(x, xb, (long)n * 128);
    pack_weights<<<24, 256, 0, stream>>>(W_l1, W_r1, W_l2, W_r2, Pl1, Pr1, Pl2, Pr2);

    // layer 1
    buildCSR(ei1, E1);
    mfma_gemm<128, 0><<<gemb, 256, 0, stream>>>(xb, Pl1, nullptr, nullptr, yb, n);
    gather_kernel<128><<<nb4, 256, 0, stream>>>(yb, rowptr, csr, agb, n);
    mfma_gemm<128, 1><<<gemb, 256, 0, stream>>>(xb, Pr1, b_l1, agb, hb, n);

    // layer 2
    buildCSR(ei2, E2);
    mfma_gemm<64, 0><<<gemb, 256, 0, stream>>>(hb, Pl2, nullptr, nullptr, yb, n);
    gather_kernel<64><<<nb4, 256, 0, stream>>>(yb, rowptr, csr, agb, n);
    mfma_gemm<64, 2><<<gemb, 256, 0, stream>>>(hb, Pr2, b_l2, agb, d_out, n);
}

// Round 5
// 333.812 us; speedup vs baseline: 4.4100x; 1.4890x over previous
//
#include <hip/hip_runtime.h>
#include <hip/hip_bf16.h>

// GraphSAGE 2-layer forward on MI355X — MFMA + bucketed-CSR edition.
// mean(x[src]) @ W == mean((x@W)[src]) -> GEMMs at node granularity (bf16 MFMA,
// prepacked weight fragments); edge phase = CSR gather.
// Round-4 profile: fill_kernel wrote 73MB for a 4MB csr (16x line-granule
// amplification on random 4B scatter) + 2M random atomics. Fix: bucketed
// counting sort (512-node buckets) -> all scatters confined to L2-resident
// regions, atomics aggregated in LDS.

typedef __attribute__((ext_vector_type(8))) short bf16x8;
typedef __attribute__((ext_vector_type(4))) float f32x4;
typedef unsigned int u32;
typedef unsigned short u16;

constexpr int BSHIFT = 9;             // 512 nodes per bucket
constexpr int BNODES = 1 << BSHIFT;
constexpr int CHUNK  = 4096;          // edges per workgroup in bucket kernels
constexpr int EPT    = CHUNK / 256;   // 16 edges per thread

__device__ __forceinline__ u16 f2bf(float f) {
    u32 u = __float_as_uint(f);
    return (u16)((u + 0x7fffu + ((u >> 16) & 1u)) >> 16);
}
__device__ __forceinline__ float bf2f(u16 h) { return __uint_as_float((u32)h << 16); }

// ---------------- convert fp32 -> bf16, 8 elems/thread ----------------
__global__ __launch_bounds__(256) void convert_bf16_kernel(const float* __restrict__ in,
                                                           u16* __restrict__ out, long total) {
    long i = ((long)blockIdx.x * 256 + threadIdx.x) * 8;
    if (i >= total) return;
    float4 v0 = *reinterpret_cast<const float4*>(in + i);
    float4 v1 = *reinterpret_cast<const float4*>(in + i + 4);
    bf16x8 o;
    o[0] = (short)f2bf(v0.x); o[1] = (short)f2bf(v0.y);
    o[2] = (short)f2bf(v0.z); o[3] = (short)f2bf(v0.w);
    o[4] = (short)f2bf(v1.x); o[5] = (short)f2bf(v1.y);
    o[6] = (short)f2bf(v1.z); o[7] = (short)f2bf(v1.w);
    *reinterpret_cast<bf16x8*>(out + i) = o;
}

// -------- pack W[K=128][O] into MFMA B-fragment order (bf16) --------
__global__ __launch_bounds__(256) void pack_weights(const float* __restrict__ Wl1,
                                                    const float* __restrict__ Wr1,
                                                    const float* __restrict__ Wl2,
                                                    const float* __restrict__ Wr2,
                                                    u16* __restrict__ Pl1, u16* __restrict__ Pr1,
                                                    u16* __restrict__ Pl2, u16* __restrict__ Pr2) {
    int u = blockIdx.x * 256 + threadIdx.x;
    if (u >= 6144) return;
    const float* W; u16* P; int O;
    if (u < 2048)      { W = Wl1; P = Pl1; O = 128; }
    else if (u < 4096) { W = Wr1; P = Pr1; O = 128; u -= 2048; }
    else if (u < 5120) { W = Wl2; P = Pl2; O = 64;  u -= 4096; }
    else               { W = Wr2; P = Pr2; O = 64;  u -= 5120; }
    int lane = u & 63, t = u >> 6;
    int ntiles = O / 16;
    int ks = t / ntiles, nt = t % ntiles;
    int k0 = ks * 32 + (lane >> 4) * 8;
    int col = nt * 16 + (lane & 15);
    bf16x8 o;
#pragma unroll
    for (int j = 0; j < 8; ++j) o[j] = (short)f2bf(W[(size_t)(k0 + j) * O + col]);
    *reinterpret_cast<bf16x8*>(P + (size_t)u * 8) = o;
}

// ---------------- bucketed CSR build ----------------
// K0: per-WG LDS histogram of bucket sizes (nB <= 1024 buckets supported)
__global__ __launch_bounds__(256) void bucket_count(const int* __restrict__ ei, int E,
                                                    int nB, int* __restrict__ bcnt) {
    __shared__ int lcnt[1024];
    for (int i = threadIdx.x; i < nB; i += 256) lcnt[i] = 0;
    __syncthreads();
    const int base = blockIdx.x * CHUNK;
    const int end = min(base + CHUNK, E);
    for (int e = base + (int)threadIdx.x; e < end; e += 256)
        atomicAdd(&lcnt[ei[E + e] >> BSHIFT], 1);
    __syncthreads();
    for (int i = threadIdx.x; i < nB; i += 256)
        if (lcnt[i]) atomicAdd(&bcnt[i], lcnt[i]);
}

// K1: single-wave exclusive scan of bucket counts; init cursors; rowptr[n]=E
__global__ void bucket_scan(const int* __restrict__ bcnt, int nB,
                            int* __restrict__ bbase, int* __restrict__ bcur,
                            int* __restrict__ rowptr, int n, int E) {
    const int lane = threadIdx.x;           // 64 threads
    int run = 0;
    for (int r = 0; r < nB; r += 64) {
        int i = r + lane;
        int v = (i < nB) ? bcnt[i] : 0;
        int x = v;
#pragma unroll
        for (int off = 1; off < 64; off <<= 1) { int y = __shfl_up(x, off); if (lane >= off) x += y; }
        int excl = run + x - v;
        if (i < nB) { bbase[i] = excl; bcur[i] = excl; }
        run += __shfl(x, 63);
    }
    if (lane == 0) { bbase[nB] = run; rowptr[n] = E; }
}

// K2: partition edges into bucket-contiguous ebuf (packed: dstLocal<<23 | src)
__global__ __launch_bounds__(256) void bucket_partition(const int* __restrict__ ei, int E,
                                                        int nB, int* __restrict__ bcur,
                                                        u32* __restrict__ ebuf) {
    __shared__ int lcnt[1024];
    __shared__ int lbase[1024];
    for (int i = threadIdx.x; i < nB; i += 256) lcnt[i] = 0;
    __syncthreads();
    const int base = blockIdx.x * CHUNK;

    u32 pk[EPT]; int bk[EPT];
#pragma unroll
    for (int k = 0; k < EPT; ++k) {
        int e = base + (int)threadIdx.x + k * 256;
        if (e < E) {
            int s = ei[e], d = ei[E + e];
            bk[k] = d >> BSHIFT;
            pk[k] = ((u32)(d & (BNODES - 1)) << 23) | (u32)s;
            atomicAdd(&lcnt[bk[k]], 1);
        } else bk[k] = -1;
    }
    __syncthreads();
    for (int i = threadIdx.x; i < nB; i += 256) {
        int c = lcnt[i];
        lbase[i] = c ? atomicAdd(&bcur[i], c) : 0;
        lcnt[i] = 0;                           // reuse as local cursor
    }
    __syncthreads();
#pragma unroll
    for (int k = 0; k < EPT; ++k) {
        if (bk[k] >= 0) {
            int p = lbase[bk[k]] + atomicAdd(&lcnt[bk[k]], 1);
            ebuf[p] = pk[k];
        }
    }
}

// K3: one WG per bucket: per-node hist + scan in LDS -> rowptr + csr fill
__global__ __launch_bounds__(256) void bucket_build(const u32* __restrict__ ebuf,
                                                    const int* __restrict__ bbase,
                                                    int n, int* __restrict__ rowptr,
                                                    int* __restrict__ csr) {
    __shared__ int hist[BNODES];
    __shared__ int sstart[BNODES];
    __shared__ int spart[4];
    const int bkt = blockIdx.x;
    const int bb = bbase[bkt], be = bbase[bkt + 1];
    const int node0 = bkt << BSHIFT;

    for (int i = threadIdx.x; i < BNODES; i += 256) hist[i] = 0;
    __syncthreads();
    for (int e = bb + (int)threadIdx.x; e < be; e += 256)
        atomicAdd(&hist[ebuf[e] >> 23], 1);
    __syncthreads();

    // exclusive scan over 512 hist values (2 per thread)
    const int t = threadIdx.x;
    const int v0 = hist[2 * t], v1 = hist[2 * t + 1];
    const int ts = v0 + v1;
    const int lane = t & 63, wave = t >> 6;
    int x = ts;
#pragma unroll
    for (int off = 1; off < 64; off <<= 1) { int y = __shfl_up(x, off); if (lane >= off) x += y; }
    if (lane == 63) spart[wave] = x;
    __syncthreads();
    int woff = 0;
#pragma unroll
    for (int w = 0; w < 4; ++w) if (w < wave) woff += spart[w];
    const int excl = woff + x - ts;
    sstart[2 * t] = excl;
    sstart[2 * t + 1] = excl + v0;
    const int nd0 = node0 + 2 * t, nd1 = node0 + 2 * t + 1;
    if (nd0 < n) rowptr[nd0] = bb + excl;
    if (nd1 < n) rowptr[nd1] = bb + excl + v0;
    // reuse hist as per-node cursors
    for (int i = threadIdx.x; i < BNODES; i += 256) hist[i] = 0;
    __syncthreads();

    for (int e = bb + (int)threadIdx.x; e < be; e += 256) {
        u32 pkv = ebuf[e];
        int dl = pkv >> 23;
        int p = atomicAdd(&hist[dl], 1);
        csr[bb + sstart[dl] + p] = (int)(pkv & 0x7FFFFFu);
    }
}

// ---------------- MFMA GEMM with fused epilogues ----------------
// MODE 0: out = bf16(A@W); MODE 1: out = bf16(relu(A@W+bias+agg));
// MODE 2: out = f32(log_softmax(A@W+bias+agg)), O==64
template<int O, int MODE>
__global__ __launch_bounds__(256) void mfma_gemm(const u16* __restrict__ A,
                                                 const u16* __restrict__ Bp,
                                                 const float* __restrict__ bias,
                                                 const u16* __restrict__ agg,
                                                 void* __restrict__ outv, int n) {
    constexpr int NT = O / 16;
    const int wave = threadIdx.x >> 6, lane = threadIdx.x & 63;
    const int row0 = (blockIdx.x * 4 + wave) * 32;
    if (row0 >= n) return;
    const int lr = lane & 15, lg = lane >> 4;

    const int ra0 = min(row0 + lr, n - 1);
    const int ra1 = min(row0 + 16 + lr, n - 1);
    const bf16x8* A0 = reinterpret_cast<const bf16x8*>(A + (size_t)ra0 * 128);
    const bf16x8* A1 = reinterpret_cast<const bf16x8*>(A + (size_t)ra1 * 128);
    const bf16x8* B8 = reinterpret_cast<const bf16x8*>(Bp) + lane;

    f32x4 acc[2][NT];
#pragma unroll
    for (int i = 0; i < 2; ++i)
#pragma unroll
        for (int t = 0; t < NT; ++t) acc[i][t] = (f32x4){0.f, 0.f, 0.f, 0.f};

#pragma unroll
    for (int ks = 0; ks < 4; ++ks) {
        bf16x8 a0 = A0[ks * 4 + lg];
        bf16x8 a1 = A1[ks * 4 + lg];
#pragma unroll
        for (int t = 0; t < NT; ++t) {
            bf16x8 b = B8[(size_t)(ks * NT + t) * 64];
            acc[0][t] = __builtin_amdgcn_mfma_f32_16x16x32_bf16(a0, b, acc[0][t], 0, 0, 0);
            acc[1][t] = __builtin_amdgcn_mfma_f32_16x16x32_bf16(a1, b, acc[1][t], 0, 0, 0);
        }
    }

    // C/D layout (m89-verified): col = lane&15, row = (lane>>4)*4 + reg
    if (MODE == 2) {
        float* out = (float*)outv;
#pragma unroll
        for (int h = 0; h < 2; ++h) {
            float v[NT][4], m[4], s[4];
#pragma unroll
            for (int t = 0; t < NT; ++t) {
                float bv = bias[t * 16 + lr];
#pragma unroll
                for (int r = 0; r < 4; ++r) {
                    int row = min(row0 + h * 16 + lg * 4 + r, n - 1);
                    v[t][r] = acc[h][t][r] + bv + bf2f(agg[(size_t)row * O + t * 16 + lr]);
                }
            }
#pragma unroll
            for (int r = 0; r < 4; ++r)
                m[r] = fmaxf(fmaxf(v[0][r], v[1][r]), fmaxf(v[2][r], v[3][r]));
#pragma unroll
            for (int off = 1; off <= 8; off <<= 1)
#pragma unroll
                for (int r = 0; r < 4; ++r) m[r] = fmaxf(m[r], __shfl_xor(m[r], off));
#pragma unroll
            for (int r = 0; r < 4; ++r)
                s[r] = expf(v[0][r] - m[r]) + expf(v[1][r] - m[r]) +
                       expf(v[2][r] - m[r]) + expf(v[3][r] - m[r]);
#pragma unroll
            for (int off = 1; off <= 8; off <<= 1)
#pragma unroll
                for (int r = 0; r < 4; ++r) s[r] += __shfl_xor(s[r], off);
#pragma unroll
            for (int r = 0; r < 4; ++r) {
                float ls = logf(s[r]);
                int row = row0 + h * 16 + lg * 4 + r;
                if (row < n)
#pragma unroll
                    for (int t = 0; t < NT; ++t)
                        out[(size_t)row * O + t * 16 + lr] = v[t][r] - m[r] - ls;
            }
        }
    } else {
        u16* out = (u16*)outv;
#pragma unroll
        for (int h = 0; h < 2; ++h)
#pragma unroll
            for (int t = 0; t < NT; ++t) {
                float bv = (MODE == 1) ? bias[t * 16 + lr] : 0.f;
#pragma unroll
                for (int r = 0; r < 4; ++r) {
                    int row = row0 + h * 16 + lg * 4 + r;
                    if (row < n) {
                        float val = acc[h][t][r];
                        if (MODE == 1) {
                            val += bv + bf2f(agg[(size_t)row * O + t * 16 + lr]);
                            val = fmaxf(val, 0.f);
                        }
                        out[(size_t)row * O + t * 16 + lr] = f2bf(val);
                    }
                }
            }
    }
}

// ---------------- gather-reduce (bf16 rows, fp32 acc) ----------------
template<int D>
__global__ __launch_bounds__(256) void gather_kernel(const u16* __restrict__ y,
                                                     const int* __restrict__ rowptr,
                                                     const int* __restrict__ csr,
                                                     u16* __restrict__ agg, int n) {
    const int wave = threadIdx.x >> 6, lane = threadIdx.x & 63;
    const int node = blockIdx.x * 4 + wave;
    if (node >= n) return;
    const int start = rowptr[node], end = rowptr[node + 1];
    float acc0 = 0.f, acc1 = 0.f;
    for (int base = start; base < end; base += 64) {
        const int m = min(64, end - base);
        int s = (lane < m) ? csr[base + lane] : 0;
        for (int j = 0; j < m; ++j) {
            const int sj = __shfl(s, j);
            if (D == 128) {
                u32 v = *reinterpret_cast<const u32*>(y + (size_t)sj * 128 + lane * 2);
                acc0 += bf2f((u16)(v & 0xffffu));
                acc1 += bf2f((u16)(v >> 16));
            } else {
                acc0 += bf2f(y[(size_t)sj * 64 + lane]);
            }
        }
    }
    const float inv = 1.0f / fmaxf((float)(end - start), 1.0f);
    if (D == 128) {
        u32 o = (u32)f2bf(acc0 * inv) | ((u32)f2bf(acc1 * inv) << 16);
        *reinterpret_cast<u32*>(agg + (size_t)node * 128 + lane * 2) = o;
    } else {
        agg[(size_t)node * 64 + lane] = f2bf(acc0 * inv);
    }
}

extern "C" void kernel_launch(void* const* d_in, const int* in_sizes, int n_in,
                              void* d_out, int out_size, void* d_ws, size_t ws_size,
                              hipStream_t stream) {
    const float* x    = (const float*)d_in[0];
    const int*   ei1  = (const int*)d_in[1];
    const int*   ei2  = (const int*)d_in[2];
    const float* W_l1 = (const float*)d_in[3];
    const float* b_l1 = (const float*)d_in[4];
    const float* W_r1 = (const float*)d_in[5];
    const float* W_l2 = (const float*)d_in[6];
    const float* b_l2 = (const float*)d_in[7];
    const float* W_r2 = (const float*)d_in[8];

    const int n  = in_sizes[0] / 128;
    const int E1 = in_sizes[1] / 2;
    const int E2 = in_sizes[2] / 2;
    const int nB = (n + BNODES - 1) >> BSHIFT;   // <= 1024 (n <= 512k)

    // ws layout:
    char* w = (char*)d_ws;
    u16* xb  = (u16*)w; w += (size_t)n * 128 * 2;   // x as bf16
    u16* hb  = (u16*)w; w += (size_t)n * 128 * 2;   // layer-1 output (bf16)
    u16* yb  = (u16*)w; w += (size_t)n * 128 * 2;   // x@W_l (bf16); layer2: n x 64
    u16* agb = (u16*)w; w += (size_t)n * 128 * 2;   // gathered mean; ebuf aliases this
    u16* Pl1 = (u16*)w; w += 16384 * 2;
    u16* Pr1 = (u16*)w; w += 16384 * 2;
    u16* Pl2 = (u16*)w; w += 8192 * 2;
    u16* Pr2 = (u16*)w; w += 8192 * 2;
    int* rowptr = (int*)w; w += (size_t)(n + 1) * 4;
    int* bcnt   = (int*)w; w += 1024 * 4;
    int* bbase  = (int*)w; w += 1025 * 4;
    int* bcur   = (int*)w; w += 1024 * 4;
    int* csr    = (int*)w;
    // ebuf (E u32) aliases agb: dead once bucket_build finishes, before gather writes agb.
    u32* ebuf = (u32*)agb;

    const int nb4  = (n + 3) / 4;
    const int gemb = ((n + 31) / 32 + 3) / 4;

    auto buildCSR = [&](const int* ei, int E) {
        const int ng = (E + CHUNK - 1) / CHUNK;
        hipMemsetAsync(bcnt, 0, nB * sizeof(int), stream);
        bucket_count<<<ng, 256, 0, stream>>>(ei, E, nB, bcnt);
        bucket_scan<<<1, 64, 0, stream>>>(bcnt, nB, bbase, bcur, rowptr, n, E);
        bucket_partition<<<ng, 256, 0, stream>>>(ei, E, nB, bcur, ebuf);
        bucket_build<<<nB, 256, 0, stream>>>(ebuf, bbase, n, rowptr, csr);
    };

    convert_bf16_kernel<<<((long)n * 128 / 8 + 255) / 256, 256, 0, stream>>>(x, xb, (long)n * 128);
    pack_weights<<<24, 256, 0, stream>>>(W_l1, W_r1, W_l2, W_r2, Pl1, Pr1, Pl2, Pr2);

    // layer 1
    buildCSR(ei1, E1);
    mfma_gemm<128, 0><<<gemb, 256, 0, stream>>>(xb, Pl1, nullptr, nullptr, yb, n);
    gather_kernel<128><<<nb4, 256, 0, stream>>>(yb, rowptr, csr, agb, n);
    mfma_gemm<128, 1><<<gemb, 256, 0, stream>>>(xb, Pr1, b_l1, agb, hb, n);

    // layer 2
    buildCSR(ei2, E2);
    mfma_gemm<64, 0><<<gemb, 256, 0, stream>>>(hb, Pl2, nullptr, nullptr, yb, n);
    gather_kernel<64><<<nb4, 256, 0, stream>>>(yb, rowptr, csr, agb, n);
    mfma_gemm<64, 2><<<gemb, 256, 0, stream>>>(hb, Pr2, b_l2, agb, d_out, n);
}

// Round 6
// 275.475 us; speedup vs baseline: 5.3440x; 1.2118x over previous
//
#include <hip/hip_runtime.h>
#include <hip/hip_bf16.h>

// GraphSAGE 2-layer forward on MI355X — MFMA + bucketed-CSR + grouped gather.
// mean(x[src]) @ W == mean((x@W)[src]) -> GEMMs at node granularity (bf16 MFMA,
// prepacked weight fragments); edge phase = CSR gather.
// Round-5 profile: gather was latency-bound (scalar dword/edge serial chain,
// VALU 32%). Fix: lane-groups of D/8 process 4-8 edges concurrently with one
// uint4 (16B) load each; cross-group shfl_xor reduction at the end.

typedef __attribute__((ext_vector_type(8))) short bf16x8;
typedef __attribute__((ext_vector_type(4))) float f32x4;
typedef unsigned int u32;
typedef unsigned short u16;

constexpr int BSHIFT = 9;             // 512 nodes per bucket
constexpr int BNODES = 1 << BSHIFT;
constexpr int CHUNK  = 4096;          // edges per workgroup in bucket kernels
constexpr int EPT    = CHUNK / 256;   // 16 edges per thread

__device__ __forceinline__ u16 f2bf(float f) {
    u32 u = __float_as_uint(f);
    return (u16)((u + 0x7fffu + ((u >> 16) & 1u)) >> 16);
}
__device__ __forceinline__ float bf2f(u16 h) { return __uint_as_float((u32)h << 16); }
__device__ __forceinline__ void acc2(float& a0, float& a1, u32 u) {
    a0 += __uint_as_float(u << 16);
    a1 += __uint_as_float(u & 0xffff0000u);
}

// ---------------- convert fp32 -> bf16, 8 elems/thread ----------------
__global__ __launch_bounds__(256) void convert_bf16_kernel(const float* __restrict__ in,
                                                           u16* __restrict__ out, long total) {
    long i = ((long)blockIdx.x * 256 + threadIdx.x) * 8;
    if (i >= total) return;
    float4 v0 = *reinterpret_cast<const float4*>(in + i);
    float4 v1 = *reinterpret_cast<const float4*>(in + i + 4);
    bf16x8 o;
    o[0] = (short)f2bf(v0.x); o[1] = (short)f2bf(v0.y);
    o[2] = (short)f2bf(v0.z); o[3] = (short)f2bf(v0.w);
    o[4] = (short)f2bf(v1.x); o[5] = (short)f2bf(v1.y);
    o[6] = (short)f2bf(v1.z); o[7] = (short)f2bf(v1.w);
    *reinterpret_cast<bf16x8*>(out + i) = o;
}

// -------- pack W[K=128][O] into MFMA B-fragment order (bf16) --------
__global__ __launch_bounds__(256) void pack_weights(const float* __restrict__ Wl1,
                                                    const float* __restrict__ Wr1,
                                                    const float* __restrict__ Wl2,
                                                    const float* __restrict__ Wr2,
                                                    u16* __restrict__ Pl1, u16* __restrict__ Pr1,
                                                    u16* __restrict__ Pl2, u16* __restrict__ Pr2) {
    int u = blockIdx.x * 256 + threadIdx.x;
    if (u >= 6144) return;
    const float* W; u16* P; int O;
    if (u < 2048)      { W = Wl1; P = Pl1; O = 128; }
    else if (u < 4096) { W = Wr1; P = Pr1; O = 128; u -= 2048; }
    else if (u < 5120) { W = Wl2; P = Pl2; O = 64;  u -= 4096; }
    else               { W = Wr2; P = Pr2; O = 64;  u -= 5120; }
    int lane = u & 63, t = u >> 6;
    int ntiles = O / 16;
    int ks = t / ntiles, nt = t % ntiles;
    int k0 = ks * 32 + (lane >> 4) * 8;
    int col = nt * 16 + (lane & 15);
    bf16x8 o;
#pragma unroll
    for (int j = 0; j < 8; ++j) o[j] = (short)f2bf(W[(size_t)(k0 + j) * O + col]);
    *reinterpret_cast<bf16x8*>(P + (size_t)u * 8) = o;
}

// ---------------- bucketed CSR build (proven round 5) ----------------
__global__ __launch_bounds__(256) void bucket_count(const int* __restrict__ ei, int E,
                                                    int nB, int* __restrict__ bcnt) {
    __shared__ int lcnt[1024];
    for (int i = threadIdx.x; i < nB; i += 256) lcnt[i] = 0;
    __syncthreads();
    const int base = blockIdx.x * CHUNK;
    const int end = min(base + CHUNK, E);
    for (int e = base + (int)threadIdx.x; e < end; e += 256)
        atomicAdd(&lcnt[ei[E + e] >> BSHIFT], 1);
    __syncthreads();
    for (int i = threadIdx.x; i < nB; i += 256)
        if (lcnt[i]) atomicAdd(&bcnt[i], lcnt[i]);
}

__global__ void bucket_scan(const int* __restrict__ bcnt, int nB,
                            int* __restrict__ bbase, int* __restrict__ bcur,
                            int* __restrict__ rowptr, int n, int E) {
    const int lane = threadIdx.x;           // 64 threads
    int run = 0;
    for (int r = 0; r < nB; r += 64) {
        int i = r + lane;
        int v = (i < nB) ? bcnt[i] : 0;
        int x = v;
#pragma unroll
        for (int off = 1; off < 64; off <<= 1) { int y = __shfl_up(x, off); if (lane >= off) x += y; }
        int excl = run + x - v;
        if (i < nB) { bbase[i] = excl; bcur[i] = excl; }
        run += __shfl(x, 63);
    }
    if (lane == 0) { bbase[nB] = run; rowptr[n] = E; }
}

__global__ __launch_bounds__(256) void bucket_partition(const int* __restrict__ ei, int E,
                                                        int nB, int* __restrict__ bcur,
                                                        u32* __restrict__ ebuf) {
    __shared__ int lcnt[1024];
    __shared__ int lbase[1024];
    for (int i = threadIdx.x; i < nB; i += 256) lcnt[i] = 0;
    __syncthreads();
    const int base = blockIdx.x * CHUNK;

    u32 pk[EPT]; int bk[EPT];
#pragma unroll
    for (int k = 0; k < EPT; ++k) {
        int e = base + (int)threadIdx.x + k * 256;
        if (e < E) {
            int s = ei[e], d = ei[E + e];
            bk[k] = d >> BSHIFT;
            pk[k] = ((u32)(d & (BNODES - 1)) << 23) | (u32)s;
            atomicAdd(&lcnt[bk[k]], 1);
        } else bk[k] = -1;
    }
    __syncthreads();
    for (int i = threadIdx.x; i < nB; i += 256) {
        int c = lcnt[i];
        lbase[i] = c ? atomicAdd(&bcur[i], c) : 0;
        lcnt[i] = 0;                           // reuse as local cursor
    }
    __syncthreads();
#pragma unroll
    for (int k = 0; k < EPT; ++k) {
        if (bk[k] >= 0) {
            int p = lbase[bk[k]] + atomicAdd(&lcnt[bk[k]], 1);
            ebuf[p] = pk[k];
        }
    }
}

__global__ __launch_bounds__(256) void bucket_build(const u32* __restrict__ ebuf,
                                                    const int* __restrict__ bbase,
                                                    int n, int* __restrict__ rowptr,
                                                    int* __restrict__ csr) {
    __shared__ int hist[BNODES];
    __shared__ int sstart[BNODES];
    __shared__ int spart[4];
    const int bkt = blockIdx.x;
    const int bb = bbase[bkt], be = bbase[bkt + 1];
    const int node0 = bkt << BSHIFT;

    for (int i = threadIdx.x; i < BNODES; i += 256) hist[i] = 0;
    __syncthreads();
    for (int e = bb + (int)threadIdx.x; e < be; e += 256)
        atomicAdd(&hist[ebuf[e] >> 23], 1);
    __syncthreads();

    const int t = threadIdx.x;
    const int v0 = hist[2 * t], v1 = hist[2 * t + 1];
    const int ts = v0 + v1;
    const int lane = t & 63, wave = t >> 6;
    int x = ts;
#pragma unroll
    for (int off = 1; off < 64; off <<= 1) { int y = __shfl_up(x, off); if (lane >= off) x += y; }
    if (lane == 63) spart[wave] = x;
    __syncthreads();
    int woff = 0;
#pragma unroll
    for (int w = 0; w < 4; ++w) if (w < wave) woff += spart[w];
    const int excl = woff + x - ts;
    sstart[2 * t] = excl;
    sstart[2 * t + 1] = excl + v0;
    const int nd0 = node0 + 2 * t, nd1 = node0 + 2 * t + 1;
    if (nd0 < n) rowptr[nd0] = bb + excl;
    if (nd1 < n) rowptr[nd1] = bb + excl + v0;
    for (int i = threadIdx.x; i < BNODES; i += 256) hist[i] = 0;
    __syncthreads();

    for (int e = bb + (int)threadIdx.x; e < be; e += 256) {
        u32 pkv = ebuf[e];
        int dl = pkv >> 23;
        int p = atomicAdd(&hist[dl], 1);
        csr[bb + sstart[dl] + p] = (int)(pkv & 0x7FFFFFu);
    }
}

// ---------------- MFMA GEMM with fused epilogues ----------------
// MODE 0: out = bf16(A@W); MODE 1: out = bf16(relu(A@W+bias+agg));
// MODE 2: out = f32(log_softmax(A@W+bias+agg)), O==64
template<int O, int MODE>
__global__ __launch_bounds__(256) void mfma_gemm(const u16* __restrict__ A,
                                                 const u16* __restrict__ Bp,
                                                 const float* __restrict__ bias,
                                                 const u16* __restrict__ agg,
                                                 void* __restrict__ outv, int n) {
    constexpr int NT = O / 16;
    const int wave = threadIdx.x >> 6, lane = threadIdx.x & 63;
    const int row0 = (blockIdx.x * 4 + wave) * 32;
    if (row0 >= n) return;
    const int lr = lane & 15, lg = lane >> 4;

    const int ra0 = min(row0 + lr, n - 1);
    const int ra1 = min(row0 + 16 + lr, n - 1);
    const bf16x8* A0 = reinterpret_cast<const bf16x8*>(A + (size_t)ra0 * 128);
    const bf16x8* A1 = reinterpret_cast<const bf16x8*>(A + (size_t)ra1 * 128);
    const bf16x8* B8 = reinterpret_cast<const bf16x8*>(Bp) + lane;

    f32x4 acc[2][NT];
#pragma unroll
    for (int i = 0; i < 2; ++i)
#pragma unroll
        for (int t = 0; t < NT; ++t) acc[i][t] = (f32x4){0.f, 0.f, 0.f, 0.f};

#pragma unroll
    for (int ks = 0; ks < 4; ++ks) {
        bf16x8 a0 = A0[ks * 4 + lg];
        bf16x8 a1 = A1[ks * 4 + lg];
#pragma unroll
        for (int t = 0; t < NT; ++t) {
            bf16x8 b = B8[(size_t)(ks * NT + t) * 64];
            acc[0][t] = __builtin_amdgcn_mfma_f32_16x16x32_bf16(a0, b, acc[0][t], 0, 0, 0);
            acc[1][t] = __builtin_amdgcn_mfma_f32_16x16x32_bf16(a1, b, acc[1][t], 0, 0, 0);
        }
    }

    // C/D layout (m89-verified): col = lane&15, row = (lane>>4)*4 + reg
    if (MODE == 2) {
        float* out = (float*)outv;
#pragma unroll
        for (int h = 0; h < 2; ++h) {
            float v[NT][4], m[4], s[4];
#pragma unroll
            for (int t = 0; t < NT; ++t) {
                float bv = bias[t * 16 + lr];
#pragma unroll
                for (int r = 0; r < 4; ++r) {
                    int row = min(row0 + h * 16 + lg * 4 + r, n - 1);
                    v[t][r] = acc[h][t][r] + bv + bf2f(agg[(size_t)row * O + t * 16 + lr]);
                }
            }
#pragma unroll
            for (int r = 0; r < 4; ++r)
                m[r] = fmaxf(fmaxf(v[0][r], v[1][r]), fmaxf(v[2][r], v[3][r]));
#pragma unroll
            for (int off = 1; off <= 8; off <<= 1)
#pragma unroll
                for (int r = 0; r < 4; ++r) m[r] = fmaxf(m[r], __shfl_xor(m[r], off));
#pragma unroll
            for (int r = 0; r < 4; ++r)
                s[r] = expf(v[0][r] - m[r]) + expf(v[1][r] - m[r]) +
                       expf(v[2][r] - m[r]) + expf(v[3][r] - m[r]);
#pragma unroll
            for (int off = 1; off <= 8; off <<= 1)
#pragma unroll
                for (int r = 0; r < 4; ++r) s[r] += __shfl_xor(s[r], off);
#pragma unroll
            for (int r = 0; r < 4; ++r) {
                float ls = logf(s[r]);
                int row = row0 + h * 16 + lg * 4 + r;
                if (row < n)
#pragma unroll
                    for (int t = 0; t < NT; ++t)
                        out[(size_t)row * O + t * 16 + lr] = v[t][r] - m[r] - ls;
            }
        }
    } else {
        u16* out = (u16*)outv;
#pragma unroll
        for (int h = 0; h < 2; ++h)
#pragma unroll
            for (int t = 0; t < NT; ++t) {
                float bv = (MODE == 1) ? bias[t * 16 + lr] : 0.f;
#pragma unroll
                for (int r = 0; r < 4; ++r) {
                    int row = row0 + h * 16 + lg * 4 + r;
                    if (row < n) {
                        float val = acc[h][t][r];
                        if (MODE == 1) {
                            val += bv + bf2f(agg[(size_t)row * O + t * 16 + lr]);
                            val = fmaxf(val, 0.f);
                        }
                        out[(size_t)row * O + t * 16 + lr] = f2bf(val);
                    }
                }
            }
    }
}

// ------- gather-reduce, lane-group edition: group of D/8 lanes per edge -------
// Each lane loads uint4 = 8 bf16 dims of one row; NG=64/(D/8) edges in flight.
template<int D>
__global__ __launch_bounds__(256) void gather_kernel(const u16* __restrict__ y,
                                                     const int* __restrict__ rowptr,
                                                     const int* __restrict__ csr,
                                                     u16* __restrict__ agg, int n) {
    constexpr int LSZ = D / 8;        // lanes per row (16 for D=128, 8 for D=64)
    constexpr int NG  = 64 / LSZ;     // concurrent edges per wave
    const int wave = threadIdx.x >> 6, lane = threadIdx.x & 63;
    const int node = blockIdx.x * 4 + wave;
    if (node >= n) return;
    const int start = rowptr[node], end = rowptr[node + 1];
    const int l = lane & (LSZ - 1), g = lane / LSZ;

    float a0 = 0.f, a1 = 0.f, a2 = 0.f, a3 = 0.f, a4 = 0.f, a5 = 0.f, a6 = 0.f, a7 = 0.f;

    for (int base = start; base < end; base += 64) {
        const int m = min(64, end - base);
        int s = (lane < m) ? csr[base + lane] : 0;
        const int iters = (m + NG - 1) / NG;
#pragma unroll 2
        for (int j = 0; j < iters; ++j) {
            const int eidx = j * NG + g;
            const int sj = __shfl(s, eidx);      // per-lane src index (ds_bpermute)
            if (eidx < m) {
                uint4 v = *reinterpret_cast<const uint4*>(y + (size_t)sj * D + l * 8);
                acc2(a0, a1, v.x);
                acc2(a2, a3, v.y);
                acc2(a4, a5, v.z);
                acc2(a6, a7, v.w);
            }
        }
    }

    // fold the NG group partials (dims are lane-aligned across groups)
#pragma unroll
    for (int off = LSZ; off < 64; off <<= 1) {
        a0 += __shfl_xor(a0, off); a1 += __shfl_xor(a1, off);
        a2 += __shfl_xor(a2, off); a3 += __shfl_xor(a3, off);
        a4 += __shfl_xor(a4, off); a5 += __shfl_xor(a5, off);
        a6 += __shfl_xor(a6, off); a7 += __shfl_xor(a7, off);
    }

    if (g == 0) {
        const float inv = 1.0f / fmaxf((float)(end - start), 1.0f);
        uint4 o;
        o.x = (u32)f2bf(a0 * inv) | ((u32)f2bf(a1 * inv) << 16);
        o.y = (u32)f2bf(a2 * inv) | ((u32)f2bf(a3 * inv) << 16);
        o.z = (u32)f2bf(a4 * inv) | ((u32)f2bf(a5 * inv) << 16);
        o.w = (u32)f2bf(a6 * inv) | ((u32)f2bf(a7 * inv) << 16);
        *reinterpret_cast<uint4*>(agg + (size_t)node * D + l * 8) = o;
    }
}

extern "C" void kernel_launch(void* const* d_in, const int* in_sizes, int n_in,
                              void* d_out, int out_size, void* d_ws, size_t ws_size,
                              hipStream_t stream) {
    const float* x    = (const float*)d_in[0];
    const int*   ei1  = (const int*)d_in[1];
    const int*   ei2  = (const int*)d_in[2];
    const float* W_l1 = (const float*)d_in[3];
    const float* b_l1 = (const float*)d_in[4];
    const float* W_r1 = (const float*)d_in[5];
    const float* W_l2 = (const float*)d_in[6];
    const float* b_l2 = (const float*)d_in[7];
    const float* W_r2 = (const float*)d_in[8];

    const int n  = in_sizes[0] / 128;
    const int E1 = in_sizes[1] / 2;
    const int E2 = in_sizes[2] / 2;
    const int nB = (n + BNODES - 1) >> BSHIFT;   // <= 1024 (n <= 512k)

    // ws layout:
    char* w = (char*)d_ws;
    u16* xb  = (u16*)w; w += (size_t)n * 128 * 2;   // x as bf16
    u16* hb  = (u16*)w; w += (size_t)n * 128 * 2;   // layer-1 output (bf16)
    u16* yb  = (u16*)w; w += (size_t)n * 128 * 2;   // x@W_l (bf16); layer2: n x 64
    u16* agb = (u16*)w; w += (size_t)n * 128 * 2;   // gathered mean; ebuf aliases this
    u16* Pl1 = (u16*)w; w += 16384 * 2;
    u16* Pr1 = (u16*)w; w += 16384 * 2;
    u16* Pl2 = (u16*)w; w += 8192 * 2;
    u16* Pr2 = (u16*)w; w += 8192 * 2;
    int* rowptr = (int*)w; w += (size_t)(n + 1) * 4;
    int* bcnt   = (int*)w; w += 1024 * 4;
    int* bbase  = (int*)w; w += 1025 * 4;
    int* bcur   = (int*)w; w += 1024 * 4;
    int* csr    = (int*)w;
    // ebuf (E u32) aliases agb: dead once bucket_build finishes, before gather writes agb.
    u32* ebuf = (u32*)agb;

    const int nb4  = (n + 3) / 4;
    const int gemb = ((n + 31) / 32 + 3) / 4;

    auto buildCSR = [&](const int* ei, int E) {
        const int ng = (E + CHUNK - 1) / CHUNK;
        hipMemsetAsync(bcnt, 0, nB * sizeof(int), stream);
        bucket_count<<<ng, 256, 0, stream>>>(ei, E, nB, bcnt);
        bucket_scan<<<1, 64, 0, stream>>>(bcnt, nB, bbase, bcur, rowptr, n, E);
        bucket_partition<<<ng, 256, 0, stream>>>(ei, E, nB, bcur, ebuf);
        bucket_build<<<nB, 256, 0, stream>>>(ebuf, bbase, n, rowptr, csr);
    };

    convert_bf16_kernel<<<((long)n * 128 / 8 + 255) / 256, 256, 0, stream>>>(x, xb, (long)n * 128);
    pack_weights<<<24, 256, 0, stream>>>(W_l1, W_r1, W_l2, W_r2, Pl1, Pr1, Pl2, Pr2);

    // layer 1
    buildCSR(ei1, E1);
    mfma_gemm<128, 0><<<gemb, 256, 0, stream>>>(xb, Pl1, nullptr, nullptr, yb, n);
    gather_kernel<128><<<nb4, 256, 0, stream>>>(yb, rowptr, csr, agb, n);
    mfma_gemm<128, 1><<<gemb, 256, 0, stream>>>(xb, Pr1, b_l1, agb, hb, n);

    // layer 2
    buildCSR(ei2, E2);
    mfma_gemm<64, 0><<<gemb, 256, 0, stream>>>(hb, Pl2, nullptr, nullptr, yb, n);
    gather_kernel<64><<<nb4, 256, 0, stream>>>(yb, rowptr, csr, agb, n);
    mfma_gemm<64, 2><<<gemb, 256, 0, stream>>>(hb, Pr2, b_l2, agb, d_out, n);
}

// Round 7
// 257.065 us; speedup vs baseline: 5.7267x; 1.0716x over previous
//
#include <hip/hip_runtime.h>
#include <hip/hip_bf16.h>

// GraphSAGE 2-layer forward on MI355X — MFMA + bucketed-CSR + per-group gather.
// mean(x[src]) @ W == mean((x@W)[src]) -> GEMMs at node granularity (bf16 MFMA,
// prepacked weight fragments); edge phase = CSR gather.
// Round-6 profile: gather 47us @ VALU 54% / HBM 38% — epilogue shfl_xor +
// bpermute broadcast ~35% of VALU. Fix: one node per lane-group (group reads
// its own csr, no cross-group reduce), unroll-2 MLP, float2 pk accumulate.

typedef __attribute__((ext_vector_type(8))) short bf16x8;
typedef __attribute__((ext_vector_type(4))) float f32x4;
typedef unsigned int u32;
typedef unsigned short u16;

constexpr int BSHIFT = 9;             // 512 nodes per bucket
constexpr int BNODES = 1 << BSHIFT;
constexpr int CHUNK  = 4096;          // edges per workgroup in bucket kernels
constexpr int EPT    = CHUNK / 256;   // 16 edges per thread

__device__ __forceinline__ u16 f2bf(float f) {
    u32 u = __float_as_uint(f);
    return (u16)((u + 0x7fffu + ((u >> 16) & 1u)) >> 16);
}
__device__ __forceinline__ float bf2f(u16 h) { return __uint_as_float((u32)h << 16); }
__device__ __forceinline__ void accp(float2& a, u32 u) {
    a.x += __uint_as_float(u << 16);
    a.y += __uint_as_float(u & 0xffff0000u);
}

// ---------------- prep: fused weight-pack (blocks 0..23) + x->bf16 convert ----------------
__global__ __launch_bounds__(256) void prep_kernel(const float* __restrict__ x, long total,
                                                   const float* __restrict__ Wl1,
                                                   const float* __restrict__ Wr1,
                                                   const float* __restrict__ Wl2,
                                                   const float* __restrict__ Wr2,
                                                   u16* __restrict__ xb,
                                                   u16* __restrict__ Pl1, u16* __restrict__ Pr1,
                                                   u16* __restrict__ Pl2, u16* __restrict__ Pr2) {
    if (blockIdx.x < 24) {
        // pack W[K=128][O] into MFMA B-fragment order:
        // unit u -> elem j = W[ks*32 + (lane>>4)*8 + j][nt*16 + (lane&15)]
        int u = blockIdx.x * 256 + threadIdx.x;
        if (u >= 6144) return;
        const float* W; u16* P; int O;
        if (u < 2048)      { W = Wl1; P = Pl1; O = 128; }
        else if (u < 4096) { W = Wr1; P = Pr1; O = 128; u -= 2048; }
        else if (u < 5120) { W = Wl2; P = Pl2; O = 64;  u -= 4096; }
        else               { W = Wr2; P = Pr2; O = 64;  u -= 5120; }
        int lane = u & 63, t = u >> 6;
        int ntiles = O / 16;
        int ks = t / ntiles, nt = t % ntiles;
        int k0 = ks * 32 + (lane >> 4) * 8;
        int col = nt * 16 + (lane & 15);
        bf16x8 o;
#pragma unroll
        for (int j = 0; j < 8; ++j) o[j] = (short)f2bf(W[(size_t)(k0 + j) * O + col]);
        *reinterpret_cast<bf16x8*>(P + (size_t)u * 8) = o;
    } else {
        long i = ((long)(blockIdx.x - 24) * 256 + threadIdx.x) * 8;
        if (i >= total) return;
        float4 v0 = *reinterpret_cast<const float4*>(x + i);
        float4 v1 = *reinterpret_cast<const float4*>(x + i + 4);
        bf16x8 o;
        o[0] = (short)f2bf(v0.x); o[1] = (short)f2bf(v0.y);
        o[2] = (short)f2bf(v0.z); o[3] = (short)f2bf(v0.w);
        o[4] = (short)f2bf(v1.x); o[5] = (short)f2bf(v1.y);
        o[6] = (short)f2bf(v1.z); o[7] = (short)f2bf(v1.w);
        *reinterpret_cast<bf16x8*>(xb + i) = o;
    }
}

// ---------------- bucketed CSR build (proven round 5) ----------------
__global__ __launch_bounds__(256) void bucket_count(const int* __restrict__ ei, int E,
                                                    int nB, int* __restrict__ bcnt) {
    __shared__ int lcnt[1024];
    for (int i = threadIdx.x; i < nB; i += 256) lcnt[i] = 0;
    __syncthreads();
    const int base = blockIdx.x * CHUNK;
    const int end = min(base + CHUNK, E);
    for (int e = base + (int)threadIdx.x; e < end; e += 256)
        atomicAdd(&lcnt[ei[E + e] >> BSHIFT], 1);
    __syncthreads();
    for (int i = threadIdx.x; i < nB; i += 256)
        if (lcnt[i]) atomicAdd(&bcnt[i], lcnt[i]);
}

__global__ void bucket_scan(const int* __restrict__ bcnt, int nB,
                            int* __restrict__ bbase, int* __restrict__ bcur,
                            int* __restrict__ rowptr, int n, int E) {
    const int lane = threadIdx.x;           // 64 threads
    int run = 0;
    for (int r = 0; r < nB; r += 64) {
        int i = r + lane;
        int v = (i < nB) ? bcnt[i] : 0;
        int x = v;
#pragma unroll
        for (int off = 1; off < 64; off <<= 1) { int y = __shfl_up(x, off); if (lane >= off) x += y; }
        int excl = run + x - v;
        if (i < nB) { bbase[i] = excl; bcur[i] = excl; }
        run += __shfl(x, 63);
    }
    if (lane == 0) { bbase[nB] = run; rowptr[n] = E; }
}

__global__ __launch_bounds__(256) void bucket_partition(const int* __restrict__ ei, int E,
                                                        int nB, int* __restrict__ bcur,
                                                        u32* __restrict__ ebuf) {
    __shared__ int lcnt[1024];
    __shared__ int lbase[1024];
    for (int i = threadIdx.x; i < nB; i += 256) lcnt[i] = 0;
    __syncthreads();
    const int base = blockIdx.x * CHUNK;

    u32 pk[EPT]; int bk[EPT];
#pragma unroll
    for (int k = 0; k < EPT; ++k) {
        int e = base + (int)threadIdx.x + k * 256;
        if (e < E) {
            int s = ei[e], d = ei[E + e];
            bk[k] = d >> BSHIFT;
            pk[k] = ((u32)(d & (BNODES - 1)) << 23) | (u32)s;
            atomicAdd(&lcnt[bk[k]], 1);
        } else bk[k] = -1;
    }
    __syncthreads();
    for (int i = threadIdx.x; i < nB; i += 256) {
        int c = lcnt[i];
        lbase[i] = c ? atomicAdd(&bcur[i], c) : 0;
        lcnt[i] = 0;                           // reuse as local cursor
    }
    __syncthreads();
#pragma unroll
    for (int k = 0; k < EPT; ++k) {
        if (bk[k] >= 0) {
            int p = lbase[bk[k]] + atomicAdd(&lcnt[bk[k]], 1);
            ebuf[p] = pk[k];
        }
    }
}

__global__ __launch_bounds__(256) void bucket_build(const u32* __restrict__ ebuf,
                                                    const int* __restrict__ bbase,
                                                    int n, int* __restrict__ rowptr,
                                                    int* __restrict__ csr) {
    __shared__ int hist[BNODES];
    __shared__ int sstart[BNODES];
    __shared__ int spart[4];
    const int bkt = blockIdx.x;
    const int bb = bbase[bkt], be = bbase[bkt + 1];
    const int node0 = bkt << BSHIFT;

    for (int i = threadIdx.x; i < BNODES; i += 256) hist[i] = 0;
    __syncthreads();
    for (int e = bb + (int)threadIdx.x; e < be; e += 256)
        atomicAdd(&hist[ebuf[e] >> 23], 1);
    __syncthreads();

    const int t = threadIdx.x;
    const int v0 = hist[2 * t], v1 = hist[2 * t + 1];
    const int ts = v0 + v1;
    const int lane = t & 63, wave = t >> 6;
    int x = ts;
#pragma unroll
    for (int off = 1; off < 64; off <<= 1) { int y = __shfl_up(x, off); if (lane >= off) x += y; }
    if (lane == 63) spart[wave] = x;
    __syncthreads();
    int woff = 0;
#pragma unroll
    for (int w = 0; w < 4; ++w) if (w < wave) woff += spart[w];
    const int excl = woff + x - ts;
    sstart[2 * t] = excl;
    sstart[2 * t + 1] = excl + v0;
    const int nd0 = node0 + 2 * t, nd1 = node0 + 2 * t + 1;
    if (nd0 < n) rowptr[nd0] = bb + excl;
    if (nd1 < n) rowptr[nd1] = bb + excl + v0;
    for (int i = threadIdx.x; i < BNODES; i += 256) hist[i] = 0;
    __syncthreads();

    for (int e = bb + (int)threadIdx.x; e < be; e += 256) {
        u32 pkv = ebuf[e];
        int dl = pkv >> 23;
        int p = atomicAdd(&hist[dl], 1);
        csr[bb + sstart[dl] + p] = (int)(pkv & 0x7FFFFFu);
    }
}

// ---------------- MFMA GEMM with fused epilogues ----------------
// MODE 0: out = bf16(A@W); MODE 1: out = bf16(relu(A@W+bias+agg));
// MODE 2: out = f32(log_softmax(A@W+bias+agg)), O==64
template<int O, int MODE>
__global__ __launch_bounds__(256) void mfma_gemm(const u16* __restrict__ A,
                                                 const u16* __restrict__ Bp,
                                                 const float* __restrict__ bias,
                                                 const u16* __restrict__ agg,
                                                 void* __restrict__ outv, int n) {
    constexpr int NT = O / 16;
    const int wave = threadIdx.x >> 6, lane = threadIdx.x & 63;
    const int row0 = (blockIdx.x * 4 + wave) * 32;
    if (row0 >= n) return;
    const int lr = lane & 15, lg = lane >> 4;

    const int ra0 = min(row0 + lr, n - 1);
    const int ra1 = min(row0 + 16 + lr, n - 1);
    const bf16x8* A0 = reinterpret_cast<const bf16x8*>(A + (size_t)ra0 * 128);
    const bf16x8* A1 = reinterpret_cast<const bf16x8*>(A + (size_t)ra1 * 128);
    const bf16x8* B8 = reinterpret_cast<const bf16x8*>(Bp) + lane;

    f32x4 acc[2][NT];
#pragma unroll
    for (int i = 0; i < 2; ++i)
#pragma unroll
        for (int t = 0; t < NT; ++t) acc[i][t] = (f32x4){0.f, 0.f, 0.f, 0.f};

#pragma unroll
    for (int ks = 0; ks < 4; ++ks) {
        bf16x8 a0 = A0[ks * 4 + lg];
        bf16x8 a1 = A1[ks * 4 + lg];
#pragma unroll
        for (int t = 0; t < NT; ++t) {
            bf16x8 b = B8[(size_t)(ks * NT + t) * 64];
            acc[0][t] = __builtin_amdgcn_mfma_f32_16x16x32_bf16(a0, b, acc[0][t], 0, 0, 0);
            acc[1][t] = __builtin_amdgcn_mfma_f32_16x16x32_bf16(a1, b, acc[1][t], 0, 0, 0);
        }
    }

    // C/D layout (m89-verified): col = lane&15, row = (lane>>4)*4 + reg
    if (MODE == 2) {
        float* out = (float*)outv;
#pragma unroll
        for (int h = 0; h < 2; ++h) {
            float v[NT][4], m[4], s[4];
#pragma unroll
            for (int t = 0; t < NT; ++t) {
                float bv = bias[t * 16 + lr];
#pragma unroll
                for (int r = 0; r < 4; ++r) {
                    int row = min(row0 + h * 16 + lg * 4 + r, n - 1);
                    v[t][r] = acc[h][t][r] + bv + bf2f(agg[(size_t)row * O + t * 16 + lr]);
                }
            }
#pragma unroll
            for (int r = 0; r < 4; ++r)
                m[r] = fmaxf(fmaxf(v[0][r], v[1][r]), fmaxf(v[2][r], v[3][r]));
#pragma unroll
            for (int off = 1; off <= 8; off <<= 1)
#pragma unroll
                for (int r = 0; r < 4; ++r) m[r] = fmaxf(m[r], __shfl_xor(m[r], off));
#pragma unroll
            for (int r = 0; r < 4; ++r)
                s[r] = expf(v[0][r] - m[r]) + expf(v[1][r] - m[r]) +
                       expf(v[2][r] - m[r]) + expf(v[3][r] - m[r]);
#pragma unroll
            for (int off = 1; off <= 8; off <<= 1)
#pragma unroll
                for (int r = 0; r < 4; ++r) s[r] += __shfl_xor(s[r], off);
#pragma unroll
            for (int r = 0; r < 4; ++r) {
                float ls = logf(s[r]);
                int row = row0 + h * 16 + lg * 4 + r;
                if (row < n)
#pragma unroll
                    for (int t = 0; t < NT; ++t)
                        out[(size_t)row * O + t * 16 + lr] = v[t][r] - m[r] - ls;
            }
        }
    } else {
        u16* out = (u16*)outv;
#pragma unroll
        for (int h = 0; h < 2; ++h)
#pragma unroll
            for (int t = 0; t < NT; ++t) {
                float bv = (MODE == 1) ? bias[t * 16 + lr] : 0.f;
#pragma unroll
                for (int r = 0; r < 4; ++r) {
                    int row = row0 + h * 16 + lg * 4 + r;
                    if (row < n) {
                        float val = acc[h][t][r];
                        if (MODE == 1) {
                            val += bv + bf2f(agg[(size_t)row * O + t * 16 + lr]);
                            val = fmaxf(val, 0.f);
                        }
                        out[(size_t)row * O + t * 16 + lr] = f2bf(val);
                    }
                }
            }
    }
}

// ------- gather-reduce, node-per-group: group of D/8 lanes owns ONE node -------
// Group reads its own csr entries (same-address within group), unroll-2 for MLP,
// no cross-group reduction, direct uint4 store.
template<int D>
__global__ __launch_bounds__(256) void gather_kernel(const u16* __restrict__ y,
                                                     const int* __restrict__ rowptr,
                                                     const int* __restrict__ csr,
                                                     u16* __restrict__ agg, int n) {
    constexpr int LSZ = D / 8;        // lanes per node (16 for D=128, 8 for D=64)
    constexpr int NG  = 64 / LSZ;     // nodes per wave
    const int wave = threadIdx.x >> 6, lane = threadIdx.x & 63;
    const int l = lane & (LSZ - 1), g = lane / LSZ;
    const int node = (blockIdx.x * 4 + wave) * NG + g;
    const bool ok = node < n;
    int start = 0, end = 0;
    if (ok) { start = rowptr[node]; end = rowptr[node + 1]; }

    float2 a0 = {0.f, 0.f}, a1 = {0.f, 0.f}, a2 = {0.f, 0.f}, a3 = {0.f, 0.f};

    int e = start;
    for (; e + 2 <= end; e += 2) {
        const int s0 = csr[e];
        const int s1 = csr[e + 1];
        uint4 v0 = *reinterpret_cast<const uint4*>(y + (size_t)s0 * D + l * 8);
        uint4 v1 = *reinterpret_cast<const uint4*>(y + (size_t)s1 * D + l * 8);
        accp(a0, v0.x); accp(a1, v0.y); accp(a2, v0.z); accp(a3, v0.w);
        accp(a0, v1.x); accp(a1, v1.y); accp(a2, v1.z); accp(a3, v1.w);
    }
    if (e < end) {
        const int s0 = csr[e];
        uint4 v0 = *reinterpret_cast<const uint4*>(y + (size_t)s0 * D + l * 8);
        accp(a0, v0.x); accp(a1, v0.y); accp(a2, v0.z); accp(a3, v0.w);
    }

    if (ok) {
        const float inv = 1.0f / fmaxf((float)(end - start), 1.0f);
        uint4 o;
        o.x = (u32)f2bf(a0.x * inv) | ((u32)f2bf(a0.y * inv) << 16);
        o.y = (u32)f2bf(a1.x * inv) | ((u32)f2bf(a1.y * inv) << 16);
        o.z = (u32)f2bf(a2.x * inv) | ((u32)f2bf(a2.y * inv) << 16);
        o.w = (u32)f2bf(a3.x * inv) | ((u32)f2bf(a3.y * inv) << 16);
        *reinterpret_cast<uint4*>(agg + (size_t)node * D + l * 8) = o;
    }
}

extern "C" void kernel_launch(void* const* d_in, const int* in_sizes, int n_in,
                              void* d_out, int out_size, void* d_ws, size_t ws_size,
                              hipStream_t stream) {
    const float* x    = (const float*)d_in[0];
    const int*   ei1  = (const int*)d_in[1];
    const int*   ei2  = (const int*)d_in[2];
    const float* W_l1 = (const float*)d_in[3];
    const float* b_l1 = (const float*)d_in[4];
    const float* W_r1 = (const float*)d_in[5];
    const float* W_l2 = (const float*)d_in[6];
    const float* b_l2 = (const float*)d_in[7];
    const float* W_r2 = (const float*)d_in[8];

    const int n  = in_sizes[0] / 128;
    const int E1 = in_sizes[1] / 2;
    const int E2 = in_sizes[2] / 2;
    const int nB = (n + BNODES - 1) >> BSHIFT;   // <= 1024 (n <= 512k)

    // ws layout:
    char* w = (char*)d_ws;
    u16* xb  = (u16*)w; w += (size_t)n * 128 * 2;   // x as bf16
    u16* hb  = (u16*)w; w += (size_t)n * 128 * 2;   // layer-1 output (bf16)
    u16* yb  = (u16*)w; w += (size_t)n * 128 * 2;   // x@W_l (bf16); layer2: n x 64
    u16* agb = (u16*)w; w += (size_t)n * 128 * 2;   // gathered mean; ebuf aliases this
    u16* Pl1 = (u16*)w; w += 16384 * 2;
    u16* Pr1 = (u16*)w; w += 16384 * 2;
    u16* Pl2 = (u16*)w; w += 8192 * 2;
    u16* Pr2 = (u16*)w; w += 8192 * 2;
    int* rowptr = (int*)w; w += (size_t)(n + 1) * 4;
    int* bcnt   = (int*)w; w += 2048 * 4;           // two layers' count regions
    int* bbase  = (int*)w; w += 1025 * 4;
    int* bcur   = (int*)w; w += 1024 * 4;
    int* csr    = (int*)w;
    // ebuf (E u32) aliases agb: dead once bucket_build finishes, before gather writes agb.
    u32* ebuf = (u32*)agb;

    auto buildCSR = [&](const int* ei, int E, int* bc) {
        const int ng = (E + CHUNK - 1) / CHUNK;
        bucket_count<<<ng, 256, 0, stream>>>(ei, E, nB, bc);
        bucket_scan<<<1, 64, 0, stream>>>(bc, nB, bbase, bcur, rowptr, n, E);
        bucket_partition<<<ng, 256, 0, stream>>>(ei, E, nB, bcur, ebuf);
        bucket_build<<<nB, 256, 0, stream>>>(ebuf, bbase, n, rowptr, csr);
    };

    const int gemb = ((n + 31) / 32 + 3) / 4;

    hipMemsetAsync(bcnt, 0, 2048 * sizeof(int), stream);
    prep_kernel<<<24 + ((long)n * 16 + 255) / 256, 256, 0, stream>>>(
        x, (long)n * 128, W_l1, W_r1, W_l2, W_r2, xb, Pl1, Pr1, Pl2, Pr2);

    // layer 1
    buildCSR(ei1, E1, bcnt);
    mfma_gemm<128, 0><<<gemb, 256, 0, stream>>>(xb, Pl1, nullptr, nullptr, yb, n);
    gather_kernel<128><<<(n + 15) / 16, 256, 0, stream>>>(yb, rowptr, csr, agb, n);
    mfma_gemm<128, 1><<<gemb, 256, 0, stream>>>(xb, Pr1, b_l1, agb, hb, n);

    // layer 2
    buildCSR(ei2, E2, bcnt + 1024);
    mfma_gemm<64, 0><<<gemb, 256, 0, stream>>>(hb, Pl2, nullptr, nullptr, yb, n);
    gather_kernel<64><<<(n + 31) / 32, 256, 0, stream>>>(yb, rowptr, csr, agb, n);
    mfma_gemm<64, 2><<<gemb, 256, 0, stream>>>(hb, Pr2, b_l2, agb, d_out, n);
}

// Round 8
// 217.780 us; speedup vs baseline: 6.7597x; 1.1804x over previous
//
#include <hip/hip_runtime.h>
#include <hip/hip_bf16.h>

// GraphSAGE 2-layer forward on MI355X — MFMA + batched bucketed-CSR + MLP gather.
// mean(x[src]) @ W == mean((x@W)[src]) -> GEMMs at node granularity (bf16 MFMA,
// prepacked weight fragments); edge phase = CSR gather.
// Round-7 profile: gather 42us @ VALU 29% / HBM 41% -> MLP-limited (2 rows in
// flight). Fix: unroll-4 row loads. CSR builds for both layers batched into
// single launches (better grid fill, fewer serialization gaps).

typedef __attribute__((ext_vector_type(8))) short bf16x8;
typedef __attribute__((ext_vector_type(4))) float f32x4;
typedef unsigned int u32;
typedef unsigned short u16;

constexpr int BSHIFT = 9;             // 512 nodes per bucket
constexpr int BNODES = 1 << BSHIFT;
constexpr int CHUNK  = 4096;          // edges per workgroup in bucket kernels
constexpr int EPT    = CHUNK / 256;   // 16 edges per thread

__device__ __forceinline__ u16 f2bf(float f) {
    u32 u = __float_as_uint(f);
    return (u16)((u + 0x7fffu + ((u >> 16) & 1u)) >> 16);
}
__device__ __forceinline__ float bf2f(u16 h) { return __uint_as_float((u32)h << 16); }
__device__ __forceinline__ void accp(float2& a, u32 u) {
    a.x += __uint_as_float(u << 16);
    a.y += __uint_as_float(u & 0xffff0000u);
}

// ---------------- prep: fused weight-pack (blocks 0..23) + x->bf16 convert ----------------
__global__ __launch_bounds__(256) void prep_kernel(const float* __restrict__ x, long total,
                                                   const float* __restrict__ Wl1,
                                                   const float* __restrict__ Wr1,
                                                   const float* __restrict__ Wl2,
                                                   const float* __restrict__ Wr2,
                                                   u16* __restrict__ xb,
                                                   u16* __restrict__ Pl1, u16* __restrict__ Pr1,
                                                   u16* __restrict__ Pl2, u16* __restrict__ Pr2) {
    if (blockIdx.x < 24) {
        int u = blockIdx.x * 256 + threadIdx.x;
        if (u >= 6144) return;
        const float* W; u16* P; int O;
        if (u < 2048)      { W = Wl1; P = Pl1; O = 128; }
        else if (u < 4096) { W = Wr1; P = Pr1; O = 128; u -= 2048; }
        else if (u < 5120) { W = Wl2; P = Pl2; O = 64;  u -= 4096; }
        else               { W = Wr2; P = Pr2; O = 64;  u -= 5120; }
        int lane = u & 63, t = u >> 6;
        int ntiles = O / 16;
        int ks = t / ntiles, nt = t % ntiles;
        int k0 = ks * 32 + (lane >> 4) * 8;
        int col = nt * 16 + (lane & 15);
        bf16x8 o;
#pragma unroll
        for (int j = 0; j < 8; ++j) o[j] = (short)f2bf(W[(size_t)(k0 + j) * O + col]);
        *reinterpret_cast<bf16x8*>(P + (size_t)u * 8) = o;
    } else {
        long i = ((long)(blockIdx.x - 24) * 256 + threadIdx.x) * 8;
        if (i >= total) return;
        float4 v0 = *reinterpret_cast<const float4*>(x + i);
        float4 v1 = *reinterpret_cast<const float4*>(x + i + 4);
        bf16x8 o;
        o[0] = (short)f2bf(v0.x); o[1] = (short)f2bf(v0.y);
        o[2] = (short)f2bf(v0.z); o[3] = (short)f2bf(v0.w);
        o[4] = (short)f2bf(v1.x); o[5] = (short)f2bf(v1.y);
        o[6] = (short)f2bf(v1.z); o[7] = (short)f2bf(v1.w);
        *reinterpret_cast<bf16x8*>(xb + i) = o;
    }
}

// ---------------- batched bucketed CSR build (both layers in one launch) ----------------
__global__ __launch_bounds__(256) void bucket_count_both(const int* __restrict__ ei1, int E1, int ng1,
                                                         int* __restrict__ bc1,
                                                         const int* __restrict__ ei2, int E2,
                                                         int* __restrict__ bc2, int nB) {
    __shared__ int lcnt[1024];
    const int b = blockIdx.x;
    const int* ei; int E; int* bcnt; int base;
    if (b < ng1) { ei = ei1; E = E1; bcnt = bc1; base = b * CHUNK; }
    else         { ei = ei2; E = E2; bcnt = bc2; base = (b - ng1) * CHUNK; }
    for (int i = threadIdx.x; i < nB; i += 256) lcnt[i] = 0;
    __syncthreads();
    const int end = min(base + CHUNK, E);
    for (int e = base + (int)threadIdx.x; e < end; e += 256)
        atomicAdd(&lcnt[ei[E + e] >> BSHIFT], 1);
    __syncthreads();
    for (int i = threadIdx.x; i < nB; i += 256)
        if (lcnt[i]) atomicAdd(&bcnt[i], lcnt[i]);
}

__global__ void bucket_scan_both(const int* __restrict__ bc1, int* __restrict__ bbase1,
                                 int* __restrict__ bcur1, int* __restrict__ rp1, int E1,
                                 const int* __restrict__ bc2, int* __restrict__ bbase2,
                                 int* __restrict__ bcur2, int* __restrict__ rp2, int E2,
                                 int nB, int n) {
    const int* bcnt; int* bbase; int* bcur; int* rowptr; int E;
    if (blockIdx.x == 0) { bcnt = bc1; bbase = bbase1; bcur = bcur1; rowptr = rp1; E = E1; }
    else                 { bcnt = bc2; bbase = bbase2; bcur = bcur2; rowptr = rp2; E = E2; }
    const int lane = threadIdx.x;           // 64 threads
    int run = 0;
    for (int r = 0; r < nB; r += 64) {
        int i = r + lane;
        int v = (i < nB) ? bcnt[i] : 0;
        int x = v;
#pragma unroll
        for (int off = 1; off < 64; off <<= 1) { int y = __shfl_up(x, off); if (lane >= off) x += y; }
        int excl = run + x - v;
        if (i < nB) { bbase[i] = excl; bcur[i] = excl; }
        run += __shfl(x, 63);
    }
    if (lane == 0) { bbase[nB] = run; rowptr[n] = E; }
}

__global__ __launch_bounds__(256) void bucket_partition_both(const int* __restrict__ ei1, int E1, int ng1,
                                                             int* __restrict__ bcur1, u32* __restrict__ eb1,
                                                             const int* __restrict__ ei2, int E2,
                                                             int* __restrict__ bcur2, u32* __restrict__ eb2,
                                                             int nB) {
    __shared__ int lcnt[1024];
    __shared__ int lbase[1024];
    const int b = blockIdx.x;
    const int* ei; int E; int* bcur; u32* ebuf; int base;
    if (b < ng1) { ei = ei1; E = E1; bcur = bcur1; ebuf = eb1; base = b * CHUNK; }
    else         { ei = ei2; E = E2; bcur = bcur2; ebuf = eb2; base = (b - ng1) * CHUNK; }
    for (int i = threadIdx.x; i < nB; i += 256) lcnt[i] = 0;
    __syncthreads();

    u32 pk[EPT]; int bk[EPT];
#pragma unroll
    for (int k = 0; k < EPT; ++k) {
        int e = base + (int)threadIdx.x + k * 256;
        if (e < E) {
            int s = ei[e], d = ei[E + e];
            bk[k] = d >> BSHIFT;
            pk[k] = ((u32)(d & (BNODES - 1)) << 23) | (u32)s;
            atomicAdd(&lcnt[bk[k]], 1);
        } else bk[k] = -1;
    }
    __syncthreads();
    for (int i = threadIdx.x; i < nB; i += 256) {
        int c = lcnt[i];
        lbase[i] = c ? atomicAdd(&bcur[i], c) : 0;
        lcnt[i] = 0;                           // reuse as local cursor
    }
    __syncthreads();
#pragma unroll
    for (int k = 0; k < EPT; ++k) {
        if (bk[k] >= 0) {
            int p = lbase[bk[k]] + atomicAdd(&lcnt[bk[k]], 1);
            ebuf[p] = pk[k];
        }
    }
}

__global__ __launch_bounds__(256) void bucket_build_both(const u32* __restrict__ eb1,
                                                         const int* __restrict__ bbase1,
                                                         int* __restrict__ rp1, int* __restrict__ csr1,
                                                         const u32* __restrict__ eb2,
                                                         const int* __restrict__ bbase2,
                                                         int* __restrict__ rp2, int* __restrict__ csr2,
                                                         int nB, int n) {
    __shared__ int hist[BNODES];
    __shared__ int sstart[BNODES];
    __shared__ int spart[4];
    int bkt = blockIdx.x;
    const u32* ebuf; const int* bbase; int* rowptr; int* csr;
    if (bkt < nB) { ebuf = eb1; bbase = bbase1; rowptr = rp1; csr = csr1; }
    else          { ebuf = eb2; bbase = bbase2; rowptr = rp2; csr = csr2; bkt -= nB; }
    const int bb = bbase[bkt], be = bbase[bkt + 1];
    const int node0 = bkt << BSHIFT;

    for (int i = threadIdx.x; i < BNODES; i += 256) hist[i] = 0;
    __syncthreads();
    for (int e = bb + (int)threadIdx.x; e < be; e += 256)
        atomicAdd(&hist[ebuf[e] >> 23], 1);
    __syncthreads();

    const int t = threadIdx.x;
    const int v0 = hist[2 * t], v1 = hist[2 * t + 1];
    const int ts = v0 + v1;
    const int lane = t & 63, wave = t >> 6;
    int x = ts;
#pragma unroll
    for (int off = 1; off < 64; off <<= 1) { int y = __shfl_up(x, off); if (lane >= off) x += y; }
    if (lane == 63) spart[wave] = x;
    __syncthreads();
    int woff = 0;
#pragma unroll
    for (int w = 0; w < 4; ++w) if (w < wave) woff += spart[w];
    const int excl = woff + x - ts;
    sstart[2 * t] = excl;
    sstart[2 * t + 1] = excl + v0;
    const int nd0 = node0 + 2 * t, nd1 = node0 + 2 * t + 1;
    if (nd0 < n) rowptr[nd0] = bb + excl;
    if (nd1 < n) rowptr[nd1] = bb + excl + v0;
    for (int i = threadIdx.x; i < BNODES; i += 256) hist[i] = 0;
    __syncthreads();

    for (int e = bb + (int)threadIdx.x; e < be; e += 256) {
        u32 pkv = ebuf[e];
        int dl = pkv >> 23;
        int p = atomicAdd(&hist[dl], 1);
        csr[bb + sstart[dl] + p] = (int)(pkv & 0x7FFFFFu);
    }
}

// ---------------- MFMA GEMM with fused epilogues ----------------
// MODE 0: out = bf16(A@W); MODE 1: out = bf16(relu(A@W+bias+agg));
// MODE 2: out = f32(log_softmax(A@W+bias+agg)), O==64
template<int O, int MODE>
__global__ __launch_bounds__(256) void mfma_gemm(const u16* __restrict__ A,
                                                 const u16* __restrict__ Bp,
                                                 const float* __restrict__ bias,
                                                 const u16* __restrict__ agg,
                                                 void* __restrict__ outv, int n) {
    constexpr int NT = O / 16;
    const int wave = threadIdx.x >> 6, lane = threadIdx.x & 63;
    const int row0 = (blockIdx.x * 4 + wave) * 32;
    if (row0 >= n) return;
    const int lr = lane & 15, lg = lane >> 4;

    const int ra0 = min(row0 + lr, n - 1);
    const int ra1 = min(row0 + 16 + lr, n - 1);
    const bf16x8* A0 = reinterpret_cast<const bf16x8*>(A + (size_t)ra0 * 128);
    const bf16x8* A1 = reinterpret_cast<const bf16x8*>(A + (size_t)ra1 * 128);
    const bf16x8* B8 = reinterpret_cast<const bf16x8*>(Bp) + lane;

    f32x4 acc[2][NT];
#pragma unroll
    for (int i = 0; i < 2; ++i)
#pragma unroll
        for (int t = 0; t < NT; ++t) acc[i][t] = (f32x4){0.f, 0.f, 0.f, 0.f};

#pragma unroll
    for (int ks = 0; ks < 4; ++ks) {
        bf16x8 a0 = A0[ks * 4 + lg];
        bf16x8 a1 = A1[ks * 4 + lg];
#pragma unroll
        for (int t = 0; t < NT; ++t) {
            bf16x8 b = B8[(size_t)(ks * NT + t) * 64];
            acc[0][t] = __builtin_amdgcn_mfma_f32_16x16x32_bf16(a0, b, acc[0][t], 0, 0, 0);
            acc[1][t] = __builtin_amdgcn_mfma_f32_16x16x32_bf16(a1, b, acc[1][t], 0, 0, 0);
        }
    }

    // C/D layout (m89-verified): col = lane&15, row = (lane>>4)*4 + reg
    if (MODE == 2) {
        float* out = (float*)outv;
#pragma unroll
        for (int h = 0; h < 2; ++h) {
            float v[NT][4], m[4], s[4];
#pragma unroll
            for (int t = 0; t < NT; ++t) {
                float bv = bias[t * 16 + lr];
#pragma unroll
                for (int r = 0; r < 4; ++r) {
                    int row = min(row0 + h * 16 + lg * 4 + r, n - 1);
                    v[t][r] = acc[h][t][r] + bv + bf2f(agg[(size_t)row * O + t * 16 + lr]);
                }
            }
#pragma unroll
            for (int r = 0; r < 4; ++r)
                m[r] = fmaxf(fmaxf(v[0][r], v[1][r]), fmaxf(v[2][r], v[3][r]));
#pragma unroll
            for (int off = 1; off <= 8; off <<= 1)
#pragma unroll
                for (int r = 0; r < 4; ++r) m[r] = fmaxf(m[r], __shfl_xor(m[r], off));
#pragma unroll
            for (int r = 0; r < 4; ++r)
                s[r] = expf(v[0][r] - m[r]) + expf(v[1][r] - m[r]) +
                       expf(v[2][r] - m[r]) + expf(v[3][r] - m[r]);
#pragma unroll
            for (int off = 1; off <= 8; off <<= 1)
#pragma unroll
                for (int r = 0; r < 4; ++r) s[r] += __shfl_xor(s[r], off);
#pragma unroll
            for (int r = 0; r < 4; ++r) {
                float ls = logf(s[r]);
                int row = row0 + h * 16 + lg * 4 + r;
                if (row < n)
#pragma unroll
                    for (int t = 0; t < NT; ++t)
                        out[(size_t)row * O + t * 16 + lr] = v[t][r] - m[r] - ls;
            }
        }
    } else {
        u16* out = (u16*)outv;
#pragma unroll
        for (int h = 0; h < 2; ++h)
#pragma unroll
            for (int t = 0; t < NT; ++t) {
                float bv = (MODE == 1) ? bias[t * 16 + lr] : 0.f;
#pragma unroll
                for (int r = 0; r < 4; ++r) {
                    int row = row0 + h * 16 + lg * 4 + r;
                    if (row < n) {
                        float val = acc[h][t][r];
                        if (MODE == 1) {
                            val += bv + bf2f(agg[(size_t)row * O + t * 16 + lr]);
                            val = fmaxf(val, 0.f);
                        }
                        out[(size_t)row * O + t * 16 + lr] = f2bf(val);
                    }
                }
            }
    }
}

// ------- gather-reduce, node-per-group, unroll-4 for MLP -------
template<int D>
__global__ __launch_bounds__(256) void gather_kernel(const u16* __restrict__ y,
                                                     const int* __restrict__ rowptr,
                                                     const int* __restrict__ csr,
                                                     u16* __restrict__ agg, int n) {
    constexpr int LSZ = D / 8;        // lanes per node (16 for D=128, 8 for D=64)
    constexpr int NG  = 64 / LSZ;     // nodes per wave
    const int wave = threadIdx.x >> 6, lane = threadIdx.x & 63;
    const int l = lane & (LSZ - 1), g = lane / LSZ;
    const int node = (blockIdx.x * 4 + wave) * NG + g;
    const bool ok = node < n;
    int start = 0, end = 0;
    if (ok) { start = rowptr[node]; end = rowptr[node + 1]; }

    float2 a0 = {0.f, 0.f}, a1 = {0.f, 0.f}, a2 = {0.f, 0.f}, a3 = {0.f, 0.f};

    int e = start;
    for (; e + 4 <= end; e += 4) {
        const int s0 = csr[e], s1 = csr[e + 1], s2 = csr[e + 2], s3 = csr[e + 3];
        uint4 v0 = *reinterpret_cast<const uint4*>(y + (size_t)s0 * D + l * 8);
        uint4 v1 = *reinterpret_cast<const uint4*>(y + (size_t)s1 * D + l * 8);
        uint4 v2 = *reinterpret_cast<const uint4*>(y + (size_t)s2 * D + l * 8);
        uint4 v3 = *reinterpret_cast<const uint4*>(y + (size_t)s3 * D + l * 8);
        accp(a0, v0.x); accp(a1, v0.y); accp(a2, v0.z); accp(a3, v0.w);
        accp(a0, v1.x); accp(a1, v1.y); accp(a2, v1.z); accp(a3, v1.w);
        accp(a0, v2.x); accp(a1, v2.y); accp(a2, v2.z); accp(a3, v2.w);
        accp(a0, v3.x); accp(a1, v3.y); accp(a2, v3.z); accp(a3, v3.w);
    }
    for (; e < end; ++e) {
        const int s0 = csr[e];
        uint4 v0 = *reinterpret_cast<const uint4*>(y + (size_t)s0 * D + l * 8);
        accp(a0, v0.x); accp(a1, v0.y); accp(a2, v0.z); accp(a3, v0.w);
    }

    if (ok) {
        const float inv = 1.0f / fmaxf((float)(end - start), 1.0f);
        uint4 o;
        o.x = (u32)f2bf(a0.x * inv) | ((u32)f2bf(a0.y * inv) << 16);
        o.y = (u32)f2bf(a1.x * inv) | ((u32)f2bf(a1.y * inv) << 16);
        o.z = (u32)f2bf(a2.x * inv) | ((u32)f2bf(a2.y * inv) << 16);
        o.w = (u32)f2bf(a3.x * inv) | ((u32)f2bf(a3.y * inv) << 16);
        *reinterpret_cast<uint4*>(agg + (size_t)node * D + l * 8) = o;
    }
}

extern "C" void kernel_launch(void* const* d_in, const int* in_sizes, int n_in,
                              void* d_out, int out_size, void* d_ws, size_t ws_size,
                              hipStream_t stream) {
    const float* x    = (const float*)d_in[0];
    const int*   ei1  = (const int*)d_in[1];
    const int*   ei2  = (const int*)d_in[2];
    const float* W_l1 = (const float*)d_in[3];
    const float* b_l1 = (const float*)d_in[4];
    const float* W_r1 = (const float*)d_in[5];
    const float* W_l2 = (const float*)d_in[6];
    const float* b_l2 = (const float*)d_in[7];
    const float* W_r2 = (const float*)d_in[8];

    const int n  = in_sizes[0] / 128;
    const int E1 = in_sizes[1] / 2;
    const int E2 = in_sizes[2] / 2;
    const int nB = (n + BNODES - 1) >> BSHIFT;   // <= 1024 (n <= 512k)
    const int ng1 = (E1 + CHUNK - 1) / CHUNK;
    const int ng2 = (E2 + CHUNK - 1) / CHUNK;

    // ws layout:
    char* w = (char*)d_ws;
    u16* xb  = (u16*)w; w += (size_t)n * 128 * 2;   // x as bf16
    u16* hb  = (u16*)w; w += (size_t)n * 128 * 2;   // layer-1 output (bf16)
    u16* yb  = (u16*)w; w += (size_t)n * 128 * 2;   // x@W_l (bf16); layer2: n x 64
    u16* agb = (u16*)w; w += (size_t)n * 128 * 2;   // gathered mean; ebuf1/2 alias this
    u16* Pl1 = (u16*)w; w += 16384 * 2;
    u16* Pr1 = (u16*)w; w += 16384 * 2;
    u16* Pl2 = (u16*)w; w += 8192 * 2;
    u16* Pr2 = (u16*)w; w += 8192 * 2;
    int* rp1   = (int*)w; w += (size_t)(n + 1) * 4;
    int* rp2   = (int*)w; w += (size_t)(n + 1) * 4;
    int* bcnt  = (int*)w; w += 2048 * 4;            // bc1 | bc2
    int* bbase1= (int*)w; w += 1025 * 4;
    int* bbase2= (int*)w; w += 1025 * 4;
    int* bcur1 = (int*)w; w += 1024 * 4;
    int* bcur2 = (int*)w; w += 1024 * 4;
    int* csr1  = (int*)w; w += (size_t)E1 * 4;
    int* csr2  = (int*)w;
    // ebuf1/2 alias agb (25.6MB >= (E1+E2)*4B): consumed by bucket_build_both,
    // which completes before gather writes agb (serial stream).
    u32* eb1 = (u32*)agb;
    u32* eb2 = eb1 + E1;

    const int gemb = ((n + 31) / 32 + 3) / 4;

    hipMemsetAsync(bcnt, 0, 2048 * sizeof(int), stream);
    prep_kernel<<<24 + ((long)n * 16 + 255) / 256, 256, 0, stream>>>(
        x, (long)n * 128, W_l1, W_r1, W_l2, W_r2, xb, Pl1, Pr1, Pl2, Pr2);

    // CSR build for BOTH layers (batched launches)
    bucket_count_both<<<ng1 + ng2, 256, 0, stream>>>(ei1, E1, ng1, bcnt, ei2, E2, bcnt + 1024, nB);
    bucket_scan_both<<<2, 64, 0, stream>>>(bcnt, bbase1, bcur1, rp1, E1,
                                           bcnt + 1024, bbase2, bcur2, rp2, E2, nB, n);
    bucket_partition_both<<<ng1 + ng2, 256, 0, stream>>>(ei1, E1, ng1, bcur1, eb1,
                                                         ei2, E2, bcur2, eb2, nB);
    bucket_build_both<<<2 * nB, 256, 0, stream>>>(eb1, bbase1, rp1, csr1,
                                                  eb2, bbase2, rp2, csr2, nB, n);

    // layer 1
    mfma_gemm<128, 0><<<gemb, 256, 0, stream>>>(xb, Pl1, nullptr, nullptr, yb, n);
    gather_kernel<128><<<(n + 15) / 16, 256, 0, stream>>>(yb, rp1, csr1, agb, n);
    mfma_gemm<128, 1><<<gemb, 256, 0, stream>>>(xb, Pr1, b_l1, agb, hb, n);

    // layer 2
    mfma_gemm<64, 0><<<gemb, 256, 0, stream>>>(hb, Pl2, nullptr, nullptr, yb, n);
    gather_kernel<64><<<(n + 31) / 32, 256, 0, stream>>>(yb, rp2, csr2, agb, n);
    mfma_gemm<64, 2><<<gemb, 256, 0, stream>>>(hb, Pr2, b_l2, agb, d_out, n);
}

// Round 9
// 190.239 us; speedup vs baseline: 7.7383x; 1.1448x over previous
//
#include <hip/hip_runtime.h>
#include <hip/hip_bf16.h>

// GraphSAGE 2-layer forward on MI355X — fused-pair MFMA + bucketed-CSR + fused gathers.
// mean(x[src]) @ W == mean((x@W)[src]). Per layer ONE gemm kernel computes
// y=A@Wl and z=A@Wr+b (A read once, LDS-staged coalesced epilogue, 16 rows/wave),
// and the gather fuses the combine: L1 h=relu(agg+z); L2 out=log_softmax(agg+z).
// Round-8 profile: mfma_gemm 40us @ Mfma 2.8%/occ 28% (latency-bound, scalar
// 2B epilogue stores); combine round-trips eliminated.

typedef __attribute__((ext_vector_type(8))) short bf16x8;
typedef __attribute__((ext_vector_type(4))) float f32x4;
typedef unsigned int u32;
typedef unsigned short u16;

constexpr int BSHIFT = 9;             // 512 nodes per bucket
constexpr int BNODES = 1 << BSHIFT;
constexpr int CHUNK  = 4096;          // edges per workgroup in bucket kernels
constexpr int EPT    = CHUNK / 256;   // 16 edges per thread

__device__ __forceinline__ u16 f2bf(float f) {
    u32 u = __float_as_uint(f);
    return (u16)((u + 0x7fffu + ((u >> 16) & 1u)) >> 16);
}
__device__ __forceinline__ float bf2f(u16 h) { return __uint_as_float((u32)h << 16); }
__device__ __forceinline__ float blo(u32 u) { return __uint_as_float(u << 16); }
__device__ __forceinline__ float bhi(u32 u) { return __uint_as_float(u & 0xffff0000u); }
__device__ __forceinline__ void accp(float2& a, u32 u) { a.x += blo(u); a.y += bhi(u); }
__device__ __forceinline__ u32 pack2(float x, float y) {
    return (u32)f2bf(x) | ((u32)f2bf(y) << 16);
}

// ---------------- prep: fused weight-pack (blocks 0..23) + x->bf16 convert ----------------
__global__ __launch_bounds__(256) void prep_kernel(const float* __restrict__ x, long total,
                                                   const float* __restrict__ Wl1,
                                                   const float* __restrict__ Wr1,
                                                   const float* __restrict__ Wl2,
                                                   const float* __restrict__ Wr2,
                                                   u16* __restrict__ xb,
                                                   u16* __restrict__ Pl1, u16* __restrict__ Pr1,
                                                   u16* __restrict__ Pl2, u16* __restrict__ Pr2) {
    if (blockIdx.x < 24) {
        int u = blockIdx.x * 256 + threadIdx.x;
        if (u >= 6144) return;
        const float* W; u16* P; int O;
        if (u < 2048)      { W = Wl1; P = Pl1; O = 128; }
        else if (u < 4096) { W = Wr1; P = Pr1; O = 128; u -= 2048; }
        else if (u < 5120) { W = Wl2; P = Pl2; O = 64;  u -= 4096; }
        else               { W = Wr2; P = Pr2; O = 64;  u -= 5120; }
        int lane = u & 63, t = u >> 6;
        int ntiles = O / 16;
        int ks = t / ntiles, nt = t % ntiles;
        int k0 = ks * 32 + (lane >> 4) * 8;
        int col = nt * 16 + (lane & 15);
        bf16x8 o;
#pragma unroll
        for (int j = 0; j < 8; ++j) o[j] = (short)f2bf(W[(size_t)(k0 + j) * O + col]);
        *reinterpret_cast<bf16x8*>(P + (size_t)u * 8) = o;
    } else {
        long i = ((long)(blockIdx.x - 24) * 256 + threadIdx.x) * 8;
        if (i >= total) return;
        float4 v0 = *reinterpret_cast<const float4*>(x + i);
        float4 v1 = *reinterpret_cast<const float4*>(x + i + 4);
        bf16x8 o;
        o[0] = (short)f2bf(v0.x); o[1] = (short)f2bf(v0.y);
        o[2] = (short)f2bf(v0.z); o[3] = (short)f2bf(v0.w);
        o[4] = (short)f2bf(v1.x); o[5] = (short)f2bf(v1.y);
        o[6] = (short)f2bf(v1.z); o[7] = (short)f2bf(v1.w);
        *reinterpret_cast<bf16x8*>(xb + i) = o;
    }
}

// ---------------- batched bucketed CSR build (both layers in one launch) ----------------
__global__ __launch_bounds__(256) void bucket_count_both(const int* __restrict__ ei1, int E1, int ng1,
                                                         int* __restrict__ bc1,
                                                         const int* __restrict__ ei2, int E2,
                                                         int* __restrict__ bc2, int nB) {
    __shared__ int lcnt[1024];
    const int b = blockIdx.x;
    const int* ei; int E; int* bcnt; int base;
    if (b < ng1) { ei = ei1; E = E1; bcnt = bc1; base = b * CHUNK; }
    else         { ei = ei2; E = E2; bcnt = bc2; base = (b - ng1) * CHUNK; }
    for (int i = threadIdx.x; i < nB; i += 256) lcnt[i] = 0;
    __syncthreads();
    const int end = min(base + CHUNK, E);
    for (int e = base + (int)threadIdx.x; e < end; e += 256)
        atomicAdd(&lcnt[ei[E + e] >> BSHIFT], 1);
    __syncthreads();
    for (int i = threadIdx.x; i < nB; i += 256)
        if (lcnt[i]) atomicAdd(&bcnt[i], lcnt[i]);
}

__global__ void bucket_scan_both(const int* __restrict__ bc1, int* __restrict__ bbase1,
                                 int* __restrict__ bcur1, int* __restrict__ rp1, int E1,
                                 const int* __restrict__ bc2, int* __restrict__ bbase2,
                                 int* __restrict__ bcur2, int* __restrict__ rp2, int E2,
                                 int nB, int n) {
    const int* bcnt; int* bbase; int* bcur; int* rowptr; int E;
    if (blockIdx.x == 0) { bcnt = bc1; bbase = bbase1; bcur = bcur1; rowptr = rp1; E = E1; }
    else                 { bcnt = bc2; bbase = bbase2; bcur = bcur2; rowptr = rp2; E = E2; }
    const int lane = threadIdx.x;           // 64 threads
    int run = 0;
    for (int r = 0; r < nB; r += 64) {
        int i = r + lane;
        int v = (i < nB) ? bcnt[i] : 0;
        int x = v;
#pragma unroll
        for (int off = 1; off < 64; off <<= 1) { int y = __shfl_up(x, off); if (lane >= off) x += y; }
        int excl = run + x - v;
        if (i < nB) { bbase[i] = excl; bcur[i] = excl; }
        run += __shfl(x, 63);
    }
    if (lane == 0) { bbase[nB] = run; rowptr[n] = E; }
}

__global__ __launch_bounds__(256) void bucket_partition_both(const int* __restrict__ ei1, int E1, int ng1,
                                                             int* __restrict__ bcur1, u32* __restrict__ eb1,
                                                             const int* __restrict__ ei2, int E2,
                                                             int* __restrict__ bcur2, u32* __restrict__ eb2,
                                                             int nB) {
    __shared__ int lcnt[1024];
    __shared__ int lbase[1024];
    const int b = blockIdx.x;
    const int* ei; int E; int* bcur; u32* ebuf; int base;
    if (b < ng1) { ei = ei1; E = E1; bcur = bcur1; ebuf = eb1; base = b * CHUNK; }
    else         { ei = ei2; E = E2; bcur = bcur2; ebuf = eb2; base = (b - ng1) * CHUNK; }
    for (int i = threadIdx.x; i < nB; i += 256) lcnt[i] = 0;
    __syncthreads();

    u32 pk[EPT]; int bk[EPT];
#pragma unroll
    for (int k = 0; k < EPT; ++k) {
        int e = base + (int)threadIdx.x + k * 256;
        if (e < E) {
            int s = ei[e], d = ei[E + e];
            bk[k] = d >> BSHIFT;
            pk[k] = ((u32)(d & (BNODES - 1)) << 23) | (u32)s;
            atomicAdd(&lcnt[bk[k]], 1);
        } else bk[k] = -1;
    }
    __syncthreads();
    for (int i = threadIdx.x; i < nB; i += 256) {
        int c = lcnt[i];
        lbase[i] = c ? atomicAdd(&bcur[i], c) : 0;
        lcnt[i] = 0;                           // reuse as local cursor
    }
    __syncthreads();
#pragma unroll
    for (int k = 0; k < EPT; ++k) {
        if (bk[k] >= 0) {
            int p = lbase[bk[k]] + atomicAdd(&lcnt[bk[k]], 1);
            ebuf[p] = pk[k];
        }
    }
}

__global__ __launch_bounds__(256) void bucket_build_both(const u32* __restrict__ eb1,
                                                         const int* __restrict__ bbase1,
                                                         int* __restrict__ rp1, int* __restrict__ csr1,
                                                         const u32* __restrict__ eb2,
                                                         const int* __restrict__ bbase2,
                                                         int* __restrict__ rp2, int* __restrict__ csr2,
                                                         int nB, int n) {
    __shared__ int hist[BNODES];
    __shared__ int sstart[BNODES];
    __shared__ int spart[4];
    int bkt = blockIdx.x;
    const u32* ebuf; const int* bbase; int* rowptr; int* csr;
    if (bkt < nB) { ebuf = eb1; bbase = bbase1; rowptr = rp1; csr = csr1; }
    else          { ebuf = eb2; bbase = bbase2; rowptr = rp2; csr = csr2; bkt -= nB; }
    const int bb = bbase[bkt], be = bbase[bkt + 1];
    const int node0 = bkt << BSHIFT;

    for (int i = threadIdx.x; i < BNODES; i += 256) hist[i] = 0;
    __syncthreads();
    for (int e = bb + (int)threadIdx.x; e < be; e += 256)
        atomicAdd(&hist[ebuf[e] >> 23], 1);
    __syncthreads();

    const int t = threadIdx.x;
    const int v0 = hist[2 * t], v1 = hist[2 * t + 1];
    const int ts = v0 + v1;
    const int lane = t & 63, wave = t >> 6;
    int x = ts;
#pragma unroll
    for (int off = 1; off < 64; off <<= 1) { int y = __shfl_up(x, off); if (lane >= off) x += y; }
    if (lane == 63) spart[wave] = x;
    __syncthreads();
    int woff = 0;
#pragma unroll
    for (int w = 0; w < 4; ++w) if (w < wave) woff += spart[w];
    const int excl = woff + x - ts;
    sstart[2 * t] = excl;
    sstart[2 * t + 1] = excl + v0;
    const int nd0 = node0 + 2 * t, nd1 = node0 + 2 * t + 1;
    if (nd0 < n) rowptr[nd0] = bb + excl;
    if (nd1 < n) rowptr[nd1] = bb + excl + v0;
    for (int i = threadIdx.x; i < BNODES; i += 256) hist[i] = 0;
    __syncthreads();

    for (int e = bb + (int)threadIdx.x; e < be; e += 256) {
        u32 pkv = ebuf[e];
        int dl = pkv >> 23;
        int p = atomicAdd(&hist[dl], 1);
        csr[bb + sstart[dl] + p] = (int)(pkv & 0x7FFFFFu);
    }
}

// ------- fused pair GEMM: y = A@Wl, z = A@Wr + b  (A: n x 128 bf16, O outputs each) -------
// 16 rows/wave, LDS-staged coalesced epilogue (y then z through the same buffer).
template<int O>
__global__ __launch_bounds__(256, 4) void fused_gemm(const u16* __restrict__ A,
                                                     const u16* __restrict__ Py,
                                                     const u16* __restrict__ Pz,
                                                     const float* __restrict__ bias,
                                                     u16* __restrict__ yb,
                                                     u16* __restrict__ zb, int n) {
    constexpr int NT  = O / 16;
    constexpr int STR = O + 8;        // u16 stride, +8 breaks bank power-of-2
    constexpr int C8  = O / 8;        // uint4 chunks per row
    __shared__ u16 lds[4][16 * STR];

    const int wave = threadIdx.x >> 6, lane = threadIdx.x & 63;
    const int row0 = (blockIdx.x * 4 + wave) * 16;
    if (row0 >= n) return;
    const int lr = lane & 15, lg = lane >> 4;

    const int ra = min(row0 + lr, n - 1);
    const bf16x8* A8 = reinterpret_cast<const bf16x8*>(A + (size_t)ra * 128);
    const bf16x8* Y8 = reinterpret_cast<const bf16x8*>(Py) + lane;
    const bf16x8* Z8 = reinterpret_cast<const bf16x8*>(Pz) + lane;

    f32x4 accy[NT], accz[NT];
#pragma unroll
    for (int t = 0; t < NT; ++t) { accy[t] = (f32x4){0,0,0,0}; accz[t] = (f32x4){0,0,0,0}; }

#pragma unroll
    for (int ks = 0; ks < 4; ++ks) {
        bf16x8 a = A8[ks * 4 + lg];
#pragma unroll
        for (int t = 0; t < NT; ++t)
            accy[t] = __builtin_amdgcn_mfma_f32_16x16x32_bf16(a, Y8[(size_t)(ks * NT + t) * 64], accy[t], 0, 0, 0);
#pragma unroll
        for (int t = 0; t < NT; ++t)
            accz[t] = __builtin_amdgcn_mfma_f32_16x16x32_bf16(a, Z8[(size_t)(ks * NT + t) * 64], accz[t], 0, 0, 0);
    }

    u16* L = lds[wave];
    // ---- phase Y: stage tiles (C/D layout: col=lane&15, row=(lane>>4)*4+r), coalesced store
#pragma unroll
    for (int t = 0; t < NT; ++t)
#pragma unroll
        for (int r = 0; r < 4; ++r)
            L[(lg * 4 + r) * STR + t * 16 + lr] = f2bf(accy[t][r]);
#pragma unroll
    for (int it = 0; it < O / 32; ++it) {
        int idx = it * 64 + lane;
        int row = idx / C8, c8 = idx % C8;
        if (row0 + row < n)
            *reinterpret_cast<uint4*>(yb + (size_t)(row0 + row) * O + c8 * 8) =
                *reinterpret_cast<const uint4*>(&L[row * STR + c8 * 8]);
    }
    // ---- phase Z: same buffer (wave-local WAR ordered by lgkmcnt)
#pragma unroll
    for (int t = 0; t < NT; ++t) {
        float bv = bias[t * 16 + lr];
#pragma unroll
        for (int r = 0; r < 4; ++r)
            L[(lg * 4 + r) * STR + t * 16 + lr] = f2bf(accz[t][r] + bv);
    }
#pragma unroll
    for (int it = 0; it < O / 32; ++it) {
        int idx = it * 64 + lane;
        int row = idx / C8, c8 = idx % C8;
        if (row0 + row < n)
            *reinterpret_cast<uint4*>(zb + (size_t)(row0 + row) * O + c8 * 8) =
                *reinterpret_cast<const uint4*>(&L[row * STR + c8 * 8]);
    }
}

// ------- gather + combine L1: h = relu(mean y[src] + z)  (D=128) -------
__global__ __launch_bounds__(256) void gather_relu(const u16* __restrict__ y,
                                                   const int* __restrict__ rowptr,
                                                   const int* __restrict__ csr,
                                                   const u16* __restrict__ z,
                                                   u16* __restrict__ h, int n) {
    const int wave = threadIdx.x >> 6, lane = threadIdx.x & 63;
    const int l = lane & 15, g = lane >> 4;           // 16 lanes/node, 4 nodes/wave
    const int node = (blockIdx.x * 4 + wave) * 4 + g;
    const bool ok = node < n;
    int start = 0, end = 0;
    if (ok) { start = rowptr[node]; end = rowptr[node + 1]; }

    float2 a0 = {0,0}, a1 = {0,0}, a2 = {0,0}, a3 = {0,0};
    int e = start;
    for (; e + 4 <= end; e += 4) {
        const int s0 = csr[e], s1 = csr[e + 1], s2 = csr[e + 2], s3 = csr[e + 3];
        uint4 v0 = *reinterpret_cast<const uint4*>(y + (size_t)s0 * 128 + l * 8);
        uint4 v1 = *reinterpret_cast<const uint4*>(y + (size_t)s1 * 128 + l * 8);
        uint4 v2 = *reinterpret_cast<const uint4*>(y + (size_t)s2 * 128 + l * 8);
        uint4 v3 = *reinterpret_cast<const uint4*>(y + (size_t)s3 * 128 + l * 8);
        accp(a0, v0.x); accp(a1, v0.y); accp(a2, v0.z); accp(a3, v0.w);
        accp(a0, v1.x); accp(a1, v1.y); accp(a2, v1.z); accp(a3, v1.w);
        accp(a0, v2.x); accp(a1, v2.y); accp(a2, v2.z); accp(a3, v2.w);
        accp(a0, v3.x); accp(a1, v3.y); accp(a2, v3.z); accp(a3, v3.w);
    }
    for (; e < end; ++e) {
        const int s0 = csr[e];
        uint4 v0 = *reinterpret_cast<const uint4*>(y + (size_t)s0 * 128 + l * 8);
        accp(a0, v0.x); accp(a1, v0.y); accp(a2, v0.z); accp(a3, v0.w);
    }

    if (ok) {
        const float inv = 1.0f / fmaxf((float)(end - start), 1.0f);
        uint4 zr = *reinterpret_cast<const uint4*>(z + (size_t)node * 128 + l * 8);
        uint4 o;
        o.x = pack2(fmaxf(a0.x * inv + blo(zr.x), 0.f), fmaxf(a0.y * inv + bhi(zr.x), 0.f));
        o.y = pack2(fmaxf(a1.x * inv + blo(zr.y), 0.f), fmaxf(a1.y * inv + bhi(zr.y), 0.f));
        o.z = pack2(fmaxf(a2.x * inv + blo(zr.z), 0.f), fmaxf(a2.y * inv + bhi(zr.z), 0.f));
        o.w = pack2(fmaxf(a3.x * inv + blo(zr.w), 0.f), fmaxf(a3.y * inv + bhi(zr.w), 0.f));
        *reinterpret_cast<uint4*>(h + (size_t)node * 128 + l * 8) = o;
    }
}

// ------- gather + combine L2: out = log_softmax(mean y2[src] + z2)  (D=64, f32 out) -------
__global__ __launch_bounds__(256) void gather_lsm(const u16* __restrict__ y,
                                                  const int* __restrict__ rowptr,
                                                  const int* __restrict__ csr,
                                                  const u16* __restrict__ z,
                                                  float* __restrict__ out, int n) {
    const int wave = threadIdx.x >> 6, lane = threadIdx.x & 63;
    const int l = lane & 7, g = lane >> 3;            // 8 lanes/node, 8 nodes/wave
    const int node = (blockIdx.x * 4 + wave) * 8 + g;
    const bool ok = node < n;
    int start = 0, end = 0;
    if (ok) { start = rowptr[node]; end = rowptr[node + 1]; }

    float2 a0 = {0,0}, a1 = {0,0}, a2 = {0,0}, a3 = {0,0};
    int e = start;
    for (; e + 4 <= end; e += 4) {
        const int s0 = csr[e], s1 = csr[e + 1], s2 = csr[e + 2], s3 = csr[e + 3];
        uint4 v0 = *reinterpret_cast<const uint4*>(y + (size_t)s0 * 64 + l * 8);
        uint4 v1 = *reinterpret_cast<const uint4*>(y + (size_t)s1 * 64 + l * 8);
        uint4 v2 = *reinterpret_cast<const uint4*>(y + (size_t)s2 * 64 + l * 8);
        uint4 v3 = *reinterpret_cast<const uint4*>(y + (size_t)s3 * 64 + l * 8);
        accp(a0, v0.x); accp(a1, v0.y); accp(a2, v0.z); accp(a3, v0.w);
        accp(a0, v1.x); accp(a1, v1.y); accp(a2, v1.z); accp(a3, v1.w);
        accp(a0, v2.x); accp(a1, v2.y); accp(a2, v2.z); accp(a3, v2.w);
        accp(a0, v3.x); accp(a1, v3.y); accp(a2, v3.z); accp(a3, v3.w);
    }
    for (; e < end; ++e) {
        const int s0 = csr[e];
        uint4 v0 = *reinterpret_cast<const uint4*>(y + (size_t)s0 * 64 + l * 8);
        accp(a0, v0.x); accp(a1, v0.y); accp(a2, v0.z); accp(a3, v0.w);
    }

    if (ok) {
        const float inv = 1.0f / fmaxf((float)(end - start), 1.0f);
        uint4 zr = *reinterpret_cast<const uint4*>(z + (size_t)node * 64 + l * 8);
        float v0 = a0.x * inv + blo(zr.x), v1 = a0.y * inv + bhi(zr.x);
        float v2 = a1.x * inv + blo(zr.y), v3 = a1.y * inv + bhi(zr.y);
        float v4 = a2.x * inv + blo(zr.z), v5 = a2.y * inv + bhi(zr.z);
        float v6 = a3.x * inv + blo(zr.w), v7 = a3.y * inv + bhi(zr.w);

        float m = fmaxf(fmaxf(fmaxf(v0, v1), fmaxf(v2, v3)), fmaxf(fmaxf(v4, v5), fmaxf(v6, v7)));
        m = fmaxf(m, __shfl_xor(m, 1));
        m = fmaxf(m, __shfl_xor(m, 2));
        m = fmaxf(m, __shfl_xor(m, 4));
        float s = expf(v0 - m) + expf(v1 - m) + expf(v2 - m) + expf(v3 - m) +
                  expf(v4 - m) + expf(v5 - m) + expf(v6 - m) + expf(v7 - m);
        s += __shfl_xor(s, 1);
        s += __shfl_xor(s, 2);
        s += __shfl_xor(s, 4);
        const float c = m + logf(s);
        float* op = out + (size_t)node * 64 + l * 8;
        *reinterpret_cast<float4*>(op)     = (float4){v0 - c, v1 - c, v2 - c, v3 - c};
        *reinterpret_cast<float4*>(op + 4) = (float4){v4 - c, v5 - c, v6 - c, v7 - c};
    }
}

extern "C" void kernel_launch(void* const* d_in, const int* in_sizes, int n_in,
                              void* d_out, int out_size, void* d_ws, size_t ws_size,
                              hipStream_t stream) {
    const float* x    = (const float*)d_in[0];
    const int*   ei1  = (const int*)d_in[1];
    const int*   ei2  = (const int*)d_in[2];
    const float* W_l1 = (const float*)d_in[3];
    const float* b_l1 = (const float*)d_in[4];
    const float* W_r1 = (const float*)d_in[5];
    const float* W_l2 = (const float*)d_in[6];
    const float* b_l2 = (const float*)d_in[7];
    const float* W_r2 = (const float*)d_in[8];

    const int n  = in_sizes[0] / 128;
    const int E1 = in_sizes[1] / 2;
    const int E2 = in_sizes[2] / 2;
    const int nB = (n + BNODES - 1) >> BSHIFT;   // <= 1024 (n <= 512k)
    const int ng1 = (E1 + CHUNK - 1) / CHUNK;
    const int ng2 = (E2 + CHUNK - 1) / CHUNK;

    // ws layout:
    char* w = (char*)d_ws;
    u16* xb  = (u16*)w; w += (size_t)n * 128 * 2;   // x as bf16
    u16* hb  = (u16*)w; w += (size_t)n * 128 * 2;   // h (bf16); ebuf1/2 alias this
    u16* yb  = (u16*)w; w += (size_t)n * 128 * 2;   // y = A@Wl (L1: nx128; L2: nx64)
    u16* zb  = (u16*)w; w += (size_t)n * 128 * 2;   // z = A@Wr+b (L1: nx128; L2: nx64)
    u16* Pl1 = (u16*)w; w += 16384 * 2;
    u16* Pr1 = (u16*)w; w += 16384 * 2;
    u16* Pl2 = (u16*)w; w += 8192 * 2;
    u16* Pr2 = (u16*)w; w += 8192 * 2;
    int* rp1   = (int*)w; w += (size_t)(n + 1) * 4;
    int* rp2   = (int*)w; w += (size_t)(n + 1) * 4;
    int* bcnt  = (int*)w; w += 2048 * 4;            // bc1 | bc2
    int* bbase1= (int*)w; w += 1025 * 4;
    int* bbase2= (int*)w; w += 1025 * 4;
    int* bcur1 = (int*)w; w += 1024 * 4;
    int* bcur2 = (int*)w; w += 1024 * 4;
    int* csr1  = (int*)w; w += (size_t)E1 * 4;
    int* csr2  = (int*)w;
    // ebuf1/2 alias hb (25.6MB >= (E1+E2)*4B): consumed by bucket_build_both,
    // which completes before gather_relu writes hb (serial stream).
    u32* eb1 = (u32*)hb;
    u32* eb2 = eb1 + E1;

    hipMemsetAsync(bcnt, 0, 2048 * sizeof(int), stream);
    prep_kernel<<<24 + ((long)n * 16 + 255) / 256, 256, 0, stream>>>(
        x, (long)n * 128, W_l1, W_r1, W_l2, W_r2, xb, Pl1, Pr1, Pl2, Pr2);

    // CSR build for BOTH layers (batched launches)
    bucket_count_both<<<ng1 + ng2, 256, 0, stream>>>(ei1, E1, ng1, bcnt, ei2, E2, bcnt + 1024, nB);
    bucket_scan_both<<<2, 64, 0, stream>>>(bcnt, bbase1, bcur1, rp1, E1,
                                           bcnt + 1024, bbase2, bcur2, rp2, E2, nB, n);
    bucket_partition_both<<<ng1 + ng2, 256, 0, stream>>>(ei1, E1, ng1, bcur1, eb1,
                                                         ei2, E2, bcur2, eb2, nB);
    bucket_build_both<<<2 * nB, 256, 0, stream>>>(eb1, bbase1, rp1, csr1,
                                                  eb2, bbase2, rp2, csr2, nB, n);

    const int gb = (n + 63) / 64;   // fused_gemm: 64 rows/block (16/wave)

    // layer 1: y1|z1 then h = relu(agg + z1)
    fused_gemm<128><<<gb, 256, 0, stream>>>(xb, Pl1, Pr1, b_l1, yb, zb, n);
    gather_relu<<<(n + 15) / 16, 256, 0, stream>>>(yb, rp1, csr1, zb, hb, n);

    // layer 2: y2|z2 then out = log_softmax(agg + z2)
    fused_gemm<64><<<gb, 256, 0, stream>>>(hb, Pl2, Pr2, b_l2, yb, zb, n);
    gather_lsm<<<(n + 31) / 32, 256, 0, stream>>>(yb, rp2, csr2, zb, (float*)d_out, n);
}

// Round 10
// 186.427 us; speedup vs baseline: 7.8965x; 1.0204x over previous
//
#include <hip/hip_runtime.h>
#include <hip/hip_bf16.h>

// GraphSAGE 2-layer forward on MI355X — merged-launch edition.
// mean(x[src]) @ W == mean((x@W)[src]). Per layer one fused GEMM pair
// (y=A@Wl, z=A@Wr+b) + gather that fuses the combine (relu / log_softmax).
// Round-9 profile: sum-of-serial-launches dominated; independent stages are
// merged into single launches (serial-stream overlap): prep||count,
// partition||gemm1, gather_relu||build2.

typedef __attribute__((ext_vector_type(8))) short bf16x8;
typedef __attribute__((ext_vector_type(4))) float f32x4;
typedef unsigned int u32;
typedef unsigned short u16;

constexpr int BSHIFT = 9;             // 512 nodes per bucket
constexpr int BNODES = 1 << BSHIFT;
constexpr int CHUNK  = 4096;          // edges per workgroup in bucket kernels
constexpr int EPT    = CHUNK / 256;   // 16 edges per thread

__device__ __forceinline__ u16 f2bf(float f) {
    u32 u = __float_as_uint(f);
    return (u16)((u + 0x7fffu + ((u >> 16) & 1u)) >> 16);
}
__device__ __forceinline__ float blo(u32 u) { return __uint_as_float(u << 16); }
__device__ __forceinline__ float bhi(u32 u) { return __uint_as_float(u & 0xffff0000u); }
__device__ __forceinline__ void accp(float2& a, u32 u) { a.x += blo(u); a.y += bhi(u); }
__device__ __forceinline__ u32 pack2(float x, float y) {
    return (u32)f2bf(x) | ((u32)f2bf(y) << 16);
}

// =============== device bodies ===============

// prep: weight-pack (bid<24) or x->bf16 convert
__device__ __forceinline__ void prep_body(int bid, const float* __restrict__ x, long total,
                                          const float* __restrict__ Wl1, const float* __restrict__ Wr1,
                                          const float* __restrict__ Wl2, const float* __restrict__ Wr2,
                                          u16* __restrict__ xb,
                                          u16* __restrict__ Pl1, u16* __restrict__ Pr1,
                                          u16* __restrict__ Pl2, u16* __restrict__ Pr2) {
    if (bid < 24) {
        int u = bid * 256 + threadIdx.x;
        if (u >= 6144) return;
        const float* W; u16* P; int O;
        if (u < 2048)      { W = Wl1; P = Pl1; O = 128; }
        else if (u < 4096) { W = Wr1; P = Pr1; O = 128; u -= 2048; }
        else if (u < 5120) { W = Wl2; P = Pl2; O = 64;  u -= 4096; }
        else               { W = Wr2; P = Pr2; O = 64;  u -= 5120; }
        int lane = u & 63, t = u >> 6;
        int ntiles = O / 16;
        int ks = t / ntiles, nt = t % ntiles;
        int k0 = ks * 32 + (lane >> 4) * 8;
        int col = nt * 16 + (lane & 15);
        bf16x8 o;
#pragma unroll
        for (int j = 0; j < 8; ++j) o[j] = (short)f2bf(W[(size_t)(k0 + j) * O + col]);
        *reinterpret_cast<bf16x8*>(P + (size_t)u * 8) = o;
    } else {
        long i = ((long)(bid - 24) * 256 + threadIdx.x) * 8;
        if (i >= total) return;
        float4 v0 = *reinterpret_cast<const float4*>(x + i);
        float4 v1 = *reinterpret_cast<const float4*>(x + i + 4);
        bf16x8 o;
        o[0] = (short)f2bf(v0.x); o[1] = (short)f2bf(v0.y);
        o[2] = (short)f2bf(v0.z); o[3] = (short)f2bf(v0.w);
        o[4] = (short)f2bf(v1.x); o[5] = (short)f2bf(v1.y);
        o[6] = (short)f2bf(v1.z); o[7] = (short)f2bf(v1.w);
        *reinterpret_cast<bf16x8*>(xb + i) = o;
    }
}

// count: per-WG LDS histogram of bucket sizes
__device__ __forceinline__ void count_body(int b, const int* __restrict__ ei, int E,
                                           int nB, int* __restrict__ bcnt, int* lcnt) {
    for (int i = threadIdx.x; i < nB; i += 256) lcnt[i] = 0;
    __syncthreads();
    const int base = b * CHUNK;
    const int end = min(base + CHUNK, E);
    for (int e = base + (int)threadIdx.x; e < end; e += 256)
        atomicAdd(&lcnt[ei[E + e] >> BSHIFT], 1);
    __syncthreads();
    for (int i = threadIdx.x; i < nB; i += 256)
        if (lcnt[i]) atomicAdd(&bcnt[i], lcnt[i]);
}

// partition: edges -> bucket-contiguous ebuf (packed dstLocal<<23 | src)
__device__ __forceinline__ void partition_body(int b, const int* __restrict__ ei, int E,
                                               int* __restrict__ bcur, u32* __restrict__ ebuf,
                                               int nB, int* lds) {
    int* lcnt = lds;
    int* lbase = lds + 1024;
    for (int i = threadIdx.x; i < nB; i += 256) lcnt[i] = 0;
    __syncthreads();
    const int base = b * CHUNK;

    u32 pk[EPT]; int bk[EPT];
#pragma unroll
    for (int k = 0; k < EPT; ++k) {
        int e = base + (int)threadIdx.x + k * 256;
        if (e < E) {
            int s = ei[e], d = ei[E + e];
            bk[k] = d >> BSHIFT;
            pk[k] = ((u32)(d & (BNODES - 1)) << 23) | (u32)s;
            atomicAdd(&lcnt[bk[k]], 1);
        } else bk[k] = -1;
    }
    __syncthreads();
    for (int i = threadIdx.x; i < nB; i += 256) {
        int c = lcnt[i];
        lbase[i] = c ? atomicAdd(&bcur[i], c) : 0;
        lcnt[i] = 0;                           // reuse as local cursor
    }
    __syncthreads();
#pragma unroll
    for (int k = 0; k < EPT; ++k) {
        if (bk[k] >= 0) {
            int p = lbase[bk[k]] + atomicAdd(&lcnt[bk[k]], 1);
            ebuf[p] = pk[k];
        }
    }
}

// build: one block per bucket -> rowptr + csr
__device__ __forceinline__ void build_body(int bkt, const u32* __restrict__ ebuf,
                                           const int* __restrict__ bbase, int n,
                                           int* __restrict__ rowptr, int* __restrict__ csr,
                                           int* lds) {
    int* hist   = lds;
    int* sstart = lds + BNODES;
    int* spart  = lds + 2 * BNODES;
    const int bb = bbase[bkt], be = bbase[bkt + 1];
    const int node0 = bkt << BSHIFT;

    for (int i = threadIdx.x; i < BNODES; i += 256) hist[i] = 0;
    __syncthreads();
    for (int e = bb + (int)threadIdx.x; e < be; e += 256)
        atomicAdd(&hist[ebuf[e] >> 23], 1);
    __syncthreads();

    const int t = threadIdx.x;
    const int v0 = hist[2 * t], v1 = hist[2 * t + 1];
    const int ts = v0 + v1;
    const int lane = t & 63, wave = t >> 6;
    int x = ts;
#pragma unroll
    for (int off = 1; off < 64; off <<= 1) { int y = __shfl_up(x, off); if (lane >= off) x += y; }
    if (lane == 63) spart[wave] = x;
    __syncthreads();
    int woff = 0;
#pragma unroll
    for (int w = 0; w < 4; ++w) if (w < wave) woff += spart[w];
    const int excl = woff + x - ts;
    sstart[2 * t] = excl;
    sstart[2 * t + 1] = excl + v0;
    const int nd0 = node0 + 2 * t, nd1 = node0 + 2 * t + 1;
    if (nd0 < n) rowptr[nd0] = bb + excl;
    if (nd1 < n) rowptr[nd1] = bb + excl + v0;
    for (int i = threadIdx.x; i < BNODES; i += 256) hist[i] = 0;
    __syncthreads();

    for (int e = bb + (int)threadIdx.x; e < be; e += 256) {
        u32 pkv = ebuf[e];
        int dl = pkv >> 23;
        int p = atomicAdd(&hist[dl], 1);
        csr[bb + sstart[dl] + p] = (int)(pkv & 0x7FFFFFu);
    }
}

// fused pair GEMM: y = A@Py, z = A@Pz + b; 16 rows/wave; LDS-staged epilogue
template<int O>
__device__ __forceinline__ void fused_gemm_body(int bid, const u16* __restrict__ A,
                                                const u16* __restrict__ Py, const u16* __restrict__ Pz,
                                                const float* __restrict__ bias,
                                                u16* __restrict__ yb, u16* __restrict__ zb,
                                                int n, u16* ldsAll) {
    constexpr int NT  = O / 16;
    constexpr int STR = O + 8;
    constexpr int C8  = O / 8;
    const int wave = threadIdx.x >> 6, lane = threadIdx.x & 63;
    const int row0 = (bid * 4 + wave) * 16;
    if (row0 >= n) return;
    const int lr = lane & 15, lg = lane >> 4;

    const int ra = min(row0 + lr, n - 1);
    const bf16x8* A8 = reinterpret_cast<const bf16x8*>(A + (size_t)ra * 128);
    const bf16x8* Y8 = reinterpret_cast<const bf16x8*>(Py) + lane;
    const bf16x8* Z8 = reinterpret_cast<const bf16x8*>(Pz) + lane;

    f32x4 accy[NT], accz[NT];
#pragma unroll
    for (int t = 0; t < NT; ++t) { accy[t] = (f32x4){0,0,0,0}; accz[t] = (f32x4){0,0,0,0}; }

#pragma unroll
    for (int ks = 0; ks < 4; ++ks) {
        bf16x8 a = A8[ks * 4 + lg];
#pragma unroll
        for (int t = 0; t < NT; ++t)
            accy[t] = __builtin_amdgcn_mfma_f32_16x16x32_bf16(a, Y8[(size_t)(ks * NT + t) * 64], accy[t], 0, 0, 0);
#pragma unroll
        for (int t = 0; t < NT; ++t)
            accz[t] = __builtin_amdgcn_mfma_f32_16x16x32_bf16(a, Z8[(size_t)(ks * NT + t) * 64], accz[t], 0, 0, 0);
    }

    u16* L = ldsAll + wave * 16 * STR;
    // phase Y (C/D layout: col=lane&15, row=(lane>>4)*4+r)
#pragma unroll
    for (int t = 0; t < NT; ++t)
#pragma unroll
        for (int r = 0; r < 4; ++r)
            L[(lg * 4 + r) * STR + t * 16 + lr] = f2bf(accy[t][r]);
#pragma unroll
    for (int it = 0; it < O / 32; ++it) {
        int idx = it * 64 + lane;
        int row = idx / C8, c8 = idx % C8;
        if (row0 + row < n)
            *reinterpret_cast<uint4*>(yb + (size_t)(row0 + row) * O + c8 * 8) =
                *reinterpret_cast<const uint4*>(&L[row * STR + c8 * 8]);
    }
    // phase Z (same buffer; wave-local WAR ordered by lgkmcnt)
#pragma unroll
    for (int t = 0; t < NT; ++t) {
        float bv = bias[t * 16 + lr];
#pragma unroll
        for (int r = 0; r < 4; ++r)
            L[(lg * 4 + r) * STR + t * 16 + lr] = f2bf(accz[t][r] + bv);
    }
#pragma unroll
    for (int it = 0; it < O / 32; ++it) {
        int idx = it * 64 + lane;
        int row = idx / C8, c8 = idx % C8;
        if (row0 + row < n)
            *reinterpret_cast<uint4*>(zb + (size_t)(row0 + row) * O + c8 * 8) =
                *reinterpret_cast<const uint4*>(&L[row * STR + c8 * 8]);
    }
}

// gather + relu combine (D=128): h = relu(mean y[src] + z)
__device__ __forceinline__ void gather_relu_body(int bid, const u16* __restrict__ y,
                                                 const int* __restrict__ rowptr,
                                                 const int* __restrict__ csr,
                                                 const u16* __restrict__ z,
                                                 u16* __restrict__ h, int n) {
    const int wave = threadIdx.x >> 6, lane = threadIdx.x & 63;
    const int l = lane & 15, g = lane >> 4;           // 16 lanes/node, 4 nodes/wave
    const int node = (bid * 4 + wave) * 4 + g;
    const bool ok = node < n;
    int start = 0, end = 0;
    if (ok) { start = rowptr[node]; end = rowptr[node + 1]; }

    float2 a0 = {0,0}, a1 = {0,0}, a2 = {0,0}, a3 = {0,0};
    int e = start;
    for (; e + 4 <= end; e += 4) {
        const int s0 = csr[e], s1 = csr[e + 1], s2 = csr[e + 2], s3 = csr[e + 3];
        uint4 v0 = *reinterpret_cast<const uint4*>(y + (size_t)s0 * 128 + l * 8);
        uint4 v1 = *reinterpret_cast<const uint4*>(y + (size_t)s1 * 128 + l * 8);
        uint4 v2 = *reinterpret_cast<const uint4*>(y + (size_t)s2 * 128 + l * 8);
        uint4 v3 = *reinterpret_cast<const uint4*>(y + (size_t)s3 * 128 + l * 8);
        accp(a0, v0.x); accp(a1, v0.y); accp(a2, v0.z); accp(a3, v0.w);
        accp(a0, v1.x); accp(a1, v1.y); accp(a2, v1.z); accp(a3, v1.w);
        accp(a0, v2.x); accp(a1, v2.y); accp(a2, v2.z); accp(a3, v2.w);
        accp(a0, v3.x); accp(a1, v3.y); accp(a2, v3.z); accp(a3, v3.w);
    }
    for (; e < end; ++e) {
        const int s0 = csr[e];
        uint4 v0 = *reinterpret_cast<const uint4*>(y + (size_t)s0 * 128 + l * 8);
        accp(a0, v0.x); accp(a1, v0.y); accp(a2, v0.z); accp(a3, v0.w);
    }

    if (ok) {
        const float inv = 1.0f / fmaxf((float)(end - start), 1.0f);
        uint4 zr = *reinterpret_cast<const uint4*>(z + (size_t)node * 128 + l * 8);
        uint4 o;
        o.x = pack2(fmaxf(a0.x * inv + blo(zr.x), 0.f), fmaxf(a0.y * inv + bhi(zr.x), 0.f));
        o.y = pack2(fmaxf(a1.x * inv + blo(zr.y), 0.f), fmaxf(a1.y * inv + bhi(zr.y), 0.f));
        o.z = pack2(fmaxf(a2.x * inv + blo(zr.z), 0.f), fmaxf(a2.y * inv + bhi(zr.z), 0.f));
        o.w = pack2(fmaxf(a3.x * inv + blo(zr.w), 0.f), fmaxf(a3.y * inv + bhi(zr.w), 0.f));
        *reinterpret_cast<uint4*>(h + (size_t)node * 128 + l * 8) = o;
    }
}

// =============== merged kernels ===============

__global__ __launch_bounds__(256) void prep_count(const float* __restrict__ x, long total,
                                                  const float* __restrict__ Wl1, const float* __restrict__ Wr1,
                                                  const float* __restrict__ Wl2, const float* __restrict__ Wr2,
                                                  u16* __restrict__ xb,
                                                  u16* __restrict__ Pl1, u16* __restrict__ Pr1,
                                                  u16* __restrict__ Pl2, u16* __restrict__ Pr2,
                                                  int ngPrep,
                                                  const int* __restrict__ ei1, int E1, int ng1, int* __restrict__ bc1,
                                                  const int* __restrict__ ei2, int E2, int* __restrict__ bc2, int nB) {
    __shared__ int lcnt[1024];
    const int b = blockIdx.x;
    if (b < ngPrep) {
        prep_body(b, x, total, Wl1, Wr1, Wl2, Wr2, xb, Pl1, Pr1, Pl2, Pr2);
    } else {
        int c = b - ngPrep;
        if (c < ng1) count_body(c, ei1, E1, nB, bc1, lcnt);
        else         count_body(c - ng1, ei2, E2, nB, bc2, lcnt);
    }
}

__global__ void bucket_scan_both(const int* __restrict__ bc1, int* __restrict__ bbase1,
                                 int* __restrict__ bcur1, int* __restrict__ rp1, int E1,
                                 const int* __restrict__ bc2, int* __restrict__ bbase2,
                                 int* __restrict__ bcur2, int* __restrict__ rp2, int E2,
                                 int nB, int n) {
    const int* bcnt; int* bbase; int* bcur; int* rowptr; int E;
    if (blockIdx.x == 0) { bcnt = bc1; bbase = bbase1; bcur = bcur1; rowptr = rp1; E = E1; }
    else                 { bcnt = bc2; bbase = bbase2; bcur = bcur2; rowptr = rp2; E = E2; }
    const int lane = threadIdx.x;           // 64 threads
    int run = 0;
    for (int r = 0; r < nB; r += 64) {
        int i = r + lane;
        int v = (i < nB) ? bcnt[i] : 0;
        int x = v;
#pragma unroll
        for (int off = 1; off < 64; off <<= 1) { int y = __shfl_up(x, off); if (lane >= off) x += y; }
        int excl = run + x - v;
        if (i < nB) { bbase[i] = excl; bcur[i] = excl; }
        run += __shfl(x, 63);
    }
    if (lane == 0) { bbase[nB] = run; rowptr[n] = E; }
}

// partition (both layers) || fused_gemm<128>
__global__ __launch_bounds__(256, 4) void part_gemm1(const int* __restrict__ ei1, int E1, int ng1,
                                                     int* __restrict__ bcur1, u32* __restrict__ eb1,
                                                     const int* __restrict__ ei2, int E2,
                                                     int* __restrict__ bcur2, u32* __restrict__ eb2,
                                                     int nB, int ngp,
                                                     const u16* __restrict__ A,
                                                     const u16* __restrict__ Py, const u16* __restrict__ Pz,
                                                     const float* __restrict__ bias,
                                                     u16* __restrict__ yb, u16* __restrict__ zb, int n) {
    __shared__ __align__(16) char smem[4 * 16 * (128 + 8) * 2];   // 17408 B (>= 8192 partition)
    const int b = blockIdx.x;
    if (b < ngp) {
        if (b < ng1) partition_body(b, ei1, E1, bcur1, eb1, nB, (int*)smem);
        else         partition_body(b - ng1, ei2, E2, bcur2, eb2, nB, (int*)smem);
    } else {
        fused_gemm_body<128>(b - ngp, A, Py, Pz, bias, yb, zb, n, (u16*)smem);
    }
}

__global__ __launch_bounds__(256) void build_kernel(const u32* __restrict__ ebuf,
                                                    const int* __restrict__ bbase, int n,
                                                    int* __restrict__ rowptr, int* __restrict__ csr) {
    __shared__ int smem[2 * BNODES + 16];
    build_body(blockIdx.x, ebuf, bbase, n, rowptr, csr, smem);
}

// gather_relu (layer 1) || build (layer 2)
__global__ __launch_bounds__(256) void gather_relu_build2(const u16* __restrict__ y,
                                                          const int* __restrict__ rp1,
                                                          const int* __restrict__ csr1,
                                                          const u16* __restrict__ z,
                                                          u16* __restrict__ h, int n, int gbG,
                                                          const u32* __restrict__ eb2,
                                                          const int* __restrict__ bbase2,
                                                          int* __restrict__ rp2, int* __restrict__ csr2) {
    __shared__ int smem[2 * BNODES + 16];
    const int b = blockIdx.x;
    if (b < gbG) gather_relu_body(b, y, rp1, csr1, z, h, n);
    else         build_body(b - gbG, eb2, bbase2, n, rp2, csr2, smem);
}

__global__ __launch_bounds__(256, 4) void gemm2_kernel(const u16* __restrict__ A,
                                                       const u16* __restrict__ Py, const u16* __restrict__ Pz,
                                                       const float* __restrict__ bias,
                                                       u16* __restrict__ yb, u16* __restrict__ zb, int n) {
    __shared__ __align__(16) u16 lds[4 * 16 * (64 + 8)];
    fused_gemm_body<64>(blockIdx.x, A, Py, Pz, bias, yb, zb, n, lds);
}

// gather + log_softmax combine (D=64, f32 out)
__global__ __launch_bounds__(256) void gather_lsm(const u16* __restrict__ y,
                                                  const int* __restrict__ rowptr,
                                                  const int* __restrict__ csr,
                                                  const u16* __restrict__ z,
                                                  float* __restrict__ out, int n) {
    const int wave = threadIdx.x >> 6, lane = threadIdx.x & 63;
    const int l = lane & 7, g = lane >> 3;            // 8 lanes/node, 8 nodes/wave
    const int node = (blockIdx.x * 4 + wave) * 8 + g;
    const bool ok = node < n;
    int start = 0, end = 0;
    if (ok) { start = rowptr[node]; end = rowptr[node + 1]; }

    float2 a0 = {0,0}, a1 = {0,0}, a2 = {0,0}, a3 = {0,0};
    int e = start;
    for (; e + 4 <= end; e += 4) {
        const int s0 = csr[e], s1 = csr[e + 1], s2 = csr[e + 2], s3 = csr[e + 3];
        uint4 v0 = *reinterpret_cast<const uint4*>(y + (size_t)s0 * 64 + l * 8);
        uint4 v1 = *reinterpret_cast<const uint4*>(y + (size_t)s1 * 64 + l * 8);
        uint4 v2 = *reinterpret_cast<const uint4*>(y + (size_t)s2 * 64 + l * 8);
        uint4 v3 = *reinterpret_cast<const uint4*>(y + (size_t)s3 * 64 + l * 8);
        accp(a0, v0.x); accp(a1, v0.y); accp(a2, v0.z); accp(a3, v0.w);
        accp(a0, v1.x); accp(a1, v1.y); accp(a2, v1.z); accp(a3, v1.w);
        accp(a0, v2.x); accp(a1, v2.y); accp(a2, v2.z); accp(a3, v2.w);
        accp(a0, v3.x); accp(a1, v3.y); accp(a2, v3.z); accp(a3, v3.w);
    }
    for (; e < end; ++e) {
        const int s0 = csr[e];
        uint4 v0 = *reinterpret_cast<const uint4*>(y + (size_t)s0 * 64 + l * 8);
        accp(a0, v0.x); accp(a1, v0.y); accp(a2, v0.z); accp(a3, v0.w);
    }

    if (ok) {
        const float inv = 1.0f / fmaxf((float)(end - start), 1.0f);
        uint4 zr = *reinterpret_cast<const uint4*>(z + (size_t)node * 64 + l * 8);
        float v0 = a0.x * inv + blo(zr.x), v1 = a0.y * inv + bhi(zr.x);
        float v2 = a1.x * inv + blo(zr.y), v3 = a1.y * inv + bhi(zr.y);
        float v4 = a2.x * inv + blo(zr.z), v5 = a2.y * inv + bhi(zr.z);
        float v6 = a3.x * inv + blo(zr.w), v7 = a3.y * inv + bhi(zr.w);

        float m = fmaxf(fmaxf(fmaxf(v0, v1), fmaxf(v2, v3)), fmaxf(fmaxf(v4, v5), fmaxf(v6, v7)));
        m = fmaxf(m, __shfl_xor(m, 1));
        m = fmaxf(m, __shfl_xor(m, 2));
        m = fmaxf(m, __shfl_xor(m, 4));
        float s = expf(v0 - m) + expf(v1 - m) + expf(v2 - m) + expf(v3 - m) +
                  expf(v4 - m) + expf(v5 - m) + expf(v6 - m) + expf(v7 - m);
        s += __shfl_xor(s, 1);
        s += __shfl_xor(s, 2);
        s += __shfl_xor(s, 4);
        const float c = m + logf(s);
        float* op = out + (size_t)node * 64 + l * 8;
        *reinterpret_cast<float4*>(op)     = (float4){v0 - c, v1 - c, v2 - c, v3 - c};
        *reinterpret_cast<float4*>(op + 4) = (float4){v4 - c, v5 - c, v6 - c, v7 - c};
    }
}

extern "C" void kernel_launch(void* const* d_in, const int* in_sizes, int n_in,
                              void* d_out, int out_size, void* d_ws, size_t ws_size,
                              hipStream_t stream) {
    const float* x    = (const float*)d_in[0];
    const int*   ei1  = (const int*)d_in[1];
    const int*   ei2  = (const int*)d_in[2];
    const float* W_l1 = (const float*)d_in[3];
    const float* b_l1 = (const float*)d_in[4];
    const float* W_r1 = (const float*)d_in[5];
    const float* W_l2 = (const float*)d_in[6];
    const float* b_l2 = (const float*)d_in[7];
    const float* W_r2 = (const float*)d_in[8];

    const int n  = in_sizes[0] / 128;
    const int E1 = in_sizes[1] / 2;
    const int E2 = in_sizes[2] / 2;
    const int nB = (n + BNODES - 1) >> BSHIFT;   // <= 1024
    const int ng1 = (E1 + CHUNK - 1) / CHUNK;
    const int ng2 = (E2 + CHUNK - 1) / CHUNK;

    // ws layout:
    char* w = (char*)d_ws;
    u16* xb  = (u16*)w; w += (size_t)n * 128 * 2;   // x bf16
    u16* hb  = (u16*)w; w += (size_t)n * 128 * 2;   // h; eb1 aliases this
    u16* yb  = (u16*)w; w += (size_t)n * 128 * 2;   // y (L1 nx128 / L2 nx64)
    u16* zb  = (u16*)w; w += (size_t)n * 128 * 2;   // z (L1 nx128 / L2 nx64)
    u16* Pl1 = (u16*)w; w += 16384 * 2;
    u16* Pr1 = (u16*)w; w += 16384 * 2;
    u16* Pl2 = (u16*)w; w += 8192 * 2;
    u16* Pr2 = (u16*)w; w += 8192 * 2;
    int* rp1   = (int*)w; w += (size_t)(n + 1) * 4;
    int* rp2   = (int*)w; w += (size_t)(n + 1) * 4;
    int* bcnt  = (int*)w; w += 2048 * 4;            // bc1 | bc2
    int* bbase1= (int*)w; w += 1025 * 4;
    int* bbase2= (int*)w; w += 1025 * 4;
    int* bcur1 = (int*)w; w += 1024 * 4;
    int* bcur2 = (int*)w; w += 1024 * 4;
    int* csr1  = (int*)w; w += (size_t)E1 * 4;
    int* csr2  = (int*)w; w += (size_t)E2 * 4;
    // eb1 aliases hb (dead until gather_relu writes h, after build1 consumed it).
    u32* eb1 = (u32*)hb;
    // eb2: dedicated region if ws allows (enables gather_relu || build2 overlap);
    // else alias hb after eb1 (forces build2 before gather_relu).
    size_t used = (size_t)(w - (char*)d_ws);
    bool dedicated = (used + (size_t)E2 * 4) <= ws_size;
    u32* eb2 = dedicated ? (u32*)w : eb1 + E1;

    const int convB  = (int)(((long)n * 128 / 8 + 255) / 256);
    const int ngPrep = 24 + convB;
    const int ngp    = ng1 + ng2;
    const int gb     = (n + 63) / 64;     // fused gemm: 64 rows/block
    const int gbG    = (n + 15) / 16;     // gather_relu: 16 nodes/block

    hipMemsetAsync(bcnt, 0, 2048 * sizeof(int), stream);

    // L0: prep || count(both layers)
    prep_count<<<ngPrep + ngp, 256, 0, stream>>>(x, (long)n * 128, W_l1, W_r1, W_l2, W_r2,
                                                 xb, Pl1, Pr1, Pl2, Pr2, ngPrep,
                                                 ei1, E1, ng1, bcnt, ei2, E2, bcnt + 1024, nB);
    // L1: scan both
    bucket_scan_both<<<2, 64, 0, stream>>>(bcnt, bbase1, bcur1, rp1, E1,
                                           bcnt + 1024, bbase2, bcur2, rp2, E2, nB, n);
    // L2: partition(both) || gemm1
    part_gemm1<<<ngp + gb, 256, 0, stream>>>(ei1, E1, ng1, bcur1, eb1, ei2, E2, bcur2, eb2,
                                             nB, ngp, xb, Pl1, Pr1, b_l1, yb, zb, n);
    if (dedicated) {
        // L3: build layer 1; L4: gather_relu || build layer 2
        build_kernel<<<nB, 256, 0, stream>>>(eb1, bbase1, n, rp1, csr1);
        gather_relu_build2<<<gbG + nB, 256, 0, stream>>>(yb, rp1, csr1, zb, hb, n, gbG,
                                                         eb2, bbase2, rp2, csr2);
    } else {
        build_kernel<<<nB, 256, 0, stream>>>(eb1, bbase1, n, rp1, csr1);
        build_kernel<<<nB, 256, 0, stream>>>(eb2, bbase2, n, rp2, csr2);
        gather_relu_build2<<<gbG, 256, 0, stream>>>(yb, rp1, csr1, zb, hb, n, gbG,
                                                    eb2, bbase2, rp2, csr2);
    }
    // L5: gemm2; L6: gather + log_softmax
    gemm2_kernel<<<gb, 256, 0, stream>>>(hb, Pl2, Pr2, b_l2, yb, zb, n);
    gather_lsm<<<(n + 31) / 32, 256, 0, stream>>>(yb, rp2, csr2, zb, (float*)d_out, n);
}

// Round 11
// 172.044 us; speedup vs baseline: 8.5567x; 1.0836x over previous
//
#include <hip/hip_runtime.h>
#include <hip/hip_bf16.h>

// GraphSAGE 2-layer forward on MI355X — wave-local fusion edition.
// mean(x[src]) @ W == mean((x@W)[src]).
// Pipeline: [pack||count] -> [scan] -> [partition||gemm1(f32 A)] -> [build_both]
//   -> [gather1+relu+gemm2 fused, wave-local LDS, no barriers] -> [gather2+lsm].
// Round-10 lessons: merging two memory-bound stages = sum not max (reverted
// gather||build); h round-trip + x-convert pass eliminated instead.

typedef __attribute__((ext_vector_type(8))) short bf16x8;
typedef __attribute__((ext_vector_type(4))) float f32x4;
typedef unsigned int u32;
typedef unsigned short u16;

constexpr int BSHIFT = 9;             // 512 nodes per bucket
constexpr int BNODES = 1 << BSHIFT;
constexpr int CHUNK  = 4096;          // edges per workgroup in bucket kernels
constexpr int EPT    = CHUNK / 256;   // 16 edges per thread

__device__ __forceinline__ u16 f2bf(float f) {
    u32 u = __float_as_uint(f);
    return (u16)((u + 0x7fffu + ((u >> 16) & 1u)) >> 16);
}
__device__ __forceinline__ float blo(u32 u) { return __uint_as_float(u << 16); }
__device__ __forceinline__ float bhi(u32 u) { return __uint_as_float(u & 0xffff0000u); }
__device__ __forceinline__ void accp(float2& a, u32 u) { a.x += blo(u); a.y += bhi(u); }
__device__ __forceinline__ u32 pack2(float x, float y) {
    return (u32)f2bf(x) | ((u32)f2bf(y) << 16);
}

// =============== device bodies ===============

// weight pack: W[K=128][O] -> MFMA B-fragment order (24 blocks)
__device__ __forceinline__ void pack_body(int bid,
                                          const float* __restrict__ Wl1, const float* __restrict__ Wr1,
                                          const float* __restrict__ Wl2, const float* __restrict__ Wr2,
                                          u16* __restrict__ Pl1, u16* __restrict__ Pr1,
                                          u16* __restrict__ Pl2, u16* __restrict__ Pr2) {
    int u = bid * 256 + threadIdx.x;
    if (u >= 6144) return;
    const float* W; u16* P; int O;
    if (u < 2048)      { W = Wl1; P = Pl1; O = 128; }
    else if (u < 4096) { W = Wr1; P = Pr1; O = 128; u -= 2048; }
    else if (u < 5120) { W = Wl2; P = Pl2; O = 64;  u -= 4096; }
    else               { W = Wr2; P = Pr2; O = 64;  u -= 5120; }
    int lane = u & 63, t = u >> 6;
    int ntiles = O / 16;
    int ks = t / ntiles, nt = t % ntiles;
    int k0 = ks * 32 + (lane >> 4) * 8;
    int col = nt * 16 + (lane & 15);
    bf16x8 o;
#pragma unroll
    for (int j = 0; j < 8; ++j) o[j] = (short)f2bf(W[(size_t)(k0 + j) * O + col]);
    *reinterpret_cast<bf16x8*>(P + (size_t)u * 8) = o;
}

// count: per-WG LDS histogram of bucket sizes
__device__ __forceinline__ void count_body(int b, const int* __restrict__ ei, int E,
                                           int nB, int* __restrict__ bcnt, int* lcnt) {
    for (int i = threadIdx.x; i < nB; i += 256) lcnt[i] = 0;
    __syncthreads();
    const int base = b * CHUNK;
    const int end = min(base + CHUNK, E);
    for (int e = base + (int)threadIdx.x; e < end; e += 256)
        atomicAdd(&lcnt[ei[E + e] >> BSHIFT], 1);
    __syncthreads();
    for (int i = threadIdx.x; i < nB; i += 256)
        if (lcnt[i]) atomicAdd(&bcnt[i], lcnt[i]);
}

// partition: edges -> bucket-contiguous ebuf (packed dstLocal<<23 | src)
__device__ __forceinline__ void partition_body(int b, const int* __restrict__ ei, int E,
                                               int* __restrict__ bcur, u32* __restrict__ ebuf,
                                               int nB, int* lds) {
    int* lcnt = lds;
    int* lbase = lds + 1024;
    for (int i = threadIdx.x; i < nB; i += 256) lcnt[i] = 0;
    __syncthreads();
    const int base = b * CHUNK;

    u32 pk[EPT]; int bk[EPT];
#pragma unroll
    for (int k = 0; k < EPT; ++k) {
        int e = base + (int)threadIdx.x + k * 256;
        if (e < E) {
            int s = ei[e], d = ei[E + e];
            bk[k] = d >> BSHIFT;
            pk[k] = ((u32)(d & (BNODES - 1)) << 23) | (u32)s;
            atomicAdd(&lcnt[bk[k]], 1);
        } else bk[k] = -1;
    }
    __syncthreads();
    for (int i = threadIdx.x; i < nB; i += 256) {
        int c = lcnt[i];
        lbase[i] = c ? atomicAdd(&bcur[i], c) : 0;
        lcnt[i] = 0;                           // reuse as local cursor
    }
    __syncthreads();
#pragma unroll
    for (int k = 0; k < EPT; ++k) {
        if (bk[k] >= 0) {
            int p = lbase[bk[k]] + atomicAdd(&lcnt[bk[k]], 1);
            ebuf[p] = pk[k];
        }
    }
}

// build: one block per bucket -> rowptr + csr
__device__ __forceinline__ void build_body(int bkt, const u32* __restrict__ ebuf,
                                           const int* __restrict__ bbase, int n,
                                           int* __restrict__ rowptr, int* __restrict__ csr,
                                           int* lds) {
    int* hist   = lds;
    int* sstart = lds + BNODES;
    int* spart  = lds + 2 * BNODES;
    const int bb = bbase[bkt], be = bbase[bkt + 1];
    const int node0 = bkt << BSHIFT;

    for (int i = threadIdx.x; i < BNODES; i += 256) hist[i] = 0;
    __syncthreads();
    for (int e = bb + (int)threadIdx.x; e < be; e += 256)
        atomicAdd(&hist[ebuf[e] >> 23], 1);
    __syncthreads();

    const int t = threadIdx.x;
    const int v0 = hist[2 * t], v1 = hist[2 * t + 1];
    const int ts = v0 + v1;
    const int lane = t & 63, wave = t >> 6;
    int x = ts;
#pragma unroll
    for (int off = 1; off < 64; off <<= 1) { int y = __shfl_up(x, off); if (lane >= off) x += y; }
    if (lane == 63) spart[wave] = x;
    __syncthreads();
    int woff = 0;
#pragma unroll
    for (int w = 0; w < 4; ++w) if (w < wave) woff += spart[w];
    const int excl = woff + x - ts;
    sstart[2 * t] = excl;
    sstart[2 * t + 1] = excl + v0;
    const int nd0 = node0 + 2 * t, nd1 = node0 + 2 * t + 1;
    if (nd0 < n) rowptr[nd0] = bb + excl;
    if (nd1 < n) rowptr[nd1] = bb + excl + v0;
    for (int i = threadIdx.x; i < BNODES; i += 256) hist[i] = 0;
    __syncthreads();

    for (int e = bb + (int)threadIdx.x; e < be; e += 256) {
        u32 pkv = ebuf[e];
        int dl = pkv >> 23;
        int p = atomicAdd(&hist[dl], 1);
        csr[bb + sstart[dl] + p] = (int)(pkv & 0x7FFFFFu);
    }
}

// fused pair GEMM: y = A@Py, z = A@Pz + b; 16 rows/wave; LDS-staged epilogue.
// F32A: A is fp32 (convert fragments in-register; kills the separate convert pass).
template<int O, bool F32A>
__device__ __forceinline__ void fused_gemm_body(int bid, const void* __restrict__ Av,
                                                const u16* __restrict__ Py, const u16* __restrict__ Pz,
                                                const float* __restrict__ bias,
                                                u16* __restrict__ yb, u16* __restrict__ zb,
                                                int n, u16* ldsAll) {
    constexpr int NT  = O / 16;
    constexpr int STR = O + 8;
    constexpr int C8  = O / 8;
    const int wave = threadIdx.x >> 6, lane = threadIdx.x & 63;
    const int row0 = (bid * 4 + wave) * 16;
    if (row0 >= n) return;
    const int lr = lane & 15, lg = lane >> 4;

    const int ra = min(row0 + lr, n - 1);
    const bf16x8* Y8 = reinterpret_cast<const bf16x8*>(Py) + lane;
    const bf16x8* Z8 = reinterpret_cast<const bf16x8*>(Pz) + lane;

    f32x4 accy[NT], accz[NT];
#pragma unroll
    for (int t = 0; t < NT; ++t) { accy[t] = (f32x4){0,0,0,0}; accz[t] = (f32x4){0,0,0,0}; }

#pragma unroll
    for (int ks = 0; ks < 4; ++ks) {
        bf16x8 a;
        if (F32A) {
            const float* Af = (const float*)Av + (size_t)ra * 128 + (ks * 4 + lg) * 8;
            float4 u0 = *reinterpret_cast<const float4*>(Af);
            float4 u1 = *reinterpret_cast<const float4*>(Af + 4);
            a[0] = (short)f2bf(u0.x); a[1] = (short)f2bf(u0.y);
            a[2] = (short)f2bf(u0.z); a[3] = (short)f2bf(u0.w);
            a[4] = (short)f2bf(u1.x); a[5] = (short)f2bf(u1.y);
            a[6] = (short)f2bf(u1.z); a[7] = (short)f2bf(u1.w);
        } else {
            a = *reinterpret_cast<const bf16x8*>((const u16*)Av + (size_t)ra * 128 + (ks * 4 + lg) * 8);
        }
#pragma unroll
        for (int t = 0; t < NT; ++t)
            accy[t] = __builtin_amdgcn_mfma_f32_16x16x32_bf16(a, Y8[(size_t)(ks * NT + t) * 64], accy[t], 0, 0, 0);
#pragma unroll
        for (int t = 0; t < NT; ++t)
            accz[t] = __builtin_amdgcn_mfma_f32_16x16x32_bf16(a, Z8[(size_t)(ks * NT + t) * 64], accz[t], 0, 0, 0);
    }

    u16* L = ldsAll + wave * 16 * STR;
    // phase Y (C/D layout: col=lane&15, row=(lane>>4)*4+r)
#pragma unroll
    for (int t = 0; t < NT; ++t)
#pragma unroll
        for (int r = 0; r < 4; ++r)
            L[(lg * 4 + r) * STR + t * 16 + lr] = f2bf(accy[t][r]);
#pragma unroll
    for (int it = 0; it < O / 32; ++it) {
        int idx = it * 64 + lane;
        int row = idx / C8, c8 = idx % C8;
        if (row0 + row < n)
            *reinterpret_cast<uint4*>(yb + (size_t)(row0 + row) * O + c8 * 8) =
                *reinterpret_cast<const uint4*>(&L[row * STR + c8 * 8]);
    }
    // phase Z (same buffer; wave-local WAR ordered by lgkmcnt)
#pragma unroll
    for (int t = 0; t < NT; ++t) {
        float bv = bias[t * 16 + lr];
#pragma unroll
        for (int r = 0; r < 4; ++r)
            L[(lg * 4 + r) * STR + t * 16 + lr] = f2bf(accz[t][r] + bv);
    }
#pragma unroll
    for (int it = 0; it < O / 32; ++it) {
        int idx = it * 64 + lane;
        int row = idx / C8, c8 = idx % C8;
        if (row0 + row < n)
            *reinterpret_cast<uint4*>(zb + (size_t)(row0 + row) * O + c8 * 8) =
                *reinterpret_cast<const uint4*>(&L[row * STR + c8 * 8]);
    }
}

// =============== kernels ===============

__global__ __launch_bounds__(256) void pack_count(const float* __restrict__ Wl1, const float* __restrict__ Wr1,
                                                  const float* __restrict__ Wl2, const float* __restrict__ Wr2,
                                                  u16* __restrict__ Pl1, u16* __restrict__ Pr1,
                                                  u16* __restrict__ Pl2, u16* __restrict__ Pr2,
                                                  const int* __restrict__ ei1, int E1, int ng1, int* __restrict__ bc1,
                                                  const int* __restrict__ ei2, int E2, int* __restrict__ bc2, int nB) {
    __shared__ int lcnt[1024];
    const int b = blockIdx.x;
    if (b < 24) {
        pack_body(b, Wl1, Wr1, Wl2, Wr2, Pl1, Pr1, Pl2, Pr2);
    } else {
        int c = b - 24;
        if (c < ng1) count_body(c, ei1, E1, nB, bc1, lcnt);
        else         count_body(c - ng1, ei2, E2, nB, bc2, lcnt);
    }
}

__global__ void bucket_scan_both(const int* __restrict__ bc1, int* __restrict__ bbase1,
                                 int* __restrict__ bcur1, int* __restrict__ rp1, int E1,
                                 const int* __restrict__ bc2, int* __restrict__ bbase2,
                                 int* __restrict__ bcur2, int* __restrict__ rp2, int E2,
                                 int nB, int n) {
    const int* bcnt; int* bbase; int* bcur; int* rowptr; int E;
    if (blockIdx.x == 0) { bcnt = bc1; bbase = bbase1; bcur = bcur1; rowptr = rp1; E = E1; }
    else                 { bcnt = bc2; bbase = bbase2; bcur = bcur2; rowptr = rp2; E = E2; }
    const int lane = threadIdx.x;           // 64 threads
    int run = 0;
    for (int r = 0; r < nB; r += 64) {
        int i = r + lane;
        int v = (i < nB) ? bcnt[i] : 0;
        int x = v;
#pragma unroll
        for (int off = 1; off < 64; off <<= 1) { int y = __shfl_up(x, off); if (lane >= off) x += y; }
        int excl = run + x - v;
        if (i < nB) { bbase[i] = excl; bcur[i] = excl; }
        run += __shfl(x, 63);
    }
    if (lane == 0) { bbase[nB] = run; rowptr[n] = E; }
}

// partition (both layers) || gemm1 (reads x as f32 directly)
__global__ __launch_bounds__(256, 4) void part_gemm1(const int* __restrict__ ei1, int E1, int ng1,
                                                     int* __restrict__ bcur1, u32* __restrict__ eb1,
                                                     const int* __restrict__ ei2, int E2,
                                                     int* __restrict__ bcur2, u32* __restrict__ eb2,
                                                     int nB, int ngp,
                                                     const float* __restrict__ x,
                                                     const u16* __restrict__ Py, const u16* __restrict__ Pz,
                                                     const float* __restrict__ bias,
                                                     u16* __restrict__ yb, u16* __restrict__ zb, int n) {
    __shared__ __align__(16) char smem[4 * 16 * (128 + 8) * 2];   // 17408 B (>= 8192 partition)
    const int b = blockIdx.x;
    if (b < ngp) {
        if (b < ng1) partition_body(b, ei1, E1, bcur1, eb1, nB, (int*)smem);
        else         partition_body(b - ng1, ei2, E2, bcur2, eb2, nB, (int*)smem);
    } else {
        fused_gemm_body<128, true>(b - ngp, x, Py, Pz, bias, yb, zb, n, (u16*)smem);
    }
}

__global__ __launch_bounds__(256) void build_both(const u32* __restrict__ eb1,
                                                  const int* __restrict__ bbase1,
                                                  int* __restrict__ rp1, int* __restrict__ csr1,
                                                  const u32* __restrict__ eb2,
                                                  const int* __restrict__ bbase2,
                                                  int* __restrict__ rp2, int* __restrict__ csr2,
                                                  int nB, int n) {
    __shared__ int smem[2 * BNODES + 16];
    int bkt = blockIdx.x;
    if (bkt < nB) build_body(bkt, eb1, bbase1, n, rp1, csr1, smem);
    else          build_body(bkt - nB, eb2, bbase2, n, rp2, csr2, smem);
}

// ---- fused: gather1 + relu + gemm2. Wave-local (16 nodes/wave), NO barriers.
// h = relu(mean y1[src] + z1) lives only in LDS; y2 = h@Pl2, z2 = h@Pr2 + b2.
__global__ __launch_bounds__(256) void gather_gemm2(const u16* __restrict__ y1,
                                                    const int* __restrict__ rp1,
                                                    const int* __restrict__ csr1,
                                                    const u16* __restrict__ z1,
                                                    const u16* __restrict__ Pl2,
                                                    const u16* __restrict__ Pr2,
                                                    const float* __restrict__ bias,
                                                    u16* __restrict__ y2, u16* __restrict__ z2,
                                                    int n) {
    constexpr int STR = 136;                   // u16 stride (272 B, 16B-aligned)
    __shared__ __align__(16) u16 H[4][16 * STR];
    const int wave = threadIdx.x >> 6, lane = threadIdx.x & 63;
    const int l = lane & 15, g = lane >> 4;
    const int nb0 = blockIdx.x * 64 + wave * 16;   // this wave's 16 nodes
    if (nb0 >= n) return;
    u16* Hw = H[wave];

    // phase 1: gather + relu -> LDS (4 rounds x 4 concurrent nodes)
    for (int r = 0; r < 4; ++r) {
        const int lrow = r * 4 + g;
        const int node = nb0 + lrow;
        uint4 o = {0u, 0u, 0u, 0u};
        if (node < n) {
            const int start = rp1[node], end = rp1[node + 1];
            float2 a0 = {0,0}, a1 = {0,0}, a2 = {0,0}, a3 = {0,0};
            int e = start;
            for (; e + 4 <= end; e += 4) {
                const int s0 = csr1[e], s1 = csr1[e + 1], s2 = csr1[e + 2], s3 = csr1[e + 3];
                uint4 v0 = *reinterpret_cast<const uint4*>(y1 + (size_t)s0 * 128 + l * 8);
                uint4 v1 = *reinterpret_cast<const uint4*>(y1 + (size_t)s1 * 128 + l * 8);
                uint4 v2 = *reinterpret_cast<const uint4*>(y1 + (size_t)s2 * 128 + l * 8);
                uint4 v3 = *reinterpret_cast<const uint4*>(y1 + (size_t)s3 * 128 + l * 8);
                accp(a0, v0.x); accp(a1, v0.y); accp(a2, v0.z); accp(a3, v0.w);
                accp(a0, v1.x); accp(a1, v1.y); accp(a2, v1.z); accp(a3, v1.w);
                accp(a0, v2.x); accp(a1, v2.y); accp(a2, v2.z); accp(a3, v2.w);
                accp(a0, v3.x); accp(a1, v3.y); accp(a2, v3.z); accp(a3, v3.w);
            }
            for (; e < end; ++e) {
                const int s0 = csr1[e];
                uint4 v0 = *reinterpret_cast<const uint4*>(y1 + (size_t)s0 * 128 + l * 8);
                accp(a0, v0.x); accp(a1, v0.y); accp(a2, v0.z); accp(a3, v0.w);
            }
            const float inv = 1.0f / fmaxf((float)(end - start), 1.0f);
            uint4 zr = *reinterpret_cast<const uint4*>(z1 + (size_t)node * 128 + l * 8);
            o.x = pack2(fmaxf(a0.x * inv + blo(zr.x), 0.f), fmaxf(a0.y * inv + bhi(zr.x), 0.f));
            o.y = pack2(fmaxf(a1.x * inv + blo(zr.y), 0.f), fmaxf(a1.y * inv + bhi(zr.y), 0.f));
            o.z = pack2(fmaxf(a2.x * inv + blo(zr.z), 0.f), fmaxf(a2.y * inv + bhi(zr.z), 0.f));
            o.w = pack2(fmaxf(a3.x * inv + blo(zr.w), 0.f), fmaxf(a3.y * inv + bhi(zr.w), 0.f));
        }
        *reinterpret_cast<uint4*>(&Hw[lrow * STR + l * 8]) = o;
    }

    // phase 2: MFMA 16 rows x {Pl2, Pr2}  (A-frags from own LDS rows)
    const bf16x8* Y8 = reinterpret_cast<const bf16x8*>(Pl2) + lane;
    const bf16x8* Z8 = reinterpret_cast<const bf16x8*>(Pr2) + lane;
    f32x4 ay[4], az[4];
#pragma unroll
    for (int t = 0; t < 4; ++t) { ay[t] = (f32x4){0,0,0,0}; az[t] = (f32x4){0,0,0,0}; }
#pragma unroll
    for (int ks = 0; ks < 4; ++ks) {
        bf16x8 a = *reinterpret_cast<const bf16x8*>(&Hw[l * STR + ks * 32 + g * 8]);
#pragma unroll
        for (int t = 0; t < 4; ++t) {
            ay[t] = __builtin_amdgcn_mfma_f32_16x16x32_bf16(a, Y8[(size_t)(ks * 4 + t) * 64], ay[t], 0, 0, 0);
            az[t] = __builtin_amdgcn_mfma_f32_16x16x32_bf16(a, Z8[(size_t)(ks * 4 + t) * 64], az[t], 0, 0, 0);
        }
    }

    // epilogue (wave-local LDS restage -> coalesced uint4 stores)
#pragma unroll
    for (int t = 0; t < 4; ++t)
#pragma unroll
        for (int r = 0; r < 4; ++r)
            Hw[(g * 4 + r) * STR + t * 16 + l] = f2bf(ay[t][r]);
#pragma unroll
    for (int it = 0; it < 2; ++it) {
        int idx = it * 64 + lane, row = idx >> 3, c8 = idx & 7;
        if (nb0 + row < n)
            *reinterpret_cast<uint4*>(y2 + (size_t)(nb0 + row) * 64 + c8 * 8) =
                *reinterpret_cast<const uint4*>(&Hw[row * STR + c8 * 8]);
    }
#pragma unroll
    for (int t = 0; t < 4; ++t) {
        float bv = bias[t * 16 + l];
#pragma unroll
        for (int r = 0; r < 4; ++r)
            Hw[(g * 4 + r) * STR + t * 16 + l] = f2bf(az[t][r] + bv);
    }
#pragma unroll
    for (int it = 0; it < 2; ++it) {
        int idx = it * 64 + lane, row = idx >> 3, c8 = idx & 7;
        if (nb0 + row < n)
            *reinterpret_cast<uint4*>(z2 + (size_t)(nb0 + row) * 64 + c8 * 8) =
                *reinterpret_cast<const uint4*>(&Hw[row * STR + c8 * 8]);
    }
}

// gather2 + log_softmax combine (D=64, f32 out)
__global__ __launch_bounds__(256) void gather_lsm(const u16* __restrict__ y,
                                                  const int* __restrict__ rowptr,
                                                  const int* __restrict__ csr,
                                                  const u16* __restrict__ z,
                                                  float* __restrict__ out, int n) {
    const int wave = threadIdx.x >> 6, lane = threadIdx.x & 63;
    const int l = lane & 7, g = lane >> 3;            // 8 lanes/node, 8 nodes/wave
    const int node = (blockIdx.x * 4 + wave) * 8 + g;
    const bool ok = node < n;
    int start = 0, end = 0;
    if (ok) { start = rowptr[node]; end = rowptr[node + 1]; }

    float2 a0 = {0,0}, a1 = {0,0}, a2 = {0,0}, a3 = {0,0};
    int e = start;
    for (; e + 4 <= end; e += 4) {
        const int s0 = csr[e], s1 = csr[e + 1], s2 = csr[e + 2], s3 = csr[e + 3];
        uint4 v0 = *reinterpret_cast<const uint4*>(y + (size_t)s0 * 64 + l * 8);
        uint4 v1 = *reinterpret_cast<const uint4*>(y + (size_t)s1 * 64 + l * 8);
        uint4 v2 = *reinterpret_cast<const uint4*>(y + (size_t)s2 * 64 + l * 8);
        uint4 v3 = *reinterpret_cast<const uint4*>(y + (size_t)s3 * 64 + l * 8);
        accp(a0, v0.x); accp(a1, v0.y); accp(a2, v0.z); accp(a3, v0.w);
        accp(a0, v1.x); accp(a1, v1.y); accp(a2, v1.z); accp(a3, v1.w);
        accp(a0, v2.x); accp(a1, v2.y); accp(a2, v2.z); accp(a3, v2.w);
        accp(a0, v3.x); accp(a1, v3.y); accp(a2, v3.z); accp(a3, v3.w);
    }
    for (; e < end; ++e) {
        const int s0 = csr[e];
        uint4 v0 = *reinterpret_cast<const uint4*>(y + (size_t)s0 * 64 + l * 8);
        accp(a0, v0.x); accp(a1, v0.y); accp(a2, v0.z); accp(a3, v0.w);
    }

    if (ok) {
        const float inv = 1.0f / fmaxf((float)(end - start), 1.0f);
        uint4 zr = *reinterpret_cast<const uint4*>(z + (size_t)node * 64 + l * 8);
        float v0 = a0.x * inv + blo(zr.x), v1 = a0.y * inv + bhi(zr.x);
        float v2 = a1.x * inv + blo(zr.y), v3 = a1.y * inv + bhi(zr.y);
        float v4 = a2.x * inv + blo(zr.z), v5 = a2.y * inv + bhi(zr.z);
        float v6 = a3.x * inv + blo(zr.w), v7 = a3.y * inv + bhi(zr.w);

        float m = fmaxf(fmaxf(fmaxf(v0, v1), fmaxf(v2, v3)), fmaxf(fmaxf(v4, v5), fmaxf(v6, v7)));
        m = fmaxf(m, __shfl_xor(m, 1));
        m = fmaxf(m, __shfl_xor(m, 2));
        m = fmaxf(m, __shfl_xor(m, 4));
        float s = expf(v0 - m) + expf(v1 - m) + expf(v2 - m) + expf(v3 - m) +
                  expf(v4 - m) + expf(v5 - m) + expf(v6 - m) + expf(v7 - m);
        s += __shfl_xor(s, 1);
        s += __shfl_xor(s, 2);
        s += __shfl_xor(s, 4);
        const float c = m + logf(s);
        float* op = out + (size_t)node * 64 + l * 8;
        *reinterpret_cast<float4*>(op)     = (float4){v0 - c, v1 - c, v2 - c, v3 - c};
        *reinterpret_cast<float4*>(op + 4) = (float4){v4 - c, v5 - c, v6 - c, v7 - c};
    }
}

extern "C" void kernel_launch(void* const* d_in, const int* in_sizes, int n_in,
                              void* d_out, int out_size, void* d_ws, size_t ws_size,
                              hipStream_t stream) {
    const float* x    = (const float*)d_in[0];
    const int*   ei1  = (const int*)d_in[1];
    const int*   ei2  = (const int*)d_in[2];
    const float* W_l1 = (const float*)d_in[3];
    const float* b_l1 = (const float*)d_in[4];
    const float* W_r1 = (const float*)d_in[5];
    const float* W_l2 = (const float*)d_in[6];
    const float* b_l2 = (const float*)d_in[7];
    const float* W_r2 = (const float*)d_in[8];

    const int n  = in_sizes[0] / 128;
    const int E1 = in_sizes[1] / 2;
    const int E2 = in_sizes[2] / 2;
    const int nB = (n + BNODES - 1) >> BSHIFT;   // <= 1024
    const int ng1 = (E1 + CHUNK - 1) / CHUNK;
    const int ng2 = (E2 + CHUNK - 1) / CHUNK;
    const int ngp = ng1 + ng2;

    // ws layout (no xb, no hb — x read as f32 by gemm1; h lives in LDS only):
    char* w = (char*)d_ws;
    u16* yb  = (u16*)w; w += (size_t)n * 128 * 2;   // y1 = x@Wl1 (bf16)
    u16* zb  = (u16*)w; w += (size_t)n * 128 * 2;   // z1 = x@Wr1 + b1 (bf16)
    u16* y2b = (u16*)w; w += (size_t)n * 64 * 2;    // y2 = h@Wl2
    u16* z2b = (u16*)w; w += (size_t)n * 64 * 2;    // z2 = h@Wr2 + b2
    u16* Pl1 = (u16*)w; w += 16384 * 2;
    u16* Pr1 = (u16*)w; w += 16384 * 2;
    u16* Pl2 = (u16*)w; w += 8192 * 2;
    u16* Pr2 = (u16*)w; w += 8192 * 2;
    int* rp1   = (int*)w; w += (size_t)(n + 1) * 4;
    int* rp2   = (int*)w; w += (size_t)(n + 1) * 4;
    int* bcnt  = (int*)w; w += 2048 * 4;            // bc1 | bc2
    int* bbase1= (int*)w; w += 1025 * 4;
    int* bbase2= (int*)w; w += 1025 * 4;
    int* bcur1 = (int*)w; w += 1024 * 4;
    int* bcur2 = (int*)w; w += 1024 * 4;
    int* csr1  = (int*)w; w += (size_t)E1 * 4;
    int* csr2  = (int*)w; w += (size_t)E2 * 4;
    u32* eb1   = (u32*)w; w += (size_t)E1 * 4;      // dedicated (freed 51MB by
    u32* eb2   = (u32*)w;                           // dropping xb/hb buffers)

    const int gb64 = (n + 63) / 64;   // 64 rows/block (16/wave)

    hipMemsetAsync(bcnt, 0, 2048 * sizeof(int), stream);

    // L0: weight pack || bucket count (both layers)
    pack_count<<<24 + ngp, 256, 0, stream>>>(W_l1, W_r1, W_l2, W_r2, Pl1, Pr1, Pl2, Pr2,
                                             ei1, E1, ng1, bcnt, ei2, E2, bcnt + 1024, nB);
    // L1: scan both
    bucket_scan_both<<<2, 64, 0, stream>>>(bcnt, bbase1, bcur1, rp1, E1,
                                           bcnt + 1024, bbase2, bcur2, rp2, E2, nB, n);
    // L2: partition(both) || gemm1 (f32 x)
    part_gemm1<<<ngp + gb64, 256, 0, stream>>>(ei1, E1, ng1, bcur1, eb1, ei2, E2, bcur2, eb2,
                                               nB, ngp, x, Pl1, Pr1, b_l1, yb, zb, n);
    // L3: build both CSRs
    build_both<<<2 * nB, 256, 0, stream>>>(eb1, bbase1, rp1, csr1,
                                           eb2, bbase2, rp2, csr2, nB, n);
    // L4: gather1 + relu + gemm2 (h in LDS only)
    gather_gemm2<<<gb64, 256, 0, stream>>>(yb, rp1, csr1, zb, Pl2, Pr2, b_l2, y2b, z2b, n);
    // L5: gather2 + log_softmax
    gather_lsm<<<(n + 31) / 32, 256, 0, stream>>>(y2b, rp2, csr2, z2b, (float*)d_out, n);
}